// Round 20
// baseline (438.459 us; speedup 1.0000x reference)
//
#include <hip/hip_runtime.h>
#include <math.h>

#define B_ 2048
#define A_ 8
#define ACT_ 14
#define FP_ 27262976l   // feat stride (16384*1664), single bf16 plane

typedef short short8 __attribute__((ext_vector_type(8)));
typedef float floatx4 __attribute__((ext_vector_type(4)));
typedef unsigned short u16x4 __attribute__((ext_vector_type(4)));

__device__ __forceinline__ unsigned short f2b(float f) {
    unsigned u = __float_as_uint(f);
    u += 0x7fff + ((u >> 16) & 1);
    return (unsigned short)(u >> 16);
}
__device__ __forceinline__ float b2f(unsigned short h) {
    return __uint_as_float(((unsigned)h) << 16);
}
__device__ __forceinline__ float sigm_(float x) { return 1.0f / (1.0f + expf(-x)); }

// ===== bf16 MFMA GEMM: 128x64 tiles, exact hi/lo weights (2-term Xh·Wh + Xh·Wl),
// ===== single-bf16 activations, ping-pong LDS (1 barrier/chunk), depth-4 reg prefetch.
// flags: 1=relu, 2=bf16 out, 4=token-fold rows, 8=split bias at col 512,
//        16=LSTM epilogue (W gate-permuted at cast; writes tok/feat, skips Y).
struct GDesc {
    const unsigned short *X1, *X2, *W1, *W2;
    const float *b1, *b2;
    void* Y;
    const unsigned short* cms;       // masked bf16 c-state [l][a][b][j]
    unsigned short* tokp;
    unsigned short* featp;
    long xsa1, xsa2, wsa1, wps1, wsa2, wps2, bsa1, bsa2, ysa;
    int ldx1, K1, ldx2, K2, ldy, N, flags, nA, Nb, layer, foff;
};

#define LOADC(c, xh0, xh1, whv, wlv) do {                                                 \
    const unsigned short *Xb_, *Wb_; int ldx_, K_, k0_; long wps_;                        \
    if ((c) < nC1) { Xb_ = X1; ldx_ = ldx1; K_ = K1; wps_ = wps1; Wb_ = W1; k0_ = (c) << 5; } \
    else { Xb_ = X2; ldx_ = ldx2; K_ = K2; wps_ = wps2; Wb_ = W2; k0_ = ((c) - nC1) << 5; } \
    { int row_ = xr0 + lrow;                                                              \
      xh0 = *(const short8*)(Xb_ + (long)(bm + row_) * ldx_ + k0_ + lslot * 8); }         \
    { int row_ = xr0 + 16 + lrow;                                                         \
      xh1 = *(const short8*)(Xb_ + (long)(bm + row_) * ldx_ + k0_ + lslot * 8); }         \
    { int row_ = wr0 + lrow;                                                              \
      const unsigned short* wp_ = Wb_ + (long)(bn + row_) * K_ + k0_ + lslot * 8;         \
      whv = *(const short8*)wp_; wlv = *(const short8*)(wp_ + wps_); }                    \
} while (0)

#define STOREC(P, xh0, xh1, whv, wlv) do {                                                \
    { int row_ = xr0 + lrow; int sl_ = lslot ^ ((row_ >> 1) & 3);                         \
      *(short8*)&Xh_l[P][row_ * 32 + sl_ * 8] = xh0; }                                    \
    { int row_ = xr0 + 16 + lrow; int sl_ = lslot ^ ((row_ >> 1) & 3);                    \
      *(short8*)&Xh_l[P][row_ * 32 + sl_ * 8] = xh1; }                                    \
    { int row_ = wr0 + lrow; int sl_ = lslot ^ ((row_ >> 1) & 3);                         \
      *(short8*)&Wh_l[P][row_ * 32 + sl_ * 8] = whv;                                      \
      *(short8*)&Wl_l[P][row_ * 32 + sl_ * 8] = wlv; }                                    \
} while (0)

#define COMPUTEC(P) do {                                                                  \
    short8 bh[4], bl[4];                                                                  \
    _Pragma("unroll") for (int ni = 0; ni < 4; ++ni) {                                    \
        int row_ = ni * 16 + lr; int off_ = row_ * 32 + ((lk ^ ((row_ >> 1) & 3)) * 8);   \
        bh[ni] = *(const short8*)&Wh_l[P][off_]; bl[ni] = *(const short8*)&Wl_l[P][off_]; } \
    _Pragma("unroll") for (int mi = 0; mi < 2; ++mi) {                                    \
        int row_ = xr0 + mi * 16 + lr; int off_ = row_ * 32 + ((lk ^ ((row_ >> 1) & 3)) * 8); \
        short8 ah = *(const short8*)&Xh_l[P][off_];                                       \
        _Pragma("unroll") for (int ni = 0; ni < 4; ++ni)                                  \
            acc[mi][ni] = __builtin_amdgcn_mfma_f32_16x16x32_bf16(ah, bh[ni], acc[mi][ni], 0, 0, 0); \
        _Pragma("unroll") for (int ni = 0; ni < 4; ++ni)                                  \
            acc[mi][ni] = __builtin_amdgcn_mfma_f32_16x16x32_bf16(ah, bl[ni], acc[mi][ni], 0, 0, 0); \
    }                                                                                     \
} while (0)

__launch_bounds__(256)
__global__ void mgemm1(GDesc d)
{
    __shared__ __align__(16) unsigned short Xh_l[2][128 * 32];
    __shared__ __align__(16) unsigned short Wh_l[2][64 * 32];
    __shared__ __align__(16) unsigned short Wl_l[2][64 * 32];

    const int wg = blockIdx.x;
    const unsigned short* X1 = d.X1; const unsigned short* X2 = d.X2;
    const unsigned short* W1 = d.W1; const unsigned short* W2 = d.W2;
    const float* b1 = d.b1; const float* b2 = d.b2;
    const long wps1 = d.wps1, wps2 = d.wps2, ysa = d.ysa;
    const int ldx1 = d.ldx1, K1 = d.K1, ldx2 = d.ldx2, K2 = d.K2;
    const int ldy = d.ldy, N = d.N, flags = d.flags, nA = d.nA, Nb = d.Nb;
    const int layer = d.layer, foff = d.foff;

    int a, mb, nb;
    if (nA == 8) { a = wg & 7; int q = wg >> 3; nb = q % Nb; mb = q / Nb; }
    else { a = 0; int x8 = wg & 7; int q = wg >> 3; nb = q % Nb; mb = (q / Nb) * 8 + x8; }

    X1 += (long)a * d.xsa1;
    W1 += (long)a * d.wsa1;
    if (X2) { X2 += (long)a * d.xsa2; W2 += (long)a * d.wsa2; }
    if (b1) b1 += (long)a * d.bsa1;
    if (b2) b2 += (long)a * d.bsa2;

    const int bm = mb * 128;
    const int bn = nb * 64;
    const int t = threadIdx.x;
    const int lane = t & 63, wid = t >> 6;

    floatx4 acc[2][4] = {};

    const int xr0 = wid * 32;
    const int wr0 = wid * 16;
    const int lrow = lane >> 2;
    const int lslot = lane & 3;
    const int lr = lane & 15, lk = lane >> 4;

    const int nC1 = K1 >> 5;
    const int nC = nC1 + (X2 ? (K2 >> 5) : 0);

    short8 Axh0, Axh1, Awh, Awl;
    short8 Bxh0, Bxh1, Bwh, Bwl;
    short8 Cxh0, Cxh1, Cwh, Cwl;
    short8 Dxh0, Dxh1, Dwh, Dwl;

    LOADC(0, Axh0, Axh1, Awh, Awl);
    if (nC > 1) LOADC(1, Bxh0, Bxh1, Bwh, Bwl);
    if (nC > 2) LOADC(2, Cxh0, Cxh1, Cwh, Cwl);
    if (nC > 3) LOADC(3, Dxh0, Dxh1, Dwh, Dwl);

    for (int c = 0; c < nC; c += 4) {
        STOREC(0, Axh0, Axh1, Awh, Awl);
        __syncthreads();
        if (c + 4 < nC) LOADC(c + 4, Axh0, Axh1, Awh, Awl);
        COMPUTEC(0);
        if (c + 1 < nC) {
            STOREC(1, Bxh0, Bxh1, Bwh, Bwl);
            __syncthreads();
            if (c + 5 < nC) LOADC(c + 5, Bxh0, Bxh1, Bwh, Bwl);
            COMPUTEC(1);
        }
        if (c + 2 < nC) {
            STOREC(0, Cxh0, Cxh1, Cwh, Cwl);
            __syncthreads();
            if (c + 6 < nC) LOADC(c + 6, Cxh0, Cxh1, Cwh, Cwl);
            COMPUTEC(0);
        }
        if (c + 3 < nC) {
            STOREC(1, Dxh0, Dxh1, Dwh, Dwl);
            __syncthreads();
            if (c + 7 < nC) LOADC(c + 7, Dxh0, Dxh1, Dwh, Dwl);
            COMPUTEC(1);
        }
    }

    const int lg = lane >> 4;

    if (flags & 16) {
        // fused LSTM pointwise epilogue (W rows gate-permuted at cast); j = nb*16 + lr
        const int j = (bn >> 2) + lr;
        unsigned short* tokp = d.tokp;
        unsigned short* featp = d.featp;
        const unsigned short* cms = d.cms;
#pragma unroll
        for (int mi = 0; mi < 2; ++mi) {
#pragma unroll
            for (int r = 0; r < 4; ++r) {
                const int b = bm + xr0 + mi * 16 + lg * 4 + r;
                float iv = acc[mi][0][r] + b1[j]       + b2[j];
                float fv = acc[mi][1][r] + b1[128 + j] + b2[128 + j];
                float gv = acc[mi][2][r] + b1[256 + j] + b2[256 + j];
                float ov = acc[mi][3][r] + b1[384 + j] + b2[384 + j];
                iv = sigm_(iv); fv = sigm_(fv); gv = tanhf(gv); ov = sigm_(ov);
                float cp = b2f(cms[(long)layer * 2097152 + (long)a * 262144 + b * 128 + j]);
                float c2 = fv * cp + iv * gv;
                float hv = ov * tanhf(c2);
                long tb = ((long)a * B_ + b) * 512;
                tokp[tb + layer * 128 + j] = f2b(hv);
                tokp[tb + (2 + layer) * 128 + j] = f2b(c2);
                if (featp) featp[((long)a * B_ + b) * 1664 + foff + j] = f2b(hv);
            }
        }
        return;
    }

    const bool relu = flags & 1, obf = flags & 2, fold = flags & 4, sbias = flags & 8;
    float* Yf = (float*)d.Y;
    unsigned short* Yh = (unsigned short*)d.Y;
#pragma unroll
    for (int mi = 0; mi < 2; ++mi) {
#pragma unroll
        for (int r = 0; r < 4; ++r) {
            int gm = bm + xr0 + mi * 16 + lg * 4 + r;
            long rowoff = fold ? ((long)(gm >> 2) * ldy + (gm & 3) * 128) : (long)gm * ldy;
            rowoff += (long)a * ysa;
#pragma unroll
            for (int ni = 0; ni < 4; ++ni) {
                int gc = bn + ni * 16 + lr;
                if (gc < N) {
                    float v = acc[mi][ni][r];
                    if (sbias) v += (gc < 512) ? b1[gc] : b2[gc - 512];
                    else { if (b1) v += b1[gc]; if (b2) v += b2[gc]; }
                    if (relu) v = fmaxf(v, 0.f);
                    if (obf) Yh[rowoff + gc] = f2b(v);
                    else     Yf[rowoff + gc] = v;
                }
            }
        }
    }
}

// ===== fused qkv-GEMM + 4-token MHA + out-proj, BOTH chains, 512 thr (8 waves) =====
// v4: W B-fragments loaded DIRECTLY from global into registers (each lane's frag is a
// contiguous short8), depth-1 prefetched under the current chunk's MFMAs. No W LDS, no
// in-loop barriers (3 block barriers total). LDS = Xs + Q only. Numerics identical.
__launch_bounds__(512, 4)
__global__ void sattn_k(const unsigned short* __restrict__ tokS,
                        const unsigned short* __restrict__ tokC,
                        const unsigned short* __restrict__ WqS,
                        const unsigned short* __restrict__ WqC, long qlo,
                        const float* __restrict__ qbS, const float* __restrict__ qbC,
                        const unsigned short* __restrict__ WoS,
                        const unsigned short* __restrict__ WoC, long olo,
                        const float* __restrict__ obS, const float* __restrict__ obC,
                        unsigned short* __restrict__ feat)
{
    __shared__ __align__(16) unsigned short Xs[64 * 128];    // tok tile -> attn_o (reused)
    __shared__ __align__(16) unsigned short Q[64 * 392];     // qkv bf16
    __shared__ float qbias[384];
    __shared__ float obias[128];

    int bid = blockIdx.x;
    const unsigned short* tok; const unsigned short* Wq; const float* qb;
    const unsigned short* Wo; const float* ob; int foff;
    if (bid < 1024) { tok = tokS; Wq = WqS; qb = qbS; Wo = WoS; ob = obS; foff = 512; }
    else { bid -= 1024; tok = tokC; Wq = WqC; qb = qbC; Wo = WoC; ob = obC; foff = 1152; }

    const int a = bid & 7;               // agent-per-XCD
    const int g = bid >> 3;              // 0..127
    const int b0 = g * 16;

    const unsigned short* Wqa = Wq + (long)a * 49152;
    const unsigned short* Woa = Wo + (long)a * 16384;
    const unsigned short* tokb = tok + ((long)a * B_ + b0) * 512;

    const int t = threadIdx.x;
    const int lane = t & 63, wid = t >> 6;          // wid 0..7
    const int lr = lane & 15, lk = lane >> 4, lg = lane >> 4;

    // ---- stage X (64x128, slot-swizzled s^(r&7)) + biases ----
    for (int idx = t; idx < 1024; idx += 512) {
        int r = idx >> 4, s = idx & 15;
        *(short8*)&Xs[r * 128 + (s ^ (r & 7)) * 8] = *(const short8*)(tokb + r * 128 + s * 8);
    }
    if (t < 384) qbias[t] = qb[a * 384 + t];
    if (t < 128) obias[t] = ob[a * 128 + t];

    // ---- fragment-direct W pointers (lane's B-frag = contiguous short8) ----
    const unsigned short* wrow0 = Wqa + (wid * 48 +  0 + lr) * 128 + lk * 8;
    const unsigned short* wrow1 = Wqa + (wid * 48 + 16 + lr) * 128 + lk * 8;
    const unsigned short* wrow2 = Wqa + (wid * 48 + 32 + lr) * 128 + lk * 8;

    // prefetch chunk 0 frags (in flight across bar1)
    short8 cbh0 = *(const short8*)(wrow0);
    short8 cbh1 = *(const short8*)(wrow1);
    short8 cbh2 = *(const short8*)(wrow2);
    short8 cbl0 = *(const short8*)(wrow0 + qlo);
    short8 cbl1 = *(const short8*)(wrow1 + qlo);
    short8 cbl2 = *(const short8*)(wrow2 + qlo);

    __syncthreads();                     // bar1: Xs + qbias visible

    floatx4 acc[4][3] = {};              // m-frag 0..3 (rows), n-frag 0..2 (cols wid*48+)

#pragma unroll
    for (int kc = 0; kc < 4; ++kc) {
        const int k0 = kc * 32;
        short8 nbh0, nbh1, nbh2, nbl0, nbl1, nbl2;
        if (kc < 3) {
            nbh0 = *(const short8*)(wrow0 + k0 + 32);
            nbh1 = *(const short8*)(wrow1 + k0 + 32);
            nbh2 = *(const short8*)(wrow2 + k0 + 32);
            nbl0 = *(const short8*)(wrow0 + qlo + k0 + 32);
            nbl1 = *(const short8*)(wrow1 + qlo + k0 + 32);
            nbl2 = *(const short8*)(wrow2 + qlo + k0 + 32);
        }
        short8 af[4];
#pragma unroll
        for (int mi = 0; mi < 4; ++mi) {
            int row = mi * 16 + lr;
            int sl = ((k0 >> 3) + lk) ^ (row & 7);
            af[mi] = *(const short8*)&Xs[row * 128 + sl * 8];
        }
#pragma unroll
        for (int mi = 0; mi < 4; ++mi) {
            acc[mi][0] = __builtin_amdgcn_mfma_f32_16x16x32_bf16(af[mi], cbh0, acc[mi][0], 0, 0, 0);
            acc[mi][1] = __builtin_amdgcn_mfma_f32_16x16x32_bf16(af[mi], cbh1, acc[mi][1], 0, 0, 0);
            acc[mi][2] = __builtin_amdgcn_mfma_f32_16x16x32_bf16(af[mi], cbh2, acc[mi][2], 0, 0, 0);
        }
#pragma unroll
        for (int mi = 0; mi < 4; ++mi) {
            acc[mi][0] = __builtin_amdgcn_mfma_f32_16x16x32_bf16(af[mi], cbl0, acc[mi][0], 0, 0, 0);
            acc[mi][1] = __builtin_amdgcn_mfma_f32_16x16x32_bf16(af[mi], cbl1, acc[mi][1], 0, 0, 0);
            acc[mi][2] = __builtin_amdgcn_mfma_f32_16x16x32_bf16(af[mi], cbl2, acc[mi][2], 0, 0, 0);
        }
        if (kc < 3) {
            cbh0 = nbh0; cbh1 = nbh1; cbh2 = nbh2;
            cbl0 = nbl0; cbl1 = nbl1; cbl2 = nbl2;
        }
    }

    // ---- write qkv (bf16 + bias) to Q[64][392]; no barrier needed before (Q untouched) ----
#pragma unroll
    for (int mi = 0; mi < 4; ++mi)
#pragma unroll
        for (int ni = 0; ni < 3; ++ni)
#pragma unroll
            for (int rr = 0; rr < 4; ++rr) {
                int row = mi * 16 + lg * 4 + rr;
                int col = wid * 48 + ni * 16 + lr;
                Q[row * 392 + col] = f2b(acc[mi][ni][rr] + qbias[col]);
            }
    __syncthreads();                     // bar2: Q visible

    // ---- prefetch out-proj W chunk 0 frags (hide under attention VALU) ----
    const unsigned short* orow = Woa + (wid * 16 + lr) * 128 + lk * 8;
    short8 obh = *(const short8*)(orow);
    short8 obl = *(const short8*)(orow + olo);

    // ---- attention: 2 threads per (sample, tq, h4); each half of PV output ----
    float oa[16];
    int qr, h4, hf;
    {
        int tt = t & 255;
        h4 = tt & 3; int tq = (tt >> 2) & 3, s = tt >> 4;
        hf = t >> 8;                       // 0 or 1: output half
        qr = s * 4 + tq;
        const unsigned short* qp = Q + qr * 392 + h4 * 32;
        float q[32];
#pragma unroll
        for (int r = 0; r < 8; ++r) {
            u16x4 v = *(const u16x4*)(qp + r * 4);
#pragma unroll
            for (int w = 0; w < 4; ++w) q[r * 4 + w] = b2f(v[w]);
        }
        float sv[4];
#pragma unroll
        for (int u = 0; u < 4; ++u) {
            const unsigned short* kp = Q + (s * 4 + u) * 392 + 128 + h4 * 32;
            float dd = 0.f;
#pragma unroll
            for (int r = 0; r < 8; ++r) {
                u16x4 v = *(const u16x4*)(kp + r * 4);
#pragma unroll
                for (int w = 0; w < 4; ++w) dd += q[r * 4 + w] * b2f(v[w]);
            }
            sv[u] = dd * 0.176776695296637f;
        }
        float mx = fmaxf(fmaxf(sv[0], sv[1]), fmaxf(sv[2], sv[3]));
        float e0 = expf(sv[0] - mx), e1 = expf(sv[1] - mx), e2 = expf(sv[2] - mx), e3 = expf(sv[3] - mx);
        float inv = 1.0f / (e0 + e1 + e2 + e3);
        float al[4] = { e0 * inv, e1 * inv, e2 * inv, e3 * inv };
#pragma unroll
        for (int w = 0; w < 16; ++w) oa[w] = 0.f;
#pragma unroll
        for (int u = 0; u < 4; ++u) {
            const unsigned short* vp = Q + (s * 4 + u) * 392 + 256 + h4 * 32 + hf * 16;
            float wgt = al[u];
#pragma unroll
            for (int r = 0; r < 4; ++r) {
                u16x4 v = *(const u16x4*)(vp + r * 4);
#pragma unroll
                for (int w = 0; w < 4; ++w) oa[r * 4 + w] += wgt * b2f(v[w]);
            }
        }
        // write attn_o half into Xs (swizzled); Xs reads all finished before bar2,
        // attn only READS Q, so no extra barrier needed here
#pragma unroll
        for (int p = 0; p < 2; ++p) {
            short8 v;
#pragma unroll
            for (int w = 0; w < 8; ++w) v[w] = (short)f2b(oa[p * 8 + w]);
            int slot = h4 * 4 + hf * 2 + p;
            *(short8*)&Xs[qr * 128 + (slot ^ (qr & 7)) * 8] = v;
        }
    }
    __syncthreads();                     // bar3: attn Xs writes visible

    // ---- out-proj: M=64, N=128 (wave owns 16 cols), K=128; fragment-direct W ----
    floatx4 acc2[4] = {};                // m-frag 0..3, col block wid*16
#pragma unroll
    for (int kc = 0; kc < 4; ++kc) {
        const int k0 = kc * 32;
        short8 nh, nl;
        if (kc < 3) {
            nh = *(const short8*)(orow + k0 + 32);
            nl = *(const short8*)(orow + olo + k0 + 32);
        }
        short8 af[4];
#pragma unroll
        for (int mi = 0; mi < 4; ++mi) {
            int row = mi * 16 + lr;
            int sl = ((k0 >> 3) + lk) ^ (row & 7);
            af[mi] = *(const short8*)&Xs[row * 128 + sl * 8];
        }
#pragma unroll
        for (int mi = 0; mi < 4; ++mi)
            acc2[mi] = __builtin_amdgcn_mfma_f32_16x16x32_bf16(af[mi], obh, acc2[mi], 0, 0, 0);
#pragma unroll
        for (int mi = 0; mi < 4; ++mi)
            acc2[mi] = __builtin_amdgcn_mfma_f32_16x16x32_bf16(af[mi], obl, acc2[mi], 0, 0, 0);
        if (kc < 3) { obh = nh; obl = nl; }
    }

    // ---- epilogue: token-folded feat write ----
#pragma unroll
    for (int mi = 0; mi < 4; ++mi)
#pragma unroll
        for (int rr = 0; rr < 4; ++rr) {
            int row = mi * 16 + lg * 4 + rr;
            int s2 = row >> 2, tq2 = row & 3;
            long base = ((long)a * B_ + b0 + s2) * 1664 + foff + tq2 * 128;
            int col = wid * 16 + lr;
            feat[base + col] = f2b(acc2[mi][rr] + obias[col]);
        }
}

// ===== weight cast (f32 -> bf16 hi + lo planes; optional LSTM gate permute) =====
#define NW 19
struct WTab {
    const float* src[NW];
    long hoff[NW];
    long loff[NW];
    int n[NW];
    int npad[NW];
    int kc[NW];
};
__global__ void wcast_k(WTab tab, unsigned short* __restrict__ wb)
{
    const int e = blockIdx.y;
    const int np = tab.npad[e];
    const float* s = tab.src[e];
    unsigned short* dh = wb + tab.hoff[e];
    unsigned short* dl = wb + tab.loff[e];
    const int n = tab.n[e];
    const int kc = tab.kc[e];
    for (long i = (long)blockIdx.x * 256 + threadIdx.x; i < np; i += (long)gridDim.x * 256) {
        long si = i;
        if (kc) {
            long per = 512l * kc;
            long ag = i / per;
            long rem = i - ag * per;
            int rp = (int)(rem / kc);
            int k = (int)(rem - (long)rp * kc);
            int srcr = (((rp & 63) >> 4) << 7) + ((rp >> 6) << 4) + (rp & 15);
            si = ag * per + (long)srcr * kc + k;
        }
        float v = (si < n) ? s[si] : 0.f;
        unsigned short h = f2b(v);
        dh[i] = h;
        dl[i] = f2b(v - b2f(h));
    }
}

// ===== prep: obs -> feat[:,0:128]; masked h/c states -> bf16 =====
__global__ void prep_k(const float* __restrict__ obs, const float* __restrict__ soh,
                       const float* __restrict__ sch, const float* __restrict__ soc,
                       const float* __restrict__ scc, const float* __restrict__ masks,
                       unsigned short* __restrict__ feat,
                       unsigned short* __restrict__ hmso, unsigned short* __restrict__ hmsc,
                       unsigned short* __restrict__ cmso, unsigned short* __restrict__ cmsc)
{
    long tid = (long)blockIdx.x * 256 + threadIdx.x;
    if (tid < 2097152) {
        int j = (int)(tid & 127);
        int row = (int)(tid >> 7);
        int b = row >> 3, aa = row & 7;
        feat[((long)aa * B_ + b) * 1664 + j] = f2b(obs[tid]);
        return;
    }
    long u = tid - 2097152;
    const float* src;
    unsigned short* dst;
    if (u < 4194304) { src = soh; dst = hmso; }
    else if (u < 2 * 4194304) { u -= 4194304; src = sch; dst = hmsc; }
    else if (u < 3 * 4194304) { u -= 2 * 4194304; src = soc; dst = cmso; }
    else { u -= 3 * 4194304; src = scc; dst = cmsc; }
    int j = (int)(u & 127);
    int b = (int)((u >> 7) & 2047);
    int aa = (int)((u >> 18) & 7);
    int l = (int)(u >> 21);
    float m = masks[b * 8 + aa];
    dst[u] = f2b(src[((long)(b * 8 + aa)) * 256 + l * 128 + j] * m);
}

// ===== GATv2 reduce (xlr combined [row][1024]: xl | xr) =====
__launch_bounds__(256)
__global__ void gat_reduce_k(const unsigned short* __restrict__ xlr,
                             const float* __restrict__ att, const float* __restrict__ bias,
                             unsigned short* __restrict__ feat, int coloff)
{
    __shared__ float xls[8][512];
    __shared__ float xrs[8][512];
    __shared__ float atts[512];
    __shared__ float es[8][8][4];
    __shared__ float as_[8][8][4];

    const int b = blockIdx.x;
    const int t = threadIdx.x;

    for (int i = t; i < 1024; i += 256) {
        int j = i >> 7, c4 = (i & 127) * 4;
        const unsigned short* base = xlr + ((long)j * B_ + b) * 1024;
        u16x4 vl = *(const u16x4*)(base + c4);
        u16x4 vr = *(const u16x4*)(base + 512 + c4);
#pragma unroll
        for (int q = 0; q < 4; ++q) {
            xls[j][c4 + q] = b2f(vl[q]);
            xrs[j][c4 + q] = b2f(vr[q]);
        }
    }
    for (int i = t; i < 128; i += 256)
        reinterpret_cast<float4*>(atts)[i] = reinterpret_cast<const float4*>(att)[i];
    __syncthreads();

    const int i = t >> 5, j = (t >> 2) & 7, h = t & 3;
    float e = 0.f;
    for (int cc = 0; cc < 128; ++cc) {
        int c = (cc + t) & 127;
        float s = xls[j][h * 128 + c] + xrs[i][h * 128 + c];
        s = s > 0.f ? s : 0.2f * s;
        e += s * atts[h * 128 + c];
    }
    es[i][j][h] = e;
    __syncthreads();

    float mx = -1e30f;
    for (int jj = 0; jj < 8; ++jj) mx = fmaxf(mx, es[i][jj][h]);
    float sum = 0.f;
    for (int jj = 0; jj < 8; ++jj) sum += expf(es[i][jj][h] - mx);
    as_[i][j][h] = expf(e - mx) / sum;
    __syncthreads();

    for (int idx = t; idx < 1024; idx += 256) {
        int ii = idx >> 7, c = idx & 127;
        float s = 0.f;
        for (int jj = 0; jj < 8; ++jj)
#pragma unroll
            for (int hh = 0; hh < 4; ++hh)
                s += as_[ii][jj][hh] * xls[jj][hh * 128 + c];
        s = s * 0.25f + bias[c];
        s = fmaxf(s, 0.f);
        feat[((long)ii * B_ + b) * 1664 + coloff + c] = f2b(s);
    }
}

// ===== log_softmax + transpose [A][B][14] -> (B,A,14) =====
__global__ void lsm_k(const float* __restrict__ logits, float* __restrict__ out)
{
    int tid = blockIdx.x * 256 + threadIdx.x;    // A*B
    int b = tid & (B_ - 1);
    int a = tid >> 11;
    const float* lp = logits + ((long)a * B_ + b) * ACT_;
    float x[ACT_];
    float mx = -1e30f;
#pragma unroll
    for (int n = 0; n < ACT_; ++n) { x[n] = lp[n]; mx = fmaxf(mx, x[n]); }
    float sum = 0.f;
#pragma unroll
    for (int n = 0; n < ACT_; ++n) sum += expf(x[n] - mx);
    float ls = mx + logf(sum);
    float* op = out + ((long)b * A_ + a) * ACT_;
#pragma unroll
    for (int n = 0; n < ACT_; ++n) op[n] = x[n] - ls;
}

extern "C" void kernel_launch(void* const* d_in, const int* in_sizes, int n_in,
                              void* d_out, int out_size, void* d_ws, size_t ws_size,
                              hipStream_t stream)
{
    const float* obs    = (const float*)d_in[0];
    const float* somu_h = (const float*)d_in[1];
    const float* somu_c = (const float*)d_in[2];
    const float* scmu_h = (const float*)d_in[3];
    const float* scmu_c = (const float*)d_in[4];
    const float* masks  = (const float*)d_in[5];
    const float* gWl0 = (const float*)d_in[6],  *gbl0 = (const float*)d_in[7];
    const float* gWr0 = (const float*)d_in[8],  *gbr0 = (const float*)d_in[9];
    const float* gatt0 = (const float*)d_in[10], *gbias0 = (const float*)d_in[11];
    const float* gWl1 = (const float*)d_in[12], *gbl1 = (const float*)d_in[13];
    const float* gWr1 = (const float*)d_in[14], *gbr1 = (const float*)d_in[15];
    const float* gatt1 = (const float*)d_in[16], *gbias1 = (const float*)d_in[17];
    const float* soWih0 = (const float*)d_in[18], *soWhh0 = (const float*)d_in[19];
    const float* sobih0 = (const float*)d_in[20], *sobhh0 = (const float*)d_in[21];
    const float* soWih1 = (const float*)d_in[22], *soWhh1 = (const float*)d_in[23];
    const float* sobih1 = (const float*)d_in[24], *sobhh1 = (const float*)d_in[25];
    const float* soqw = (const float*)d_in[26], *soqb = (const float*)d_in[27];
    const float* soow = (const float*)d_in[28], *soob = (const float*)d_in[29];
    const float* scWih0 = (const float*)d_in[30], *scWhh0 = (const float*)d_in[31];
    const float* scbih0 = (const float*)d_in[32], *scbhh0 = (const float*)d_in[33];
    const float* scWih1 = (const float*)d_in[34], *scWhh1 = (const float*)d_in[35];
    const float* scbih1 = (const float*)d_in[36], *scbhh1 = (const float*)d_in[37];
    const float* scqw = (const float*)d_in[38], *scqb = (const float*)d_in[39];
    const float* scow = (const float*)d_in[40], *scob = (const float*)d_in[41];
    const float* fcw0 = (const float*)d_in[42], *fcb0 = (const float*)d_in[43];
    const float* fcw1 = (const float*)d_in[44], *fcb1 = (const float*)d_in[45];
    const float* actw = (const float*)d_in[46], *actb = (const float*)d_in[47];

    // ---------- workspace layout (~200 MB) ----------
    unsigned short* wb = (unsigned short*)d_ws;
    long wo = 0;
    auto nxt = [&](long n) { long c = wo; wo += n; return c; };
    const long o_gW0 = nxt(262144), o_gW1 = nxt(262144);
    const long o_soWih0 = nxt(2 * 524288), o_soWhh0 = nxt(2 * 524288);
    const long o_soWih1 = nxt(2 * 524288), o_soWhh1 = nxt(2 * 524288);
    const long o_soqw = nxt(2 * 393216), o_soow = nxt(2 * 131072);
    const long o_scWih0 = nxt(2 * 1572864), o_scWhh0 = nxt(2 * 524288);
    const long o_scWih1 = nxt(2 * 524288), o_scWhh1 = nxt(2 * 524288);
    const long o_scqw = nxt(2 * 393216), o_scow = nxt(2 * 131072);
    const long o_fcw0 = nxt(2 * 425984), o_fcw1 = nxt(2 * 65536);
    const long o_actw = nxt(2 * 32768);                         // weights end: 14,155,776

    unsigned short* feat   = wb + nxt(FP_);            // single plane
    unsigned short* hmso   = wb + nxt(4194304);
    unsigned short* hmsc   = wb + nxt(4194304);
    unsigned short* cmso   = wb + nxt(4194304);
    unsigned short* cmsc   = wb + nxt(4194304);
    unsigned short* arenaA = wb + nxt(25165824);       // xlr | x1,x2,logits
    unsigned short* arenaB = wb + nxt(16777216);       // tokS, tokC
    // total ≈ 100.1M shorts = 200 MB

    unsigned short* xlr    = arenaA;                   // GAT phase [16384][1024]
    unsigned short* tokS   = arenaB;                   // [A][B][4][128]
    unsigned short* tokC   = arenaB + 8388608;
    unsigned short* x1     = arenaA;                   // head phase (single plane)
    unsigned short* x2     = arenaA + 4194304;
    float*          logits = (float*)(arenaA + 8388608);

    // ---------- weight cast ----------
    WTab tab;
    int ei = 0;
    auto ent = [&](const float* s, long hoff, long loff, int n, int npad, int kc) {
        tab.src[ei] = s; tab.hoff[ei] = hoff; tab.loff[ei] = loff;
        tab.n[ei] = n; tab.npad[ei] = npad; tab.kc[ei] = kc; ++ei;
    };
    ent(gWl0, o_gW0,          o_gW0 + 131072,          65536, 65536, 0);
    ent(gWr0, o_gW0 + 65536,  o_gW0 + 196608,          65536, 65536, 0);
    ent(gWl1, o_gW1,          o_gW1 + 131072,          65536, 65536, 0);
    ent(gWr1, o_gW1 + 65536,  o_gW1 + 196608,          65536, 65536, 0);
    ent(soWih0, o_soWih0, o_soWih0 + 524288, 524288, 524288, 128);
    ent(soWhh0, o_soWhh0, o_soWhh0 + 524288, 524288, 524288, 128);
    ent(soWih1, o_soWih1, o_soWih1 + 524288, 524288, 524288, 128);
    ent(soWhh1, o_soWhh1, o_soWhh1 + 524288, 524288, 524288, 128);
    ent(soqw, o_soqw, o_soqw + 393216, 393216, 393216, 0);
    ent(soow, o_soow, o_soow + 131072, 131072, 131072, 0);
    ent(scWih0, o_scWih0, o_scWih0 + 1572864, 1572864, 1572864, 384);
    ent(scWhh0, o_scWhh0, o_scWhh0 + 524288, 524288, 524288, 128);
    ent(scWih1, o_scWih1, o_scWih1 + 524288, 524288, 524288, 128);
    ent(scWhh1, o_scWhh1, o_scWhh1 + 524288, 524288, 524288, 128);
    ent(scqw, o_scqw, o_scqw + 393216, 393216, 393216, 0);
    ent(scow, o_scow, o_scow + 131072, 131072, 131072, 0);
    ent(fcw0, o_fcw0, o_fcw0 + 425984, 425984, 425984, 0);
    ent(fcw1, o_fcw1, o_fcw1 + 65536, 65536, 65536, 0);
    ent(actw, o_actw, o_actw + 32768, 3584, 32768, 0);
    wcast_k<<<dim3(1024, NW), 256, 0, stream>>>(tab, wb);

    prep_k<<<(2097152 + 4 * 4194304) / 256, 256, 0, stream>>>(
        obs, somu_h, scmu_h, somu_c, scmu_c, masks, feat, hmso, hmsc, cmso, cmsc);

    auto mkd = [&](const unsigned short* X1p, long xsa1, int ldx1, int K1,
                   const unsigned short* X2p, long xsa2, int ldx2, int K2,
                   long wo1, long wsa1, long wps1, long wo2, long wsa2, long wps2,
                   const float* bb1, long bsa1, const float* bb2, long bsa2,
                   void* Y, long ysa, int ldy, int N, int flags, int nA,
                   const unsigned short* cmsp, unsigned short* tokp, unsigned short* featp,
                   int layer, int foff) -> GDesc {
        GDesc d;
        d.X1 = X1p; d.X2 = X2p;
        d.W1 = wb + wo1; d.W2 = X2p ? wb + wo2 : nullptr;
        d.b1 = bb1; d.b2 = bb2; d.Y = Y;
        d.cms = cmsp; d.tokp = tokp; d.featp = featp;
        d.xsa1 = xsa1; d.xsa2 = xsa2;
        d.wsa1 = wsa1; d.wps1 = wps1; d.wsa2 = wsa2; d.wps2 = wps2;
        d.bsa1 = bsa1; d.bsa2 = bsa2; d.ysa = ysa;
        d.ldx1 = ldx1; d.K1 = K1; d.ldx2 = ldx2; d.K2 = K2; d.ldy = ldy; d.N = N;
        d.flags = flags; d.nA = nA; d.Nb = (N + 63) / 64;
        d.layer = layer; d.foff = foff;
        return d;
    };
    auto grid_of = [&](const GDesc& d, int M) { return d.nA * (M / 128) * d.Nb; };

    // ---------- descriptors ----------
    GDesc gat0 = mkd(feat, 0, 1664, 128, nullptr, 0, 0, 0,
                     o_gW0, 0, 131072, 0, 0, 0, gbl0, 0, gbr0, 0,
                     xlr, 0, 1024, 1024, 2 | 8, 1, nullptr, nullptr, nullptr, 0, 0);
    GDesc gat1 = mkd(feat + 128, 0, 1664, 128, nullptr, 0, 0, 0,
                     o_gW1, 0, 131072, 0, 0, 0, gbl1, 0, gbr1, 0,
                     xlr, 0, 1024, 1024, 2 | 8, 1, nullptr, nullptr, nullptr, 0, 0);
    GDesc so0  = mkd(feat, (long)B_ * 1664, 1664, 128, hmso, (long)B_ * 128, 128, 128,
                     o_soWih0, 512l * 128, 524288, o_soWhh0, 512l * 128, 524288,
                     sobih0, 512, sobhh0, 512, nullptr, 0, 0, 512, 16, A_,
                     cmso, tokS, nullptr, 0, 0);
    GDesc so1  = mkd(tokS, (long)B_ * 512, 512, 128, hmso + 2097152, (long)B_ * 128, 128, 128,
                     o_soWih1, 512l * 128, 524288, o_soWhh1, 512l * 128, 524288,
                     sobih1, 512, sobhh1, 512, nullptr, 0, 0, 512, 16, A_,
                     cmso, tokS, feat, 1, 384);
    GDesc sc0  = mkd(feat, (long)B_ * 1664, 1664, 384, hmsc, (long)B_ * 128, 128, 128,
                     o_scWih0, 512l * 384, 1572864, o_scWhh0, 512l * 128, 524288,
                     scbih0, 512, scbhh0, 512, nullptr, 0, 0, 512, 16, A_,
                     cmsc, tokC, nullptr, 0, 0);
    GDesc sc1  = mkd(tokC, (long)B_ * 512, 512, 128, hmsc + 2097152, (long)B_ * 128, 128, 128,
                     o_scWih1, 512l * 128, 524288, o_scWhh1, 512l * 128, 524288,
                     scbih1, 512, scbhh1, 512, nullptr, 0, 0, 512, 16, A_,
                     cmsc, tokC, feat, 1, 1024);
    GDesc fc0d = mkd(feat, 0, 1664, 1664, nullptr, 0, 0, 0,
                     o_fcw0, 0, 425984, 0, 0, 0, fcb0, 0, nullptr, 0,
                     x1, 0, 256, 256, 1 | 2, 1, nullptr, nullptr, nullptr, 0, 0);
    GDesc fc1d = mkd(x1, 0, 256, 256, nullptr, 0, 0, 0,
                     o_fcw1, 0, 65536, 0, 0, 0, fcb1, 0, nullptr, 0,
                     x2, 0, 256, 256, 1 | 2, 1, nullptr, nullptr, nullptr, 0, 0);
    GDesc actd = mkd(x2, 0, 256, 256, nullptr, 0, 0, 0,
                     o_actw, 0, 32768, 0, 0, 0, actb, 0, nullptr, 0,
                     logits, 0, ACT_, ACT_, 0, 1, nullptr, nullptr, nullptr, 0, 0);

    // ---------- schedule ----------
    mgemm1<<<grid_of(gat0, 16384), 256, 0, stream>>>(gat0);
    gat_reduce_k<<<B_, 256, 0, stream>>>(xlr, gatt0, gbias0, feat, 128);
    mgemm1<<<grid_of(gat1, 16384), 256, 0, stream>>>(gat1);
    gat_reduce_k<<<B_, 256, 0, stream>>>(xlr, gatt1, gbias1, feat, 256);

    // gates (tokS then tokC; chains independent)
    mgemm1<<<grid_of(so0, B_), 256, 0, stream>>>(so0);
    mgemm1<<<grid_of(so1, B_), 256, 0, stream>>>(so1);
    mgemm1<<<grid_of(sc0, B_), 256, 0, stream>>>(sc0);
    mgemm1<<<grid_of(sc1, B_), 256, 0, stream>>>(sc1);

    // both chains' qkv+attn+outproj in ONE launch, 8-wave blocks, fragment-direct W
    sattn_k<<<2048, 512, 0, stream>>>(tokS, tokC,
                                      wb + o_soqw, wb + o_scqw, 393216, soqb, scqb,
                                      wb + o_soow, wb + o_scow, 131072, soob, scob,
                                      feat);

    mgemm1<<<grid_of(fc0d, 16384), 256, 0, stream>>>(fc0d);
    mgemm1<<<grid_of(fc1d, 16384), 256, 0, stream>>>(fc1d);
    mgemm1<<<grid_of(actd, 16384), 256, 0, stream>>>(actd);
    lsm_k<<<A_ * B_ / 256, 256, 0, stream>>>(logits, (float*)d_out);
}

// Round 21
// 413.383 us; speedup vs baseline: 1.0607x; 1.0607x over previous
//
#include <hip/hip_runtime.h>
#include <math.h>

#define B_ 2048
#define A_ 8
#define ACT_ 14
#define FP_ 27262976l   // feat stride (16384*1664), single bf16 plane

typedef short short8 __attribute__((ext_vector_type(8)));
typedef float floatx4 __attribute__((ext_vector_type(4)));
typedef unsigned short u16x4 __attribute__((ext_vector_type(4)));

__device__ __forceinline__ unsigned short f2b(float f) {
    unsigned u = __float_as_uint(f);
    u += 0x7fff + ((u >> 16) & 1);
    return (unsigned short)(u >> 16);
}
__device__ __forceinline__ float b2f(unsigned short h) {
    return __uint_as_float(((unsigned)h) << 16);
}
__device__ __forceinline__ float sigm_(float x) { return 1.0f / (1.0f + expf(-x)); }

// ===== bf16 MFMA GEMM: (MI*64)x64 tiles, exact hi/lo weights (Xh·Wh + Xh·Wl),
// ===== single-bf16 activations, ping-pong LDS (1 barrier/chunk), depth-4 reg prefetch.
// flags: 1=relu, 2=bf16 out, 4=token-fold rows, 8=split bias at col 512,
//        16=LSTM epilogue (W gate-permuted at cast; writes tok/feat, skips Y).
struct GDesc {
    const unsigned short *X1, *X2, *W1, *W2;
    const float *b1, *b2;
    void* Y;
    const unsigned short* cms;       // masked bf16 c-state [l][a][b][j]
    unsigned short* tokp;
    unsigned short* featp;
    long xsa1, xsa2, wsa1, wps1, wsa2, wps2, bsa1, bsa2, ysa;
    int ldx1, K1, ldx2, K2, ldy, N, flags, nA, Nb, layer, foff;
};

#define LOADC(c, xh, whv, wlv) do {                                                       \
    const unsigned short *Xb_, *Wb_; int ldx_, K_, k0_; long wps_;                        \
    if ((c) < nC1) { Xb_ = X1; ldx_ = ldx1; K_ = K1; wps_ = wps1; Wb_ = W1; k0_ = (c) << 5; } \
    else { Xb_ = X2; ldx_ = ldx2; K_ = K2; wps_ = wps2; Wb_ = W2; k0_ = ((c) - nC1) << 5; } \
    _Pragma("unroll") for (int mi_ = 0; mi_ < MI; ++mi_) {                                \
        int row_ = xr0 + mi_ * 16 + lrow;                                                 \
        xh[mi_] = *(const short8*)(Xb_ + (long)(bm + row_) * ldx_ + k0_ + lslot * 8); }   \
    { int row_ = wr0 + lrow;                                                              \
      const unsigned short* wp_ = Wb_ + (long)(bn + row_) * K_ + k0_ + lslot * 8;         \
      whv = *(const short8*)wp_; wlv = *(const short8*)(wp_ + wps_); }                    \
} while (0)

#define STOREC(P, xh, whv, wlv) do {                                                      \
    _Pragma("unroll") for (int mi_ = 0; mi_ < MI; ++mi_) {                                \
        int row_ = xr0 + mi_ * 16 + lrow; int sl_ = lslot ^ ((row_ >> 1) & 3);            \
        *(short8*)&Xh_l[P][row_ * 32 + sl_ * 8] = xh[mi_]; }                              \
    { int row_ = wr0 + lrow; int sl_ = lslot ^ ((row_ >> 1) & 3);                         \
      *(short8*)&Wh_l[P][row_ * 32 + sl_ * 8] = whv;                                      \
      *(short8*)&Wl_l[P][row_ * 32 + sl_ * 8] = wlv; }                                    \
} while (0)

#define COMPUTEC(P) do {                                                                  \
    short8 bh[4], bl[4];                                                                  \
    _Pragma("unroll") for (int ni = 0; ni < 4; ++ni) {                                    \
        int row_ = ni * 16 + lr; int off_ = row_ * 32 + ((lk ^ ((row_ >> 1) & 3)) * 8);   \
        bh[ni] = *(const short8*)&Wh_l[P][off_]; bl[ni] = *(const short8*)&Wl_l[P][off_]; } \
    _Pragma("unroll") for (int mi = 0; mi < MI; ++mi) {                                   \
        int row_ = xr0 + mi * 16 + lr; int off_ = row_ * 32 + ((lk ^ ((row_ >> 1) & 3)) * 8); \
        short8 ah = *(const short8*)&Xh_l[P][off_];                                       \
        _Pragma("unroll") for (int ni = 0; ni < 4; ++ni)                                  \
            acc[mi][ni] = __builtin_amdgcn_mfma_f32_16x16x32_bf16(ah, bh[ni], acc[mi][ni], 0, 0, 0); \
        _Pragma("unroll") for (int ni = 0; ni < 4; ++ni)                                  \
            acc[mi][ni] = __builtin_amdgcn_mfma_f32_16x16x32_bf16(ah, bl[ni], acc[mi][ni], 0, 0, 0); \
    }                                                                                     \
} while (0)

template<int MI>
__launch_bounds__(256)
__global__ void mgemm_t(GDesc d)
{
    __shared__ __align__(16) unsigned short Xh_l[2][MI * 64 * 32];
    __shared__ __align__(16) unsigned short Wh_l[2][64 * 32];
    __shared__ __align__(16) unsigned short Wl_l[2][64 * 32];

    const int wg = blockIdx.x;
    const unsigned short* X1 = d.X1; const unsigned short* X2 = d.X2;
    const unsigned short* W1 = d.W1; const unsigned short* W2 = d.W2;
    const float* b1 = d.b1; const float* b2 = d.b2;
    const long wps1 = d.wps1, wps2 = d.wps2, ysa = d.ysa;
    const int ldx1 = d.ldx1, K1 = d.K1, ldx2 = d.ldx2, K2 = d.K2;
    const int ldy = d.ldy, N = d.N, flags = d.flags, nA = d.nA, Nb = d.Nb;
    const int layer = d.layer, foff = d.foff;

    int a, mb, nb;
    if (nA == 8) { a = wg & 7; int q = wg >> 3; nb = q % Nb; mb = q / Nb; }
    else { a = 0; int x8 = wg & 7; int q = wg >> 3; nb = q % Nb; mb = (q / Nb) * 8 + x8; }

    X1 += (long)a * d.xsa1;
    W1 += (long)a * d.wsa1;
    if (X2) { X2 += (long)a * d.xsa2; W2 += (long)a * d.wsa2; }
    if (b1) b1 += (long)a * d.bsa1;
    if (b2) b2 += (long)a * d.bsa2;

    const int bm = mb * (MI * 64);
    const int bn = nb * 64;
    const int t = threadIdx.x;
    const int lane = t & 63, wid = t >> 6;

    floatx4 acc[MI][4] = {};

    const int xr0 = wid * (MI * 16);
    const int wr0 = wid * 16;
    const int lrow = lane >> 2;
    const int lslot = lane & 3;
    const int lr = lane & 15, lk = lane >> 4;

    const int nC1 = K1 >> 5;
    const int nC = nC1 + (X2 ? (K2 >> 5) : 0);

    short8 Axh[MI], Awh, Awl;
    short8 Bxh[MI], Bwh, Bwl;
    short8 Cxh[MI], Cwh, Cwl;
    short8 Dxh[MI], Dwh, Dwl;

    LOADC(0, Axh, Awh, Awl);
    if (nC > 1) LOADC(1, Bxh, Bwh, Bwl);
    if (nC > 2) LOADC(2, Cxh, Cwh, Cwl);
    if (nC > 3) LOADC(3, Dxh, Dwh, Dwl);

    for (int c = 0; c < nC; c += 4) {
        STOREC(0, Axh, Awh, Awl);
        __syncthreads();
        if (c + 4 < nC) LOADC(c + 4, Axh, Awh, Awl);
        COMPUTEC(0);
        if (c + 1 < nC) {
            STOREC(1, Bxh, Bwh, Bwl);
            __syncthreads();
            if (c + 5 < nC) LOADC(c + 5, Bxh, Bwh, Bwl);
            COMPUTEC(1);
        }
        if (c + 2 < nC) {
            STOREC(0, Cxh, Cwh, Cwl);
            __syncthreads();
            if (c + 6 < nC) LOADC(c + 6, Cxh, Cwh, Cwl);
            COMPUTEC(0);
        }
        if (c + 3 < nC) {
            STOREC(1, Dxh, Dwh, Dwl);
            __syncthreads();
            if (c + 7 < nC) LOADC(c + 7, Dxh, Dwh, Dwl);
            COMPUTEC(1);
        }
    }

    const int lg = lane >> 4;

    if (flags & 16) {
        // fused LSTM pointwise epilogue (W rows gate-permuted at cast); j = nb*16 + lr
        const int j = (bn >> 2) + lr;
        unsigned short* tokp = d.tokp;
        unsigned short* featp = d.featp;
        const unsigned short* cms = d.cms;
#pragma unroll
        for (int mi = 0; mi < MI; ++mi) {
#pragma unroll
            for (int r = 0; r < 4; ++r) {
                const int b = bm + xr0 + mi * 16 + lg * 4 + r;
                float iv = acc[mi][0][r] + b1[j]       + b2[j];
                float fv = acc[mi][1][r] + b1[128 + j] + b2[128 + j];
                float gv = acc[mi][2][r] + b1[256 + j] + b2[256 + j];
                float ov = acc[mi][3][r] + b1[384 + j] + b2[384 + j];
                iv = sigm_(iv); fv = sigm_(fv); gv = tanhf(gv); ov = sigm_(ov);
                float cp = b2f(cms[(long)layer * 2097152 + (long)a * 262144 + b * 128 + j]);
                float c2 = fv * cp + iv * gv;
                float hv = ov * tanhf(c2);
                long tb = ((long)a * B_ + b) * 512;
                tokp[tb + layer * 128 + j] = f2b(hv);
                tokp[tb + (2 + layer) * 128 + j] = f2b(c2);
                if (featp) featp[((long)a * B_ + b) * 1664 + foff + j] = f2b(hv);
            }
        }
        return;
    }

    const bool relu = flags & 1, obf = flags & 2, fold = flags & 4, sbias = flags & 8;
    float* Yf = (float*)d.Y;
    unsigned short* Yh = (unsigned short*)d.Y;
#pragma unroll
    for (int mi = 0; mi < MI; ++mi) {
#pragma unroll
        for (int r = 0; r < 4; ++r) {
            int gm = bm + xr0 + mi * 16 + lg * 4 + r;
            long rowoff = fold ? ((long)(gm >> 2) * ldy + (gm & 3) * 128) : (long)gm * ldy;
            rowoff += (long)a * ysa;
#pragma unroll
            for (int ni = 0; ni < 4; ++ni) {
                int gc = bn + ni * 16 + lr;
                if (gc < N) {
                    float v = acc[mi][ni][r];
                    if (sbias) v += (gc < 512) ? b1[gc] : b2[gc - 512];
                    else { if (b1) v += b1[gc]; if (b2) v += b2[gc]; }
                    if (relu) v = fmaxf(v, 0.f);
                    if (obf) Yh[rowoff + gc] = f2b(v);
                    else     Yf[rowoff + gc] = v;
                }
            }
        }
    }
}

// ===== fused qkv-GEMM + 4-token MHA + out-proj, BOTH chains, 512 thr (8 waves) =====
// v3 (round-19 proven, 82 us): W chunks staged via LDS with register prefetch, out-proj
// chunk0 prefetched under the attention phase, attention over all 512 threads.
__launch_bounds__(512)
__global__ void sattn_k(const unsigned short* __restrict__ tokS,
                        const unsigned short* __restrict__ tokC,
                        const unsigned short* __restrict__ WqS,
                        const unsigned short* __restrict__ WqC, long qlo,
                        const float* __restrict__ qbS, const float* __restrict__ qbC,
                        const unsigned short* __restrict__ WoS,
                        const unsigned short* __restrict__ WoC, long olo,
                        const float* __restrict__ obS, const float* __restrict__ obC,
                        unsigned short* __restrict__ feat)
{
    __shared__ __align__(16) unsigned short Xs[64 * 128];    // tok tile -> attn_o (reused)
    __shared__ __align__(16) unsigned short BufW[25600];     // W chunks -> Q[64][392]
    __shared__ float qbias[384];
    __shared__ float obias[128];

    int bid = blockIdx.x;
    const unsigned short* tok; const unsigned short* Wq; const float* qb;
    const unsigned short* Wo; const float* ob; int foff;
    if (bid < 1024) { tok = tokS; Wq = WqS; qb = qbS; Wo = WoS; ob = obS; foff = 512; }
    else { bid -= 1024; tok = tokC; Wq = WqC; qb = qbC; Wo = WoC; ob = obC; foff = 1152; }

    const int a = bid & 7;               // agent-per-XCD
    const int g = bid >> 3;              // 0..127
    const int b0 = g * 16;

    const unsigned short* Wqa = Wq + (long)a * 49152;
    const unsigned short* Woa = Wo + (long)a * 16384;
    const unsigned short* tokb = tok + ((long)a * B_ + b0) * 512;

    const int t = threadIdx.x;
    const int lane = t & 63, wid = t >> 6;          // wid 0..7
    const int lr = lane & 15, lk = lane >> 4, lg = lane >> 4;

    // ---- per-thread W slot geometry (qkv: 6 slots of 3072; outproj: 2 of 1024) ----
    int qwr[6], qws[6], qwp[6];
#pragma unroll
    for (int j = 0; j < 6; ++j) {
        int idx = t + j * 512;
        int pl = idx >= 1536;
        int rem = idx - (pl ? 1536 : 0);
        qwr[j] = rem >> 2; qws[j] = rem & 3; qwp[j] = pl;
    }
    int owr[2], ows[2], owp[2];
#pragma unroll
    for (int j = 0; j < 2; ++j) {
        int idx = t + j * 512;
        int pl = idx >> 9;
        int rem = idx & 511;
        owr[j] = rem >> 2; ows[j] = rem & 3; owp[j] = pl;
    }

    // ---- stage X (64x128, slot-swizzled s^(r&7)) + biases ----
    for (int idx = t; idx < 1024; idx += 512) {
        int r = idx >> 4, s = idx & 15;
        *(short8*)&Xs[r * 128 + (s ^ (r & 7)) * 8] = *(const short8*)(tokb + r * 128 + s * 8);
    }
    if (t < 384) qbias[t] = qb[a * 384 + t];
    if (t < 128) obias[t] = ob[a * 128 + t];

    unsigned short* Wh = BufW;             // [384][32]
    unsigned short* Wl = BufW + 12800;     // [384][32]

    short8 pw[6];
#pragma unroll
    for (int j = 0; j < 6; ++j)
        pw[j] = *(const short8*)(Wqa + (qwp[j] ? qlo : 0) + qwr[j] * 128 + qws[j] * 8);

    floatx4 acc[4][3] = {};                // m-frag 0..3 (rows), n-frag 0..2 (cols wid*48+)

    for (int kc = 0; kc < 4; ++kc) {
        const int k0 = kc * 32;
        if (kc) __syncthreads();           // prior chunk LDS reads done
#pragma unroll
        for (int j = 0; j < 6; ++j) {
            unsigned short* dst = (qwp[j] ? Wl : Wh) + qwr[j] * 32 + ((qws[j] ^ ((qwr[j] >> 1) & 3)) * 8);
            *(short8*)dst = pw[j];
        }
        __syncthreads();                   // X (first iter) + W writes visible
        if (kc < 3) {
            const int k1 = k0 + 32;
#pragma unroll
            for (int j = 0; j < 6; ++j)
                pw[j] = *(const short8*)(Wqa + (qwp[j] ? qlo : 0) + qwr[j] * 128 + k1 + qws[j] * 8);
        }
        short8 af[4];
#pragma unroll
        for (int mi = 0; mi < 4; ++mi) {
            int row = mi * 16 + lr;
            int sl = ((k0 >> 3) + lk) ^ (row & 7);
            af[mi] = *(const short8*)&Xs[row * 128 + sl * 8];
        }
#pragma unroll
        for (int ni = 0; ni < 3; ++ni) {
            int nrow = wid * 48 + ni * 16 + lr;
            int off = nrow * 32 + ((lk ^ ((nrow >> 1) & 3)) * 8);
            short8 bh = *(const short8*)&Wh[off];
            short8 bl = *(const short8*)&Wl[off];
#pragma unroll
            for (int mi = 0; mi < 4; ++mi) {
                acc[mi][ni] = __builtin_amdgcn_mfma_f32_16x16x32_bf16(af[mi], bh, acc[mi][ni], 0, 0, 0);
                acc[mi][ni] = __builtin_amdgcn_mfma_f32_16x16x32_bf16(af[mi], bl, acc[mi][ni], 0, 0, 0);
            }
        }
    }
    __syncthreads();                       // all W reads done; BufW -> Q

    // ---- write qkv (bf16 + bias) to Q[64][392] ----
    unsigned short* Q = BufW;
#pragma unroll
    for (int mi = 0; mi < 4; ++mi)
#pragma unroll
        for (int ni = 0; ni < 3; ++ni)
#pragma unroll
            for (int rr = 0; rr < 4; ++rr) {
                int row = mi * 16 + lg * 4 + rr;
                int col = wid * 48 + ni * 16 + lr;
                Q[row * 392 + col] = f2b(acc[mi][ni][rr] + qbias[col]);
            }
    __syncthreads();                       // Q visible

    // ---- prefetch out-proj W chunk 0 (hides under attention VALU) ----
    short8 po[2];
#pragma unroll
    for (int j = 0; j < 2; ++j)
        po[j] = *(const short8*)(Woa + (owp[j] ? olo : 0) + owr[j] * 128 + ows[j] * 8);

    // ---- attention: 2 threads per (sample, tq, h4); each half of PV output ----
    float oa[16];
    int qr, h4, hf;
    {
        int tt = t & 255;
        h4 = tt & 3; int tq = (tt >> 2) & 3, s = tt >> 4;
        hf = t >> 8;                       // 0 or 1: output half
        qr = s * 4 + tq;
        const unsigned short* qp = Q + qr * 392 + h4 * 32;
        float q[32];
#pragma unroll
        for (int r = 0; r < 8; ++r) {
            u16x4 v = *(const u16x4*)(qp + r * 4);
#pragma unroll
            for (int w = 0; w < 4; ++w) q[r * 4 + w] = b2f(v[w]);
        }
        float sv[4];
#pragma unroll
        for (int u = 0; u < 4; ++u) {
            const unsigned short* kp = Q + (s * 4 + u) * 392 + 128 + h4 * 32;
            float dd = 0.f;
#pragma unroll
            for (int r = 0; r < 8; ++r) {
                u16x4 v = *(const u16x4*)(kp + r * 4);
#pragma unroll
                for (int w = 0; w < 4; ++w) dd += q[r * 4 + w] * b2f(v[w]);
            }
            sv[u] = dd * 0.176776695296637f;
        }
        float mx = fmaxf(fmaxf(sv[0], sv[1]), fmaxf(sv[2], sv[3]));
        float e0 = expf(sv[0] - mx), e1 = expf(sv[1] - mx), e2 = expf(sv[2] - mx), e3 = expf(sv[3] - mx);
        float inv = 1.0f / (e0 + e1 + e2 + e3);
        float al[4] = { e0 * inv, e1 * inv, e2 * inv, e3 * inv };
#pragma unroll
        for (int w = 0; w < 16; ++w) oa[w] = 0.f;
#pragma unroll
        for (int u = 0; u < 4; ++u) {
            const unsigned short* vp = Q + (s * 4 + u) * 392 + 256 + h4 * 32 + hf * 16;
            float wgt = al[u];
#pragma unroll
            for (int r = 0; r < 4; ++r) {
                u16x4 v = *(const u16x4*)(vp + r * 4);
#pragma unroll
                for (int w = 0; w < 4; ++w) oa[r * 4 + w] += wgt * b2f(v[w]);
            }
        }
    }
    __syncthreads();                       // all Q reads done
    {                                      // write attn_o half into Xs (swizzled)
#pragma unroll
        for (int p = 0; p < 2; ++p) {
            short8 v;
#pragma unroll
            for (int w = 0; w < 8; ++w) v[w] = (short)f2b(oa[p * 8 + w]);
            int slot = h4 * 4 + hf * 2 + p;
            *(short8*)&Xs[qr * 128 + (slot ^ (qr & 7)) * 8] = v;
        }
    }

    // ---- out-proj: M=64, N=128 (wave owns 16 cols), K=128; reg-prefetched W ----
    unsigned short* Wh2 = BufW;            // [128][32]
    unsigned short* Wl2 = BufW + 4096;
    floatx4 acc2[4] = {};                  // m-frag 0..3, col block wid*16

    for (int kc = 0; kc < 4; ++kc) {
        const int k0 = kc * 32;
        __syncthreads();                   // prior reads done (incl. attn Xs writes visible)
#pragma unroll
        for (int j = 0; j < 2; ++j) {
            unsigned short* dst = (owp[j] ? Wl2 : Wh2) + owr[j] * 32 + ((ows[j] ^ ((owr[j] >> 1) & 3)) * 8);
            *(short8*)dst = po[j];
        }
        __syncthreads();
        if (kc < 3) {
            const int k1 = k0 + 32;
#pragma unroll
            for (int j = 0; j < 2; ++j)
                po[j] = *(const short8*)(Woa + (owp[j] ? olo : 0) + owr[j] * 128 + k1 + ows[j] * 8);
        }
        short8 af[4];
#pragma unroll
        for (int mi = 0; mi < 4; ++mi) {
            int row = mi * 16 + lr;
            int sl = ((k0 >> 3) + lk) ^ (row & 7);
            af[mi] = *(const short8*)&Xs[row * 128 + sl * 8];
        }
        {
            int nrow = wid * 16 + lr;
            int off = nrow * 32 + ((lk ^ ((nrow >> 1) & 3)) * 8);
            short8 bh = *(const short8*)&Wh2[off];
            short8 bl = *(const short8*)&Wl2[off];
#pragma unroll
            for (int mi = 0; mi < 4; ++mi) {
                acc2[mi] = __builtin_amdgcn_mfma_f32_16x16x32_bf16(af[mi], bh, acc2[mi], 0, 0, 0);
                acc2[mi] = __builtin_amdgcn_mfma_f32_16x16x32_bf16(af[mi], bl, acc2[mi], 0, 0, 0);
            }
        }
    }

    // ---- epilogue: token-folded feat write ----
#pragma unroll
    for (int mi = 0; mi < 4; ++mi)
#pragma unroll
        for (int rr = 0; rr < 4; ++rr) {
            int row = mi * 16 + lg * 4 + rr;
            int s2 = row >> 2, tq2 = row & 3;
            long base = ((long)a * B_ + b0 + s2) * 1664 + foff + tq2 * 128;
            int col = wid * 16 + lr;
            feat[base + col] = f2b(acc2[mi][rr] + obias[col]);
        }
}

// ===== weight cast (f32 -> bf16 hi + lo planes; optional LSTM gate permute) =====
#define NW 19
struct WTab {
    const float* src[NW];
    long hoff[NW];
    long loff[NW];
    int n[NW];
    int npad[NW];
    int kc[NW];
};
__global__ void wcast_k(WTab tab, unsigned short* __restrict__ wb)
{
    const int e = blockIdx.y;
    const int np = tab.npad[e];
    const float* s = tab.src[e];
    unsigned short* dh = wb + tab.hoff[e];
    unsigned short* dl = wb + tab.loff[e];
    const int n = tab.n[e];
    const int kc = tab.kc[e];
    for (long i = (long)blockIdx.x * 256 + threadIdx.x; i < np; i += (long)gridDim.x * 256) {
        long si = i;
        if (kc) {
            long per = 512l * kc;
            long ag = i / per;
            long rem = i - ag * per;
            int rp = (int)(rem / kc);
            int k = (int)(rem - (long)rp * kc);
            int srcr = (((rp & 63) >> 4) << 7) + ((rp >> 6) << 4) + (rp & 15);
            si = ag * per + (long)srcr * kc + k;
        }
        float v = (si < n) ? s[si] : 0.f;
        unsigned short h = f2b(v);
        dh[i] = h;
        dl[i] = f2b(v - b2f(h));
    }
}

// ===== prep: obs -> feat[:,0:128]; masked h/c states -> bf16 =====
__global__ void prep_k(const float* __restrict__ obs, const float* __restrict__ soh,
                       const float* __restrict__ sch, const float* __restrict__ soc,
                       const float* __restrict__ scc, const float* __restrict__ masks,
                       unsigned short* __restrict__ feat,
                       unsigned short* __restrict__ hmso, unsigned short* __restrict__ hmsc,
                       unsigned short* __restrict__ cmso, unsigned short* __restrict__ cmsc)
{
    long tid = (long)blockIdx.x * 256 + threadIdx.x;
    if (tid < 2097152) {
        int j = (int)(tid & 127);
        int row = (int)(tid >> 7);
        int b = row >> 3, aa = row & 7;
        feat[((long)aa * B_ + b) * 1664 + j] = f2b(obs[tid]);
        return;
    }
    long u = tid - 2097152;
    const float* src;
    unsigned short* dst;
    if (u < 4194304) { src = soh; dst = hmso; }
    else if (u < 2 * 4194304) { u -= 4194304; src = sch; dst = hmsc; }
    else if (u < 3 * 4194304) { u -= 2 * 4194304; src = soc; dst = cmso; }
    else { u -= 3 * 4194304; src = scc; dst = cmsc; }
    int j = (int)(u & 127);
    int b = (int)((u >> 7) & 2047);
    int aa = (int)((u >> 18) & 7);
    int l = (int)(u >> 21);
    float m = masks[b * 8 + aa];
    dst[u] = f2b(src[((long)(b * 8 + aa)) * 256 + l * 128 + j] * m);
}

// ===== GATv2 reduce (xlr combined [row][1024]: xl | xr) =====
__launch_bounds__(256)
__global__ void gat_reduce_k(const unsigned short* __restrict__ xlr,
                             const float* __restrict__ att, const float* __restrict__ bias,
                             unsigned short* __restrict__ feat, int coloff)
{
    __shared__ float xls[8][512];
    __shared__ float xrs[8][512];
    __shared__ float atts[512];
    __shared__ float es[8][8][4];
    __shared__ float as_[8][8][4];

    const int b = blockIdx.x;
    const int t = threadIdx.x;

    for (int i = t; i < 1024; i += 256) {
        int j = i >> 7, c4 = (i & 127) * 4;
        const unsigned short* base = xlr + ((long)j * B_ + b) * 1024;
        u16x4 vl = *(const u16x4*)(base + c4);
        u16x4 vr = *(const u16x4*)(base + 512 + c4);
#pragma unroll
        for (int q = 0; q < 4; ++q) {
            xls[j][c4 + q] = b2f(vl[q]);
            xrs[j][c4 + q] = b2f(vr[q]);
        }
    }
    for (int i = t; i < 128; i += 256)
        reinterpret_cast<float4*>(atts)[i] = reinterpret_cast<const float4*>(att)[i];
    __syncthreads();

    const int i = t >> 5, j = (t >> 2) & 7, h = t & 3;
    float e = 0.f;
    for (int cc = 0; cc < 128; ++cc) {
        int c = (cc + t) & 127;
        float s = xls[j][h * 128 + c] + xrs[i][h * 128 + c];
        s = s > 0.f ? s : 0.2f * s;
        e += s * atts[h * 128 + c];
    }
    es[i][j][h] = e;
    __syncthreads();

    float mx = -1e30f;
    for (int jj = 0; jj < 8; ++jj) mx = fmaxf(mx, es[i][jj][h]);
    float sum = 0.f;
    for (int jj = 0; jj < 8; ++jj) sum += expf(es[i][jj][h] - mx);
    as_[i][j][h] = expf(e - mx) / sum;
    __syncthreads();

    for (int idx = t; idx < 1024; idx += 256) {
        int ii = idx >> 7, c = idx & 127;
        float s = 0.f;
        for (int jj = 0; jj < 8; ++jj)
#pragma unroll
            for (int hh = 0; hh < 4; ++hh)
                s += as_[ii][jj][hh] * xls[jj][hh * 128 + c];
        s = s * 0.25f + bias[c];
        s = fmaxf(s, 0.f);
        feat[((long)ii * B_ + b) * 1664 + coloff + c] = f2b(s);
    }
}

// ===== log_softmax + transpose [A][B][14] -> (B,A,14) =====
__global__ void lsm_k(const float* __restrict__ logits, float* __restrict__ out)
{
    int tid = blockIdx.x * 256 + threadIdx.x;    // A*B
    int b = tid & (B_ - 1);
    int a = tid >> 11;
    const float* lp = logits + ((long)a * B_ + b) * ACT_;
    float x[ACT_];
    float mx = -1e30f;
#pragma unroll
    for (int n = 0; n < ACT_; ++n) { x[n] = lp[n]; mx = fmaxf(mx, x[n]); }
    float sum = 0.f;
#pragma unroll
    for (int n = 0; n < ACT_; ++n) sum += expf(x[n] - mx);
    float ls = mx + logf(sum);
    float* op = out + ((long)b * A_ + a) * ACT_;
#pragma unroll
    for (int n = 0; n < ACT_; ++n) op[n] = x[n] - ls;
}

extern "C" void kernel_launch(void* const* d_in, const int* in_sizes, int n_in,
                              void* d_out, int out_size, void* d_ws, size_t ws_size,
                              hipStream_t stream)
{
    const float* obs    = (const float*)d_in[0];
    const float* somu_h = (const float*)d_in[1];
    const float* somu_c = (const float*)d_in[2];
    const float* scmu_h = (const float*)d_in[3];
    const float* scmu_c = (const float*)d_in[4];
    const float* masks  = (const float*)d_in[5];
    const float* gWl0 = (const float*)d_in[6],  *gbl0 = (const float*)d_in[7];
    const float* gWr0 = (const float*)d_in[8],  *gbr0 = (const float*)d_in[9];
    const float* gatt0 = (const float*)d_in[10], *gbias0 = (const float*)d_in[11];
    const float* gWl1 = (const float*)d_in[12], *gbl1 = (const float*)d_in[13];
    const float* gWr1 = (const float*)d_in[14], *gbr1 = (const float*)d_in[15];
    const float* gatt1 = (const float*)d_in[16], *gbias1 = (const float*)d_in[17];
    const float* soWih0 = (const float*)d_in[18], *soWhh0 = (const float*)d_in[19];
    const float* sobih0 = (const float*)d_in[20], *sobhh0 = (const float*)d_in[21];
    const float* soWih1 = (const float*)d_in[22], *soWhh1 = (const float*)d_in[23];
    const float* sobih1 = (const float*)d_in[24], *sobhh1 = (const float*)d_in[25];
    const float* soqw = (const float*)d_in[26], *soqb = (const float*)d_in[27];
    const float* soow = (const float*)d_in[28], *soob = (const float*)d_in[29];
    const float* scWih0 = (const float*)d_in[30], *scWhh0 = (const float*)d_in[31];
    const float* scbih0 = (const float*)d_in[32], *scbhh0 = (const float*)d_in[33];
    const float* scWih1 = (const float*)d_in[34], *scWhh1 = (const float*)d_in[35];
    const float* scbih1 = (const float*)d_in[36], *scbhh1 = (const float*)d_in[37];
    const float* scqw = (const float*)d_in[38], *scqb = (const float*)d_in[39];
    const float* scow = (const float*)d_in[40], *scob = (const float*)d_in[41];
    const float* fcw0 = (const float*)d_in[42], *fcb0 = (const float*)d_in[43];
    const float* fcw1 = (const float*)d_in[44], *fcb1 = (const float*)d_in[45];
    const float* actw = (const float*)d_in[46], *actb = (const float*)d_in[47];

    // ---------- workspace layout (~200 MB) ----------
    unsigned short* wb = (unsigned short*)d_ws;
    long wo = 0;
    auto nxt = [&](long n) { long c = wo; wo += n; return c; };
    const long o_gW0 = nxt(262144), o_gW1 = nxt(262144);
    const long o_soWih0 = nxt(2 * 524288), o_soWhh0 = nxt(2 * 524288);
    const long o_soWih1 = nxt(2 * 524288), o_soWhh1 = nxt(2 * 524288);
    const long o_soqw = nxt(2 * 393216), o_soow = nxt(2 * 131072);
    const long o_scWih0 = nxt(2 * 1572864), o_scWhh0 = nxt(2 * 524288);
    const long o_scWih1 = nxt(2 * 524288), o_scWhh1 = nxt(2 * 524288);
    const long o_scqw = nxt(2 * 393216), o_scow = nxt(2 * 131072);
    const long o_fcw0 = nxt(2 * 425984), o_fcw1 = nxt(2 * 65536);
    const long o_actw = nxt(2 * 32768);                         // weights end: 14,155,776

    unsigned short* feat   = wb + nxt(FP_);            // single plane
    unsigned short* hmso   = wb + nxt(4194304);
    unsigned short* hmsc   = wb + nxt(4194304);
    unsigned short* cmso   = wb + nxt(4194304);
    unsigned short* cmsc   = wb + nxt(4194304);
    unsigned short* arenaA = wb + nxt(25165824);       // xlr | x1,x2,logits
    unsigned short* arenaB = wb + nxt(16777216);       // tokS, tokC
    // total ≈ 100.1M shorts = 200 MB

    unsigned short* xlr    = arenaA;                   // GAT phase [16384][1024]
    unsigned short* tokS   = arenaB;                   // [A][B][4][128]
    unsigned short* tokC   = arenaB + 8388608;
    unsigned short* x1     = arenaA;                   // head phase (single plane)
    unsigned short* x2     = arenaA + 4194304;
    float*          logits = (float*)(arenaA + 8388608);

    // ---------- weight cast ----------
    WTab tab;
    int ei = 0;
    auto ent = [&](const float* s, long hoff, long loff, int n, int npad, int kc) {
        tab.src[ei] = s; tab.hoff[ei] = hoff; tab.loff[ei] = loff;
        tab.n[ei] = n; tab.npad[ei] = npad; tab.kc[ei] = kc; ++ei;
    };
    ent(gWl0, o_gW0,          o_gW0 + 131072,          65536, 65536, 0);
    ent(gWr0, o_gW0 + 65536,  o_gW0 + 196608,          65536, 65536, 0);
    ent(gWl1, o_gW1,          o_gW1 + 131072,          65536, 65536, 0);
    ent(gWr1, o_gW1 + 65536,  o_gW1 + 196608,          65536, 65536, 0);
    ent(soWih0, o_soWih0, o_soWih0 + 524288, 524288, 524288, 128);
    ent(soWhh0, o_soWhh0, o_soWhh0 + 524288, 524288, 524288, 128);
    ent(soWih1, o_soWih1, o_soWih1 + 524288, 524288, 524288, 128);
    ent(soWhh1, o_soWhh1, o_soWhh1 + 524288, 524288, 524288, 128);
    ent(soqw, o_soqw, o_soqw + 393216, 393216, 393216, 0);
    ent(soow, o_soow, o_soow + 131072, 131072, 131072, 0);
    ent(scWih0, o_scWih0, o_scWih0 + 1572864, 1572864, 1572864, 384);
    ent(scWhh0, o_scWhh0, o_scWhh0 + 524288, 524288, 524288, 128);
    ent(scWih1, o_scWih1, o_scWih1 + 524288, 524288, 524288, 128);
    ent(scWhh1, o_scWhh1, o_scWhh1 + 524288, 524288, 524288, 128);
    ent(scqw, o_scqw, o_scqw + 393216, 393216, 393216, 0);
    ent(scow, o_scow, o_scow + 131072, 131072, 131072, 0);
    ent(fcw0, o_fcw0, o_fcw0 + 425984, 425984, 425984, 0);
    ent(fcw1, o_fcw1, o_fcw1 + 65536, 65536, 65536, 0);
    ent(actw, o_actw, o_actw + 32768, 3584, 32768, 0);
    wcast_k<<<dim3(1024, NW), 256, 0, stream>>>(tab, wb);

    prep_k<<<(2097152 + 4 * 4194304) / 256, 256, 0, stream>>>(
        obs, somu_h, scmu_h, somu_c, scmu_c, masks, feat, hmso, hmsc, cmso, cmsc);

    auto mkd = [&](const unsigned short* X1p, long xsa1, int ldx1, int K1,
                   const unsigned short* X2p, long xsa2, int ldx2, int K2,
                   long wo1, long wsa1, long wps1, long wo2, long wsa2, long wps2,
                   const float* bb1, long bsa1, const float* bb2, long bsa2,
                   void* Y, long ysa, int ldy, int N, int flags, int nA,
                   const unsigned short* cmsp, unsigned short* tokp, unsigned short* featp,
                   int layer, int foff) -> GDesc {
        GDesc d;
        d.X1 = X1p; d.X2 = X2p;
        d.W1 = wb + wo1; d.W2 = X2p ? wb + wo2 : nullptr;
        d.b1 = bb1; d.b2 = bb2; d.Y = Y;
        d.cms = cmsp; d.tokp = tokp; d.featp = featp;
        d.xsa1 = xsa1; d.xsa2 = xsa2;
        d.wsa1 = wsa1; d.wps1 = wps1; d.wsa2 = wsa2; d.wps2 = wps2;
        d.bsa1 = bsa1; d.bsa2 = bsa2; d.ysa = ysa;
        d.ldx1 = ldx1; d.K1 = K1; d.ldx2 = ldx2; d.K2 = K2; d.ldy = ldy; d.N = N;
        d.flags = flags; d.nA = nA; d.Nb = (N + 63) / 64;
        d.layer = layer; d.foff = foff;
        return d;
    };

    // ---------- descriptors ----------
    GDesc gat0 = mkd(feat, 0, 1664, 128, nullptr, 0, 0, 0,
                     o_gW0, 0, 131072, 0, 0, 0, gbl0, 0, gbr0, 0,
                     xlr, 0, 1024, 1024, 2 | 8, 1, nullptr, nullptr, nullptr, 0, 0);
    GDesc gat1 = mkd(feat + 128, 0, 1664, 128, nullptr, 0, 0, 0,
                     o_gW1, 0, 131072, 0, 0, 0, gbl1, 0, gbr1, 0,
                     xlr, 0, 1024, 1024, 2 | 8, 1, nullptr, nullptr, nullptr, 0, 0);
    GDesc so0  = mkd(feat, (long)B_ * 1664, 1664, 128, hmso, (long)B_ * 128, 128, 128,
                     o_soWih0, 512l * 128, 524288, o_soWhh0, 512l * 128, 524288,
                     sobih0, 512, sobhh0, 512, nullptr, 0, 0, 512, 16, A_,
                     cmso, tokS, nullptr, 0, 0);
    GDesc so1  = mkd(tokS, (long)B_ * 512, 512, 128, hmso + 2097152, (long)B_ * 128, 128, 128,
                     o_soWih1, 512l * 128, 524288, o_soWhh1, 512l * 128, 524288,
                     sobih1, 512, sobhh1, 512, nullptr, 0, 0, 512, 16, A_,
                     cmso, tokS, feat, 1, 384);
    GDesc sc0  = mkd(feat, (long)B_ * 1664, 1664, 384, hmsc, (long)B_ * 128, 128, 128,
                     o_scWih0, 512l * 384, 1572864, o_scWhh0, 512l * 128, 524288,
                     scbih0, 512, scbhh0, 512, nullptr, 0, 0, 512, 16, A_,
                     cmsc, tokC, nullptr, 0, 0);
    GDesc sc1  = mkd(tokC, (long)B_ * 512, 512, 128, hmsc + 2097152, (long)B_ * 128, 128, 128,
                     o_scWih1, 512l * 128, 524288, o_scWhh1, 512l * 128, 524288,
                     scbih1, 512, scbhh1, 512, nullptr, 0, 0, 512, 16, A_,
                     cmsc, tokC, feat, 1, 1024);
    GDesc fc0d = mkd(feat, 0, 1664, 1664, nullptr, 0, 0, 0,
                     o_fcw0, 0, 425984, 0, 0, 0, fcb0, 0, nullptr, 0,
                     x1, 0, 256, 256, 1 | 2, 1, nullptr, nullptr, nullptr, 0, 0);
    GDesc fc1d = mkd(x1, 0, 256, 256, nullptr, 0, 0, 0,
                     o_fcw1, 0, 65536, 0, 0, 0, fcb1, 0, nullptr, 0,
                     x2, 0, 256, 256, 1 | 2, 1, nullptr, nullptr, nullptr, 0, 0);
    GDesc actd = mkd(x2, 0, 256, 256, nullptr, 0, 0, 0,
                     o_actw, 0, 32768, 0, 0, 0, actb, 0, nullptr, 0,
                     logits, 0, ACT_, ACT_, 0, 1, nullptr, nullptr, nullptr, 0, 0);

    // grid helpers: MI=2 -> BM=128, MI=1 -> BM=64
    auto grid2 = [&](const GDesc& d, int M) { return d.nA * (M / 128) * d.Nb; };
    auto grid1 = [&](const GDesc& d, int M) { return d.nA * (M / 64) * d.Nb; };

    // ---------- schedule ----------
    mgemm_t<2><<<grid2(gat0, 16384), 256, 0, stream>>>(gat0);
    gat_reduce_k<<<B_, 256, 0, stream>>>(xlr, gatt0, gbias0, feat, 128);
    mgemm_t<2><<<grid2(gat1, 16384), 256, 0, stream>>>(gat1);
    gat_reduce_k<<<B_, 256, 0, stream>>>(xlr, gatt1, gbias1, feat, 256);

    // gates: BM=64 tiles (2048 blocks, 24KB LDS -> higher occupancy)
    mgemm_t<1><<<grid1(so0, B_), 256, 0, stream>>>(so0);
    mgemm_t<1><<<grid1(so1, B_), 256, 0, stream>>>(so1);
    mgemm_t<1><<<grid1(sc0, B_), 256, 0, stream>>>(sc0);
    mgemm_t<1><<<grid1(sc1, B_), 256, 0, stream>>>(sc1);

    // both chains' qkv+attn+outproj in ONE launch, 8-wave blocks (r19-proven v3)
    sattn_k<<<2048, 512, 0, stream>>>(tokS, tokC,
                                      wb + o_soqw, wb + o_scqw, 393216, soqb, scqb,
                                      wb + o_soow, wb + o_scow, 131072, soob, scob,
                                      feat);

    mgemm_t<2><<<grid2(fc0d, 16384), 256, 0, stream>>>(fc0d);
    mgemm_t<2><<<grid2(fc1d, 16384), 256, 0, stream>>>(fc1d);
    mgemm_t<2><<<grid2(actd, 16384), 256, 0, stream>>>(actd);
    lsm_k<<<A_ * B_ / 256, 256, 0, stream>>>(logits, (float*)d_out);
}

// Round 22
// 376.193 us; speedup vs baseline: 1.1655x; 1.0989x over previous
//
#include <hip/hip_runtime.h>
#include <math.h>

#define B_ 2048
#define A_ 8
#define ACT_ 14
#define FP_ 27262976l   // feat stride (16384*1664), single bf16 plane

typedef short short8 __attribute__((ext_vector_type(8)));
typedef float floatx4 __attribute__((ext_vector_type(4)));
typedef unsigned short u16x4 __attribute__((ext_vector_type(4)));

__device__ __forceinline__ unsigned short f2b(float f) {
    unsigned u = __float_as_uint(f);
    u += 0x7fff + ((u >> 16) & 1);
    return (unsigned short)(u >> 16);
}
__device__ __forceinline__ float b2f(unsigned short h) {
    return __uint_as_float(((unsigned)h) << 16);
}
__device__ __forceinline__ float sigm_(float x) { return 1.0f / (1.0f + expf(-x)); }

// ===== bf16 MFMA GEMM: (MI*64)x64 tiles; TT=1 -> exact hi/lo W (2-term), TT=0 -> hi only.
// ===== single-bf16 activations, ping-pong LDS (1 barrier/chunk), depth-4 reg prefetch.
// flags: 1=relu, 2=bf16 out, 4=token-fold rows, 8=split bias at col 512,
//        16=LSTM epilogue (W gate-permuted at cast; writes tok/feat, skips Y).
struct GDesc {
    const unsigned short *X1, *X2, *W1, *W2;
    const float *b1, *b2;
    void* Y;
    const unsigned short* cms;       // masked bf16 c-state [l][a][b][j]
    unsigned short* tokp;
    unsigned short* featp;
    long xsa1, xsa2, wsa1, wps1, wsa2, wps2, bsa1, bsa2, ysa;
    int ldx1, K1, ldx2, K2, ldy, N, flags, nA, Nb, layer, foff;
};

#define LOADC(c, xh, whv, wlv) do {                                                       \
    const unsigned short *Xb_, *Wb_; int ldx_, K_, k0_; long wps_;                        \
    if ((c) < nC1) { Xb_ = X1; ldx_ = ldx1; K_ = K1; wps_ = wps1; Wb_ = W1; k0_ = (c) << 5; } \
    else { Xb_ = X2; ldx_ = ldx2; K_ = K2; wps_ = wps2; Wb_ = W2; k0_ = ((c) - nC1) << 5; } \
    _Pragma("unroll") for (int mi_ = 0; mi_ < MI; ++mi_) {                                \
        int row_ = xr0 + mi_ * 16 + lrow;                                                 \
        xh[mi_] = *(const short8*)(Xb_ + (long)(bm + row_) * ldx_ + k0_ + lslot * 8); }   \
    { int row_ = wr0 + lrow;                                                              \
      const unsigned short* wp_ = Wb_ + (long)(bn + row_) * K_ + k0_ + lslot * 8;         \
      whv = *(const short8*)wp_;                                                          \
      if (TT) wlv = *(const short8*)(wp_ + wps_); }                                       \
} while (0)

#define STOREC(P, xh, whv, wlv) do {                                                      \
    _Pragma("unroll") for (int mi_ = 0; mi_ < MI; ++mi_) {                                \
        int row_ = xr0 + mi_ * 16 + lrow; int sl_ = lslot ^ ((row_ >> 1) & 3);            \
        *(short8*)&Xh_l[P][row_ * 32 + sl_ * 8] = xh[mi_]; }                              \
    { int row_ = wr0 + lrow; int sl_ = lslot ^ ((row_ >> 1) & 3);                         \
      *(short8*)&Wh_l[P][row_ * 32 + sl_ * 8] = whv;                                      \
      if (TT) *(short8*)&Wl_l[P][row_ * 32 + sl_ * 8] = wlv; }                            \
} while (0)

#define COMPUTEC(P) do {                                                                  \
    short8 bh[4], bl[4];                                                                  \
    _Pragma("unroll") for (int ni = 0; ni < 4; ++ni) {                                    \
        int row_ = ni * 16 + lr; int off_ = row_ * 32 + ((lk ^ ((row_ >> 1) & 3)) * 8);   \
        bh[ni] = *(const short8*)&Wh_l[P][off_];                                          \
        if (TT) bl[ni] = *(const short8*)&Wl_l[P][off_]; }                                \
    _Pragma("unroll") for (int mi = 0; mi < MI; ++mi) {                                   \
        int row_ = xr0 + mi * 16 + lr; int off_ = row_ * 32 + ((lk ^ ((row_ >> 1) & 3)) * 8); \
        short8 ah = *(const short8*)&Xh_l[P][off_];                                       \
        _Pragma("unroll") for (int ni = 0; ni < 4; ++ni)                                  \
            acc[mi][ni] = __builtin_amdgcn_mfma_f32_16x16x32_bf16(ah, bh[ni], acc[mi][ni], 0, 0, 0); \
        if (TT) {                                                                         \
            _Pragma("unroll") for (int ni = 0; ni < 4; ++ni)                              \
                acc[mi][ni] = __builtin_amdgcn_mfma_f32_16x16x32_bf16(ah, bl[ni], acc[mi][ni], 0, 0, 0); \
        }                                                                                 \
    }                                                                                     \
} while (0)

template<int MI, int TT>
__launch_bounds__(256)
__global__ void mgemm_t(GDesc d)
{
    __shared__ __align__(16) unsigned short Xh_l[2][MI * 64 * 32];
    __shared__ __align__(16) unsigned short Wh_l[2][64 * 32];
    __shared__ __align__(16) unsigned short Wl_l[2][TT ? 64 * 32 : 8];

    const int wg = blockIdx.x;
    const unsigned short* X1 = d.X1; const unsigned short* X2 = d.X2;
    const unsigned short* W1 = d.W1; const unsigned short* W2 = d.W2;
    const float* b1 = d.b1; const float* b2 = d.b2;
    const long wps1 = d.wps1, wps2 = d.wps2, ysa = d.ysa;
    const int ldx1 = d.ldx1, K1 = d.K1, ldx2 = d.ldx2, K2 = d.K2;
    const int ldy = d.ldy, N = d.N, flags = d.flags, nA = d.nA, Nb = d.Nb;
    const int layer = d.layer, foff = d.foff;

    int a, mb, nb;
    if (nA == 8) { a = wg & 7; int q = wg >> 3; nb = q % Nb; mb = q / Nb; }
    else { a = 0; int x8 = wg & 7; int q = wg >> 3; nb = q % Nb; mb = (q / Nb) * 8 + x8; }

    X1 += (long)a * d.xsa1;
    W1 += (long)a * d.wsa1;
    if (X2) { X2 += (long)a * d.xsa2; W2 += (long)a * d.wsa2; }
    if (b1) b1 += (long)a * d.bsa1;
    if (b2) b2 += (long)a * d.bsa2;

    const int bm = mb * (MI * 64);
    const int bn = nb * 64;
    const int t = threadIdx.x;
    const int lane = t & 63, wid = t >> 6;

    floatx4 acc[MI][4] = {};

    const int xr0 = wid * (MI * 16);
    const int wr0 = wid * 16;
    const int lrow = lane >> 2;
    const int lslot = lane & 3;
    const int lr = lane & 15, lk = lane >> 4;

    const int nC1 = K1 >> 5;
    const int nC = nC1 + (X2 ? (K2 >> 5) : 0);

    short8 Axh[MI], Awh, Awl;
    short8 Bxh[MI], Bwh, Bwl;
    short8 Cxh[MI], Cwh, Cwl;
    short8 Dxh[MI], Dwh, Dwl;

    LOADC(0, Axh, Awh, Awl);
    if (nC > 1) LOADC(1, Bxh, Bwh, Bwl);
    if (nC > 2) LOADC(2, Cxh, Cwh, Cwl);
    if (nC > 3) LOADC(3, Dxh, Dwh, Dwl);

    for (int c = 0; c < nC; c += 4) {
        STOREC(0, Axh, Awh, Awl);
        __syncthreads();
        if (c + 4 < nC) LOADC(c + 4, Axh, Awh, Awl);
        COMPUTEC(0);
        if (c + 1 < nC) {
            STOREC(1, Bxh, Bwh, Bwl);
            __syncthreads();
            if (c + 5 < nC) LOADC(c + 5, Bxh, Bwh, Bwl);
            COMPUTEC(1);
        }
        if (c + 2 < nC) {
            STOREC(0, Cxh, Cwh, Cwl);
            __syncthreads();
            if (c + 6 < nC) LOADC(c + 6, Cxh, Cwh, Cwl);
            COMPUTEC(0);
        }
        if (c + 3 < nC) {
            STOREC(1, Dxh, Dwh, Dwl);
            __syncthreads();
            if (c + 7 < nC) LOADC(c + 7, Dxh, Dwh, Dwl);
            COMPUTEC(1);
        }
    }

    const int lg = lane >> 4;

    if (flags & 16) {
        // fused LSTM pointwise epilogue (W rows gate-permuted at cast); j = nb*16 + lr
        const int j = (bn >> 2) + lr;
        unsigned short* tokp = d.tokp;
        unsigned short* featp = d.featp;
        const unsigned short* cms = d.cms;
#pragma unroll
        for (int mi = 0; mi < MI; ++mi) {
#pragma unroll
            for (int r = 0; r < 4; ++r) {
                const int b = bm + xr0 + mi * 16 + lg * 4 + r;
                float iv = acc[mi][0][r] + b1[j]       + b2[j];
                float fv = acc[mi][1][r] + b1[128 + j] + b2[128 + j];
                float gv = acc[mi][2][r] + b1[256 + j] + b2[256 + j];
                float ov = acc[mi][3][r] + b1[384 + j] + b2[384 + j];
                iv = sigm_(iv); fv = sigm_(fv); gv = tanhf(gv); ov = sigm_(ov);
                float cp = b2f(cms[(long)layer * 2097152 + (long)a * 262144 + b * 128 + j]);
                float c2 = fv * cp + iv * gv;
                float hv = ov * tanhf(c2);
                long tb = ((long)a * B_ + b) * 512;
                tokp[tb + layer * 128 + j] = f2b(hv);
                tokp[tb + (2 + layer) * 128 + j] = f2b(c2);
                if (featp) featp[((long)a * B_ + b) * 1664 + foff + j] = f2b(hv);
            }
        }
        return;
    }

    const bool relu = flags & 1, obf = flags & 2, fold = flags & 4, sbias = flags & 8;
    float* Yf = (float*)d.Y;
    unsigned short* Yh = (unsigned short*)d.Y;
#pragma unroll
    for (int mi = 0; mi < MI; ++mi) {
#pragma unroll
        for (int r = 0; r < 4; ++r) {
            int gm = bm + xr0 + mi * 16 + lg * 4 + r;
            long rowoff = fold ? ((long)(gm >> 2) * ldy + (gm & 3) * 128) : (long)gm * ldy;
            rowoff += (long)a * ysa;
#pragma unroll
            for (int ni = 0; ni < 4; ++ni) {
                int gc = bn + ni * 16 + lr;
                if (gc < N) {
                    float v = acc[mi][ni][r];
                    if (sbias) v += (gc < 512) ? b1[gc] : b2[gc - 512];
                    else { if (b1) v += b1[gc]; if (b2) v += b2[gc]; }
                    if (relu) v = fmaxf(v, 0.f);
                    if (obf) Yh[rowoff + gc] = f2b(v);
                    else     Yf[rowoff + gc] = v;
                }
            }
        }
    }
}

// ===== fused qkv-GEMM + 4-token MHA + out-proj, BOTH chains, 512 thr (8 waves) =====
// v3 + Q stride 396 (bank-conflict-free across the 16 sample rows).
__launch_bounds__(512)
__global__ void sattn_k(const unsigned short* __restrict__ tokS,
                        const unsigned short* __restrict__ tokC,
                        const unsigned short* __restrict__ WqS,
                        const unsigned short* __restrict__ WqC, long qlo,
                        const float* __restrict__ qbS, const float* __restrict__ qbC,
                        const unsigned short* __restrict__ WoS,
                        const unsigned short* __restrict__ WoC, long olo,
                        const float* __restrict__ obS, const float* __restrict__ obC,
                        unsigned short* __restrict__ feat)
{
    __shared__ __align__(16) unsigned short Xs[64 * 128];    // tok tile -> attn_o (reused)
    __shared__ __align__(16) unsigned short BufW[25600];     // W chunks -> Q[64][396]
    __shared__ float qbias[384];
    __shared__ float obias[128];

    int bid = blockIdx.x;
    const unsigned short* tok; const unsigned short* Wq; const float* qb;
    const unsigned short* Wo; const float* ob; int foff;
    if (bid < 1024) { tok = tokS; Wq = WqS; qb = qbS; Wo = WoS; ob = obS; foff = 512; }
    else { bid -= 1024; tok = tokC; Wq = WqC; qb = qbC; Wo = WoC; ob = obC; foff = 1152; }

    const int a = bid & 7;               // agent-per-XCD
    const int g = bid >> 3;              // 0..127
    const int b0 = g * 16;

    const unsigned short* Wqa = Wq + (long)a * 49152;
    const unsigned short* Woa = Wo + (long)a * 16384;
    const unsigned short* tokb = tok + ((long)a * B_ + b0) * 512;

    const int t = threadIdx.x;
    const int lane = t & 63, wid = t >> 6;          // wid 0..7
    const int lr = lane & 15, lk = lane >> 4, lg = lane >> 4;

    // ---- per-thread W slot geometry (qkv: 6 slots of 3072; outproj: 2 of 1024) ----
    int qwr[6], qws[6], qwp[6];
#pragma unroll
    for (int j = 0; j < 6; ++j) {
        int idx = t + j * 512;
        int pl = idx >= 1536;
        int rem = idx - (pl ? 1536 : 0);
        qwr[j] = rem >> 2; qws[j] = rem & 3; qwp[j] = pl;
    }
    int owr[2], ows[2], owp[2];
#pragma unroll
    for (int j = 0; j < 2; ++j) {
        int idx = t + j * 512;
        int pl = idx >> 9;
        int rem = idx & 511;
        owr[j] = rem >> 2; ows[j] = rem & 3; owp[j] = pl;
    }

    // ---- stage X (64x128, slot-swizzled s^(r&7)) + biases ----
    for (int idx = t; idx < 1024; idx += 512) {
        int r = idx >> 4, s = idx & 15;
        *(short8*)&Xs[r * 128 + (s ^ (r & 7)) * 8] = *(const short8*)(tokb + r * 128 + s * 8);
    }
    if (t < 384) qbias[t] = qb[a * 384 + t];
    if (t < 128) obias[t] = ob[a * 128 + t];

    unsigned short* Wh = BufW;             // [384][32]
    unsigned short* Wl = BufW + 12800;     // [384][32]

    short8 pw[6];
#pragma unroll
    for (int j = 0; j < 6; ++j)
        pw[j] = *(const short8*)(Wqa + (qwp[j] ? qlo : 0) + qwr[j] * 128 + qws[j] * 8);

    floatx4 acc[4][3] = {};                // m-frag 0..3 (rows), n-frag 0..2 (cols wid*48+)

    for (int kc = 0; kc < 4; ++kc) {
        const int k0 = kc * 32;
        if (kc) __syncthreads();           // prior chunk LDS reads done
#pragma unroll
        for (int j = 0; j < 6; ++j) {
            unsigned short* dst = (qwp[j] ? Wl : Wh) + qwr[j] * 32 + ((qws[j] ^ ((qwr[j] >> 1) & 3)) * 8);
            *(short8*)dst = pw[j];
        }
        __syncthreads();                   // X (first iter) + W writes visible
        if (kc < 3) {
            const int k1 = k0 + 32;
#pragma unroll
            for (int j = 0; j < 6; ++j)
                pw[j] = *(const short8*)(Wqa + (qwp[j] ? qlo : 0) + qwr[j] * 128 + k1 + qws[j] * 8);
        }
        short8 af[4];
#pragma unroll
        for (int mi = 0; mi < 4; ++mi) {
            int row = mi * 16 + lr;
            int sl = ((k0 >> 3) + lk) ^ (row & 7);
            af[mi] = *(const short8*)&Xs[row * 128 + sl * 8];
        }
#pragma unroll
        for (int ni = 0; ni < 3; ++ni) {
            int nrow = wid * 48 + ni * 16 + lr;
            int off = nrow * 32 + ((lk ^ ((nrow >> 1) & 3)) * 8);
            short8 bh = *(const short8*)&Wh[off];
            short8 bl = *(const short8*)&Wl[off];
#pragma unroll
            for (int mi = 0; mi < 4; ++mi) {
                acc[mi][ni] = __builtin_amdgcn_mfma_f32_16x16x32_bf16(af[mi], bh, acc[mi][ni], 0, 0, 0);
                acc[mi][ni] = __builtin_amdgcn_mfma_f32_16x16x32_bf16(af[mi], bl, acc[mi][ni], 0, 0, 0);
            }
        }
    }
    __syncthreads();                       // all W reads done; BufW -> Q

    // ---- write qkv (bf16 + bias) to Q[64][396] (stride 396: conflict-free rows) ----
    unsigned short* Q = BufW;
#pragma unroll
    for (int mi = 0; mi < 4; ++mi)
#pragma unroll
        for (int ni = 0; ni < 3; ++ni)
#pragma unroll
            for (int rr = 0; rr < 4; ++rr) {
                int row = mi * 16 + lg * 4 + rr;
                int col = wid * 48 + ni * 16 + lr;
                Q[row * 396 + col] = f2b(acc[mi][ni][rr] + qbias[col]);
            }
    __syncthreads();                       // Q visible

    // ---- prefetch out-proj W chunk 0 (hides under attention VALU) ----
    short8 po[2];
#pragma unroll
    for (int j = 0; j < 2; ++j)
        po[j] = *(const short8*)(Woa + (owp[j] ? olo : 0) + owr[j] * 128 + ows[j] * 8);

    // ---- attention: 2 threads per (sample, tq, h4); each half of PV output ----
    float oa[16];
    int qr, h4, hf;
    {
        int tt = t & 255;
        h4 = tt & 3; int tq = (tt >> 2) & 3, s = tt >> 4;
        hf = t >> 8;                       // 0 or 1: output half
        qr = s * 4 + tq;
        const unsigned short* qp = Q + qr * 396 + h4 * 32;
        float q[32];
#pragma unroll
        for (int r = 0; r < 8; ++r) {
            u16x4 v = *(const u16x4*)(qp + r * 4);
#pragma unroll
            for (int w = 0; w < 4; ++w) q[r * 4 + w] = b2f(v[w]);
        }
        float sv[4];
#pragma unroll
        for (int u = 0; u < 4; ++u) {
            const unsigned short* kp = Q + (s * 4 + u) * 396 + 128 + h4 * 32;
            float dd = 0.f;
#pragma unroll
            for (int r = 0; r < 8; ++r) {
                u16x4 v = *(const u16x4*)(kp + r * 4);
#pragma unroll
                for (int w = 0; w < 4; ++w) dd += q[r * 4 + w] * b2f(v[w]);
            }
            sv[u] = dd * 0.176776695296637f;
        }
        float mx = fmaxf(fmaxf(sv[0], sv[1]), fmaxf(sv[2], sv[3]));
        float e0 = expf(sv[0] - mx), e1 = expf(sv[1] - mx), e2 = expf(sv[2] - mx), e3 = expf(sv[3] - mx);
        float inv = 1.0f / (e0 + e1 + e2 + e3);
        float al[4] = { e0 * inv, e1 * inv, e2 * inv, e3 * inv };
#pragma unroll
        for (int w = 0; w < 16; ++w) oa[w] = 0.f;
#pragma unroll
        for (int u = 0; u < 4; ++u) {
            const unsigned short* vp = Q + (s * 4 + u) * 396 + 256 + h4 * 32 + hf * 16;
            float wgt = al[u];
#pragma unroll
            for (int r = 0; r < 4; ++r) {
                u16x4 v = *(const u16x4*)(vp + r * 4);
#pragma unroll
                for (int w = 0; w < 4; ++w) oa[r * 4 + w] += wgt * b2f(v[w]);
            }
        }
    }
    __syncthreads();                       // all Q reads done
    {                                      // write attn_o half into Xs (swizzled)
#pragma unroll
        for (int p = 0; p < 2; ++p) {
            short8 v;
#pragma unroll
            for (int w = 0; w < 8; ++w) v[w] = (short)f2b(oa[p * 8 + w]);
            int slot = h4 * 4 + hf * 2 + p;
            *(short8*)&Xs[qr * 128 + (slot ^ (qr & 7)) * 8] = v;
        }
    }

    // ---- out-proj: M=64, N=128 (wave owns 16 cols), K=128; reg-prefetched W ----
    unsigned short* Wh2 = BufW;            // [128][32]
    unsigned short* Wl2 = BufW + 4096;
    floatx4 acc2[4] = {};                  // m-frag 0..3, col block wid*16

    for (int kc = 0; kc < 4; ++kc) {
        const int k0 = kc * 32;
        __syncthreads();                   // prior reads done (incl. attn Xs writes visible)
#pragma unroll
        for (int j = 0; j < 2; ++j) {
            unsigned short* dst = (owp[j] ? Wl2 : Wh2) + owr[j] * 32 + ((ows[j] ^ ((owr[j] >> 1) & 3)) * 8);
            *(short8*)dst = po[j];
        }
        __syncthreads();
        if (kc < 3) {
            const int k1 = k0 + 32;
#pragma unroll
            for (int j = 0; j < 2; ++j)
                po[j] = *(const short8*)(Woa + (owp[j] ? olo : 0) + owr[j] * 128 + k1 + ows[j] * 8);
        }
        short8 af[4];
#pragma unroll
        for (int mi = 0; mi < 4; ++mi) {
            int row = mi * 16 + lr;
            int sl = ((k0 >> 3) + lk) ^ (row & 7);
            af[mi] = *(const short8*)&Xs[row * 128 + sl * 8];
        }
        {
            int nrow = wid * 16 + lr;
            int off = nrow * 32 + ((lk ^ ((nrow >> 1) & 3)) * 8);
            short8 bh = *(const short8*)&Wh2[off];
            short8 bl = *(const short8*)&Wl2[off];
#pragma unroll
            for (int mi = 0; mi < 4; ++mi) {
                acc2[mi] = __builtin_amdgcn_mfma_f32_16x16x32_bf16(af[mi], bh, acc2[mi], 0, 0, 0);
                acc2[mi] = __builtin_amdgcn_mfma_f32_16x16x32_bf16(af[mi], bl, acc2[mi], 0, 0, 0);
            }
        }
    }

    // ---- epilogue: token-folded feat write ----
#pragma unroll
    for (int mi = 0; mi < 4; ++mi)
#pragma unroll
        for (int rr = 0; rr < 4; ++rr) {
            int row = mi * 16 + lg * 4 + rr;
            int s2 = row >> 2, tq2 = row & 3;
            long base = ((long)a * B_ + b0 + s2) * 1664 + foff + tq2 * 128;
            int col = wid * 16 + lr;
            feat[base + col] = f2b(acc2[mi][rr] + obias[col]);
        }
}

// ===== weight cast (f32 -> bf16 hi + lo planes; optional LSTM gate permute) =====
#define NW 19
struct WTab {
    const float* src[NW];
    long hoff[NW];
    long loff[NW];
    int n[NW];
    int npad[NW];
    int kc[NW];
};
__global__ void wcast_k(WTab tab, unsigned short* __restrict__ wb)
{
    const int e = blockIdx.y;
    const int np = tab.npad[e];
    const float* s = tab.src[e];
    unsigned short* dh = wb + tab.hoff[e];
    unsigned short* dl = wb + tab.loff[e];
    const int n = tab.n[e];
    const int kc = tab.kc[e];
    for (long i = (long)blockIdx.x * 256 + threadIdx.x; i < np; i += (long)gridDim.x * 256) {
        long si = i;
        if (kc) {
            long per = 512l * kc;
            long ag = i / per;
            long rem = i - ag * per;
            int rp = (int)(rem / kc);
            int k = (int)(rem - (long)rp * kc);
            int srcr = (((rp & 63) >> 4) << 7) + ((rp >> 6) << 4) + (rp & 15);
            si = ag * per + (long)srcr * kc + k;
        }
        float v = (si < n) ? s[si] : 0.f;
        unsigned short h = f2b(v);
        dh[i] = h;
        dl[i] = f2b(v - b2f(h));
    }
}

// ===== prep: obs -> feat[:,0:128]; masked h/c states -> bf16 =====
__global__ void prep_k(const float* __restrict__ obs, const float* __restrict__ soh,
                       const float* __restrict__ sch, const float* __restrict__ soc,
                       const float* __restrict__ scc, const float* __restrict__ masks,
                       unsigned short* __restrict__ feat,
                       unsigned short* __restrict__ hmso, unsigned short* __restrict__ hmsc,
                       unsigned short* __restrict__ cmso, unsigned short* __restrict__ cmsc)
{
    long tid = (long)blockIdx.x * 256 + threadIdx.x;
    if (tid < 2097152) {
        int j = (int)(tid & 127);
        int row = (int)(tid >> 7);
        int b = row >> 3, aa = row & 7;
        feat[((long)aa * B_ + b) * 1664 + j] = f2b(obs[tid]);
        return;
    }
    long u = tid - 2097152;
    const float* src;
    unsigned short* dst;
    if (u < 4194304) { src = soh; dst = hmso; }
    else if (u < 2 * 4194304) { u -= 4194304; src = sch; dst = hmsc; }
    else if (u < 3 * 4194304) { u -= 2 * 4194304; src = soc; dst = cmso; }
    else { u -= 3 * 4194304; src = scc; dst = cmsc; }
    int j = (int)(u & 127);
    int b = (int)((u >> 7) & 2047);
    int aa = (int)((u >> 18) & 7);
    int l = (int)(u >> 21);
    float m = masks[b * 8 + aa];
    dst[u] = f2b(src[((long)(b * 8 + aa)) * 256 + l * 128 + j] * m);
}

// ===== GATv2 reduce (xlr combined [row][1024]: xl | xr) =====
__launch_bounds__(256)
__global__ void gat_reduce_k(const unsigned short* __restrict__ xlr,
                             const float* __restrict__ att, const float* __restrict__ bias,
                             unsigned short* __restrict__ feat, int coloff)
{
    __shared__ float xls[8][512];
    __shared__ float xrs[8][512];
    __shared__ float atts[512];
    __shared__ float es[8][8][4];
    __shared__ float as_[8][8][4];

    const int b = blockIdx.x;
    const int t = threadIdx.x;

    for (int i = t; i < 1024; i += 256) {
        int j = i >> 7, c4 = (i & 127) * 4;
        const unsigned short* base = xlr + ((long)j * B_ + b) * 1024;
        u16x4 vl = *(const u16x4*)(base + c4);
        u16x4 vr = *(const u16x4*)(base + 512 + c4);
#pragma unroll
        for (int q = 0; q < 4; ++q) {
            xls[j][c4 + q] = b2f(vl[q]);
            xrs[j][c4 + q] = b2f(vr[q]);
        }
    }
    for (int i = t; i < 128; i += 256)
        reinterpret_cast<float4*>(atts)[i] = reinterpret_cast<const float4*>(att)[i];
    __syncthreads();

    const int i = t >> 5, j = (t >> 2) & 7, h = t & 3;
    float e = 0.f;
    for (int cc = 0; cc < 128; ++cc) {
        int c = (cc + t) & 127;
        float s = xls[j][h * 128 + c] + xrs[i][h * 128 + c];
        s = s > 0.f ? s : 0.2f * s;
        e += s * atts[h * 128 + c];
    }
    es[i][j][h] = e;
    __syncthreads();

    float mx = -1e30f;
    for (int jj = 0; jj < 8; ++jj) mx = fmaxf(mx, es[i][jj][h]);
    float sum = 0.f;
    for (int jj = 0; jj < 8; ++jj) sum += expf(es[i][jj][h] - mx);
    as_[i][j][h] = expf(e - mx) / sum;
    __syncthreads();

    for (int idx = t; idx < 1024; idx += 256) {
        int ii = idx >> 7, c = idx & 127;
        float s = 0.f;
        for (int jj = 0; jj < 8; ++jj)
#pragma unroll
            for (int hh = 0; hh < 4; ++hh)
                s += as_[ii][jj][hh] * xls[jj][hh * 128 + c];
        s = s * 0.25f + bias[c];
        s = fmaxf(s, 0.f);
        feat[((long)ii * B_ + b) * 1664 + coloff + c] = f2b(s);
    }
}

// ===== log_softmax + transpose [A][B][14] -> (B,A,14) =====
__global__ void lsm_k(const float* __restrict__ logits, float* __restrict__ out)
{
    int tid = blockIdx.x * 256 + threadIdx.x;    // A*B
    int b = tid & (B_ - 1);
    int a = tid >> 11;
    const float* lp = logits + ((long)a * B_ + b) * ACT_;
    float x[ACT_];
    float mx = -1e30f;
#pragma unroll
    for (int n = 0; n < ACT_; ++n) { x[n] = lp[n]; mx = fmaxf(mx, x[n]); }
    float sum = 0.f;
#pragma unroll
    for (int n = 0; n < ACT_; ++n) sum += expf(x[n] - mx);
    float ls = mx + logf(sum);
    float* op = out + ((long)b * A_ + a) * ACT_;
#pragma unroll
    for (int n = 0; n < ACT_; ++n) op[n] = x[n] - ls;
}

extern "C" void kernel_launch(void* const* d_in, const int* in_sizes, int n_in,
                              void* d_out, int out_size, void* d_ws, size_t ws_size,
                              hipStream_t stream)
{
    const float* obs    = (const float*)d_in[0];
    const float* somu_h = (const float*)d_in[1];
    const float* somu_c = (const float*)d_in[2];
    const float* scmu_h = (const float*)d_in[3];
    const float* scmu_c = (const float*)d_in[4];
    const float* masks  = (const float*)d_in[5];
    const float* gWl0 = (const float*)d_in[6],  *gbl0 = (const float*)d_in[7];
    const float* gWr0 = (const float*)d_in[8],  *gbr0 = (const float*)d_in[9];
    const float* gatt0 = (const float*)d_in[10], *gbias0 = (const float*)d_in[11];
    const float* gWl1 = (const float*)d_in[12], *gbl1 = (const float*)d_in[13];
    const float* gWr1 = (const float*)d_in[14], *gbr1 = (const float*)d_in[15];
    const float* gatt1 = (const float*)d_in[16], *gbias1 = (const float*)d_in[17];
    const float* soWih0 = (const float*)d_in[18], *soWhh0 = (const float*)d_in[19];
    const float* sobih0 = (const float*)d_in[20], *sobhh0 = (const float*)d_in[21];
    const float* soWih1 = (const float*)d_in[22], *soWhh1 = (const float*)d_in[23];
    const float* sobih1 = (const float*)d_in[24], *sobhh1 = (const float*)d_in[25];
    const float* soqw = (const float*)d_in[26], *soqb = (const float*)d_in[27];
    const float* soow = (const float*)d_in[28], *soob = (const float*)d_in[29];
    const float* scWih0 = (const float*)d_in[30], *scWhh0 = (const float*)d_in[31];
    const float* scbih0 = (const float*)d_in[32], *scbhh0 = (const float*)d_in[33];
    const float* scWih1 = (const float*)d_in[34], *scWhh1 = (const float*)d_in[35];
    const float* scbih1 = (const float*)d_in[36], *scbhh1 = (const float*)d_in[37];
    const float* scqw = (const float*)d_in[38], *scqb = (const float*)d_in[39];
    const float* scow = (const float*)d_in[40], *scob = (const float*)d_in[41];
    const float* fcw0 = (const float*)d_in[42], *fcb0 = (const float*)d_in[43];
    const float* fcw1 = (const float*)d_in[44], *fcb1 = (const float*)d_in[45];
    const float* actw = (const float*)d_in[46], *actb = (const float*)d_in[47];

    // ---------- workspace layout (~200 MB) ----------
    unsigned short* wb = (unsigned short*)d_ws;
    long wo = 0;
    auto nxt = [&](long n) { long c = wo; wo += n; return c; };
    const long o_gW0 = nxt(262144), o_gW1 = nxt(262144);
    const long o_soWih0 = nxt(2 * 524288), o_soWhh0 = nxt(2 * 524288);
    const long o_soWih1 = nxt(2 * 524288), o_soWhh1 = nxt(2 * 524288);
    const long o_soqw = nxt(2 * 393216), o_soow = nxt(2 * 131072);
    const long o_scWih0 = nxt(2 * 1572864), o_scWhh0 = nxt(2 * 524288);
    const long o_scWih1 = nxt(2 * 524288), o_scWhh1 = nxt(2 * 524288);
    const long o_scqw = nxt(2 * 393216), o_scow = nxt(2 * 131072);
    const long o_fcw0 = nxt(2 * 425984), o_fcw1 = nxt(2 * 65536);
    const long o_actw = nxt(2 * 32768);                         // weights end: 14,155,776

    unsigned short* feat   = wb + nxt(FP_);            // single plane
    unsigned short* hmso   = wb + nxt(4194304);
    unsigned short* hmsc   = wb + nxt(4194304);
    unsigned short* cmso   = wb + nxt(4194304);
    unsigned short* cmsc   = wb + nxt(4194304);
    unsigned short* arenaA = wb + nxt(25165824);       // xlr | x1,x2,logits
    unsigned short* arenaB = wb + nxt(16777216);       // tokS, tokC
    // total ≈ 100.1M shorts = 200 MB

    unsigned short* xlr    = arenaA;                   // GAT phase [16384][1024]
    unsigned short* tokS   = arenaB;                   // [A][B][4][128]
    unsigned short* tokC   = arenaB + 8388608;
    unsigned short* x1     = arenaA;                   // head phase (single plane)
    unsigned short* x2     = arenaA + 4194304;
    float*          logits = (float*)(arenaA + 8388608);

    // ---------- weight cast ----------
    WTab tab;
    int ei = 0;
    auto ent = [&](const float* s, long hoff, long loff, int n, int npad, int kc) {
        tab.src[ei] = s; tab.hoff[ei] = hoff; tab.loff[ei] = loff;
        tab.n[ei] = n; tab.npad[ei] = npad; tab.kc[ei] = kc; ++ei;
    };
    ent(gWl0, o_gW0,          o_gW0 + 131072,          65536, 65536, 0);
    ent(gWr0, o_gW0 + 65536,  o_gW0 + 196608,          65536, 65536, 0);
    ent(gWl1, o_gW1,          o_gW1 + 131072,          65536, 65536, 0);
    ent(gWr1, o_gW1 + 65536,  o_gW1 + 196608,          65536, 65536, 0);
    ent(soWih0, o_soWih0, o_soWih0 + 524288, 524288, 524288, 128);
    ent(soWhh0, o_soWhh0, o_soWhh0 + 524288, 524288, 524288, 128);
    ent(soWih1, o_soWih1, o_soWih1 + 524288, 524288, 524288, 128);
    ent(soWhh1, o_soWhh1, o_soWhh1 + 524288, 524288, 524288, 128);
    ent(soqw, o_soqw, o_soqw + 393216, 393216, 393216, 0);
    ent(soow, o_soow, o_soow + 131072, 131072, 131072, 0);
    ent(scWih0, o_scWih0, o_scWih0 + 1572864, 1572864, 1572864, 384);
    ent(scWhh0, o_scWhh0, o_scWhh0 + 524288, 524288, 524288, 128);
    ent(scWih1, o_scWih1, o_scWih1 + 524288, 524288, 524288, 128);
    ent(scWhh1, o_scWhh1, o_scWhh1 + 524288, 524288, 524288, 128);
    ent(scqw, o_scqw, o_scqw + 393216, 393216, 393216, 0);
    ent(scow, o_scow, o_scow + 131072, 131072, 131072, 0);
    ent(fcw0, o_fcw0, o_fcw0 + 425984, 425984, 425984, 0);
    ent(fcw1, o_fcw1, o_fcw1 + 65536, 65536, 65536, 0);
    ent(actw, o_actw, o_actw + 32768, 3584, 32768, 0);
    wcast_k<<<dim3(1024, NW), 256, 0, stream>>>(tab, wb);

    prep_k<<<(2097152 + 4 * 4194304) / 256, 256, 0, stream>>>(
        obs, somu_h, scmu_h, somu_c, scmu_c, masks, feat, hmso, hmsc, cmso, cmsc);

    auto mkd = [&](const unsigned short* X1p, long xsa1, int ldx1, int K1,
                   const unsigned short* X2p, long xsa2, int ldx2, int K2,
                   long wo1, long wsa1, long wps1, long wo2, long wsa2, long wps2,
                   const float* bb1, long bsa1, const float* bb2, long bsa2,
                   void* Y, long ysa, int ldy, int N, int flags, int nA,
                   const unsigned short* cmsp, unsigned short* tokp, unsigned short* featp,
                   int layer, int foff) -> GDesc {
        GDesc d;
        d.X1 = X1p; d.X2 = X2p;
        d.W1 = wb + wo1; d.W2 = X2p ? wb + wo2 : nullptr;
        d.b1 = bb1; d.b2 = bb2; d.Y = Y;
        d.cms = cmsp; d.tokp = tokp; d.featp = featp;
        d.xsa1 = xsa1; d.xsa2 = xsa2;
        d.wsa1 = wsa1; d.wps1 = wps1; d.wsa2 = wsa2; d.wps2 = wps2;
        d.bsa1 = bsa1; d.bsa2 = bsa2; d.ysa = ysa;
        d.ldx1 = ldx1; d.K1 = K1; d.ldx2 = ldx2; d.K2 = K2; d.ldy = ldy; d.N = N;
        d.flags = flags; d.nA = nA; d.Nb = (N + 63) / 64;
        d.layer = layer; d.foff = foff;
        return d;
    };

    // ---------- descriptors ----------
    GDesc gat0 = mkd(feat, 0, 1664, 128, nullptr, 0, 0, 0,
                     o_gW0, 0, 131072, 0, 0, 0, gbl0, 0, gbr0, 0,
                     xlr, 0, 1024, 1024, 2 | 8, 1, nullptr, nullptr, nullptr, 0, 0);
    GDesc gat1 = mkd(feat + 128, 0, 1664, 128, nullptr, 0, 0, 0,
                     o_gW1, 0, 131072, 0, 0, 0, gbl1, 0, gbr1, 0,
                     xlr, 0, 1024, 1024, 2 | 8, 1, nullptr, nullptr, nullptr, 0, 0);
    GDesc so0  = mkd(feat, (long)B_ * 1664, 1664, 128, hmso, (long)B_ * 128, 128, 128,
                     o_soWih0, 512l * 128, 524288, o_soWhh0, 512l * 128, 524288,
                     sobih0, 512, sobhh0, 512, nullptr, 0, 0, 512, 16, A_,
                     cmso, tokS, nullptr, 0, 0);
    GDesc so1  = mkd(tokS, (long)B_ * 512, 512, 128, hmso + 2097152, (long)B_ * 128, 128, 128,
                     o_soWih1, 512l * 128, 524288, o_soWhh1, 512l * 128, 524288,
                     sobih1, 512, sobhh1, 512, nullptr, 0, 0, 512, 16, A_,
                     cmso, tokS, feat, 1, 384);
    GDesc sc0  = mkd(feat, (long)B_ * 1664, 1664, 384, hmsc, (long)B_ * 128, 128, 128,
                     o_scWih0, 512l * 384, 1572864, o_scWhh0, 512l * 128, 524288,
                     scbih0, 512, scbhh0, 512, nullptr, 0, 0, 512, 16, A_,
                     cmsc, tokC, nullptr, 0, 0);
    GDesc sc1  = mkd(tokC, (long)B_ * 512, 512, 128, hmsc + 2097152, (long)B_ * 128, 128, 128,
                     o_scWih1, 512l * 128, 524288, o_scWhh1, 512l * 128, 524288,
                     scbih1, 512, scbhh1, 512, nullptr, 0, 0, 512, 16, A_,
                     cmsc, tokC, feat, 1, 1024);
    GDesc fc0d = mkd(feat, 0, 1664, 1664, nullptr, 0, 0, 0,
                     o_fcw0, 0, 425984, 0, 0, 0, fcb0, 0, nullptr, 0,
                     x1, 0, 256, 256, 1 | 2, 1, nullptr, nullptr, nullptr, 0, 0);
    GDesc fc1d = mkd(x1, 0, 256, 256, nullptr, 0, 0, 0,
                     o_fcw1, 0, 65536, 0, 0, 0, fcb1, 0, nullptr, 0,
                     x2, 0, 256, 256, 1 | 2, 1, nullptr, nullptr, nullptr, 0, 0);
    GDesc actd = mkd(x2, 0, 256, 256, nullptr, 0, 0, 0,
                     o_actw, 0, 32768, 0, 0, 0, actb, 0, nullptr, 0,
                     logits, 0, ACT_, ACT_, 0, 1, nullptr, nullptr, nullptr, 0, 0);

    // grid helpers: MI=2 -> BM=128, MI=1 -> BM=64
    auto grid2 = [&](const GDesc& d, int M) { return d.nA * (M / 128) * d.Nb; };
    auto grid1 = [&](const GDesc& d, int M) { return d.nA * (M / 64) * d.Nb; };

    // ---------- schedule ----------
    // GAT: single-plane W (TT=0; early layer, error attenuated downstream)
    mgemm_t<2, 0><<<grid2(gat0, 16384), 256, 0, stream>>>(gat0);
    gat_reduce_k<<<B_, 256, 0, stream>>>(xlr, gatt0, gbias0, feat, 128);
    mgemm_t<2, 0><<<grid2(gat1, 16384), 256, 0, stream>>>(gat1);
    gat_reduce_k<<<B_, 256, 0, stream>>>(xlr, gatt1, gbias1, feat, 256);

    // gates: BM=64 tiles, single-plane W (sigmoid/tanh attenuate rounding)
    mgemm_t<1, 0><<<grid1(so0, B_), 256, 0, stream>>>(so0);
    mgemm_t<1, 0><<<grid1(so1, B_), 256, 0, stream>>>(so1);
    mgemm_t<1, 0><<<grid1(sc0, B_), 256, 0, stream>>>(sc0);
    mgemm_t<1, 0><<<grid1(sc1, B_), 256, 0, stream>>>(sc1);

    // both chains' qkv+attn+outproj in ONE launch (exact W; Q stride 396)
    sattn_k<<<2048, 512, 0, stream>>>(tokS, tokC,
                                      wb + o_soqw, wb + o_scqw, 393216, soqb, scqb,
                                      wb + o_soow, wb + o_scow, 131072, soob, scob,
                                      feat);

    // head: exact hi/lo W (feeds checked logits directly)
    mgemm_t<2, 1><<<grid2(fc0d, 16384), 256, 0, stream>>>(fc0d);
    mgemm_t<2, 1><<<grid2(fc1d, 16384), 256, 0, stream>>>(fc1d);
    mgemm_t<2, 1><<<grid2(actd, 16384), 256, 0, stream>>>(actd);
    lsm_k<<<A_ * B_ / 256, 256, 0, stream>>>(logits, (float*)d_out);
}

// Round 23
// 350.448 us; speedup vs baseline: 1.2511x; 1.0735x over previous
//
#include <hip/hip_runtime.h>
#include <math.h>

#define B_ 2048
#define A_ 8
#define ACT_ 14
#define FP_ 27262976l   // feat stride (16384*1664), single bf16 plane

typedef short short8 __attribute__((ext_vector_type(8)));
typedef float floatx4 __attribute__((ext_vector_type(4)));
typedef unsigned short u16x4 __attribute__((ext_vector_type(4)));

__device__ __forceinline__ unsigned short f2b(float f) {
    unsigned u = __float_as_uint(f);
    u += 0x7fff + ((u >> 16) & 1);
    return (unsigned short)(u >> 16);
}
__device__ __forceinline__ float b2f(unsigned short h) {
    return __uint_as_float(((unsigned)h) << 16);
}
__device__ __forceinline__ float sigm_(float x) { return 1.0f / (1.0f + expf(-x)); }

// ===== bf16 MFMA GEMM: (MI*64)x64 tiles; TT=1 -> exact hi/lo W (2-term), TT=0 -> hi only.
// ===== single-bf16 activations, ping-pong LDS (1 barrier/chunk), depth-4 reg prefetch.
// flags: 1=relu, 2=bf16 out, 4=token-fold rows, 8=split bias at col 512,
//        16=LSTM epilogue (W gate-permuted at cast; writes tok/feat, skips Y).
struct GDesc {
    const unsigned short *X1, *X2, *W1, *W2;
    const float *b1, *b2;
    void* Y;
    const unsigned short* cms;       // masked bf16 c-state [l][a][b][j]
    unsigned short* tokp;
    unsigned short* featp;
    long xsa1, xsa2, wsa1, wps1, wsa2, wps2, bsa1, bsa2, ysa;
    int ldx1, K1, ldx2, K2, ldy, N, flags, nA, Nb, layer, foff;
};

#define LOADC(c, xh, whv, wlv) do {                                                       \
    const unsigned short *Xb_, *Wb_; int ldx_, K_, k0_; long wps_;                        \
    if ((c) < nC1) { Xb_ = X1; ldx_ = ldx1; K_ = K1; wps_ = wps1; Wb_ = W1; k0_ = (c) << 5; } \
    else { Xb_ = X2; ldx_ = ldx2; K_ = K2; wps_ = wps2; Wb_ = W2; k0_ = ((c) - nC1) << 5; } \
    _Pragma("unroll") for (int mi_ = 0; mi_ < MI; ++mi_) {                                \
        int row_ = xr0 + mi_ * 16 + lrow;                                                 \
        xh[mi_] = *(const short8*)(Xb_ + (long)(bm + row_) * ldx_ + k0_ + lslot * 8); }   \
    { int row_ = wr0 + lrow;                                                              \
      const unsigned short* wp_ = Wb_ + (long)(bn + row_) * K_ + k0_ + lslot * 8;         \
      whv = *(const short8*)wp_;                                                          \
      if (TT) wlv = *(const short8*)(wp_ + wps_); }                                       \
} while (0)

#define STOREC(P, xh, whv, wlv) do {                                                      \
    _Pragma("unroll") for (int mi_ = 0; mi_ < MI; ++mi_) {                                \
        int row_ = xr0 + mi_ * 16 + lrow; int sl_ = lslot ^ ((row_ >> 1) & 3);            \
        *(short8*)&Xh_l[P][row_ * 32 + sl_ * 8] = xh[mi_]; }                              \
    { int row_ = wr0 + lrow; int sl_ = lslot ^ ((row_ >> 1) & 3);                         \
      *(short8*)&Wh_l[P][row_ * 32 + sl_ * 8] = whv;                                      \
      if (TT) *(short8*)&Wl_l[P][row_ * 32 + sl_ * 8] = wlv; }                            \
} while (0)

#define COMPUTEC(P) do {                                                                  \
    short8 bh[4], bl[4];                                                                  \
    _Pragma("unroll") for (int ni = 0; ni < 4; ++ni) {                                    \
        int row_ = ni * 16 + lr; int off_ = row_ * 32 + ((lk ^ ((row_ >> 1) & 3)) * 8);   \
        bh[ni] = *(const short8*)&Wh_l[P][off_];                                          \
        if (TT) bl[ni] = *(const short8*)&Wl_l[P][off_]; }                                \
    _Pragma("unroll") for (int mi = 0; mi < MI; ++mi) {                                   \
        int row_ = xr0 + mi * 16 + lr; int off_ = row_ * 32 + ((lk ^ ((row_ >> 1) & 3)) * 8); \
        short8 ah = *(const short8*)&Xh_l[P][off_];                                       \
        _Pragma("unroll") for (int ni = 0; ni < 4; ++ni)                                  \
            acc[mi][ni] = __builtin_amdgcn_mfma_f32_16x16x32_bf16(ah, bh[ni], acc[mi][ni], 0, 0, 0); \
        if (TT) {                                                                         \
            _Pragma("unroll") for (int ni = 0; ni < 4; ++ni)                              \
                acc[mi][ni] = __builtin_amdgcn_mfma_f32_16x16x32_bf16(ah, bl[ni], acc[mi][ni], 0, 0, 0); \
        }                                                                                 \
    }                                                                                     \
} while (0)

template<int MI, int TT>
__launch_bounds__(256)
__global__ void mgemm_t(GDesc d)
{
    __shared__ __align__(16) unsigned short Xh_l[2][MI * 64 * 32];
    __shared__ __align__(16) unsigned short Wh_l[2][64 * 32];
    __shared__ __align__(16) unsigned short Wl_l[2][TT ? 64 * 32 : 8];

    const int wg = blockIdx.x;
    const unsigned short* X1 = d.X1; const unsigned short* X2 = d.X2;
    const unsigned short* W1 = d.W1; const unsigned short* W2 = d.W2;
    const float* b1 = d.b1; const float* b2 = d.b2;
    const long wps1 = d.wps1, wps2 = d.wps2, ysa = d.ysa;
    const int ldx1 = d.ldx1, K1 = d.K1, ldx2 = d.ldx2, K2 = d.K2;
    const int ldy = d.ldy, N = d.N, flags = d.flags, nA = d.nA, Nb = d.Nb;
    const int layer = d.layer, foff = d.foff;

    int a, mb, nb;
    if (nA == 8) { a = wg & 7; int q = wg >> 3; nb = q % Nb; mb = q / Nb; }
    else { a = 0; int x8 = wg & 7; int q = wg >> 3; nb = q % Nb; mb = (q / Nb) * 8 + x8; }

    X1 += (long)a * d.xsa1;
    W1 += (long)a * d.wsa1;
    if (X2) { X2 += (long)a * d.xsa2; W2 += (long)a * d.wsa2; }
    if (b1) b1 += (long)a * d.bsa1;
    if (b2) b2 += (long)a * d.bsa2;

    const int bm = mb * (MI * 64);
    const int bn = nb * 64;
    const int t = threadIdx.x;
    const int lane = t & 63, wid = t >> 6;

    floatx4 acc[MI][4] = {};

    const int xr0 = wid * (MI * 16);
    const int wr0 = wid * 16;
    const int lrow = lane >> 2;
    const int lslot = lane & 3;
    const int lr = lane & 15, lk = lane >> 4;

    const int nC1 = K1 >> 5;
    const int nC = nC1 + (X2 ? (K2 >> 5) : 0);

    short8 Axh[MI], Awh, Awl;
    short8 Bxh[MI], Bwh, Bwl;
    short8 Cxh[MI], Cwh, Cwl;
    short8 Dxh[MI], Dwh, Dwl;

    LOADC(0, Axh, Awh, Awl);
    if (nC > 1) LOADC(1, Bxh, Bwh, Bwl);
    if (nC > 2) LOADC(2, Cxh, Cwh, Cwl);
    if (nC > 3) LOADC(3, Dxh, Dwh, Dwl);

    for (int c = 0; c < nC; c += 4) {
        STOREC(0, Axh, Awh, Awl);
        __syncthreads();
        if (c + 4 < nC) LOADC(c + 4, Axh, Awh, Awl);
        COMPUTEC(0);
        if (c + 1 < nC) {
            STOREC(1, Bxh, Bwh, Bwl);
            __syncthreads();
            if (c + 5 < nC) LOADC(c + 5, Bxh, Bwh, Bwl);
            COMPUTEC(1);
        }
        if (c + 2 < nC) {
            STOREC(0, Cxh, Cwh, Cwl);
            __syncthreads();
            if (c + 6 < nC) LOADC(c + 6, Cxh, Cwh, Cwl);
            COMPUTEC(0);
        }
        if (c + 3 < nC) {
            STOREC(1, Dxh, Dwh, Dwl);
            __syncthreads();
            if (c + 7 < nC) LOADC(c + 7, Dxh, Dwh, Dwl);
            COMPUTEC(1);
        }
    }

    const int lg = lane >> 4;

    if (flags & 16) {
        // fused LSTM pointwise epilogue (W rows gate-permuted at cast); j = nb*16 + lr
        const int j = (bn >> 2) + lr;
        unsigned short* tokp = d.tokp;
        unsigned short* featp = d.featp;
        const unsigned short* cms = d.cms;
#pragma unroll
        for (int mi = 0; mi < MI; ++mi) {
#pragma unroll
            for (int r = 0; r < 4; ++r) {
                const int b = bm + xr0 + mi * 16 + lg * 4 + r;
                float iv = acc[mi][0][r] + b1[j]       + b2[j];
                float fv = acc[mi][1][r] + b1[128 + j] + b2[128 + j];
                float gv = acc[mi][2][r] + b1[256 + j] + b2[256 + j];
                float ov = acc[mi][3][r] + b1[384 + j] + b2[384 + j];
                iv = sigm_(iv); fv = sigm_(fv); gv = tanhf(gv); ov = sigm_(ov);
                float cp = b2f(cms[(long)layer * 2097152 + (long)a * 262144 + b * 128 + j]);
                float c2 = fv * cp + iv * gv;
                float hv = ov * tanhf(c2);
                long tb = ((long)a * B_ + b) * 512;
                tokp[tb + layer * 128 + j] = f2b(hv);
                tokp[tb + (2 + layer) * 128 + j] = f2b(c2);
                if (featp) featp[((long)a * B_ + b) * 1664 + foff + j] = f2b(hv);
            }
        }
        return;
    }

    const bool relu = flags & 1, obf = flags & 2, fold = flags & 4, sbias = flags & 8;
    float* Yf = (float*)d.Y;
    unsigned short* Yh = (unsigned short*)d.Y;
#pragma unroll
    for (int mi = 0; mi < MI; ++mi) {
#pragma unroll
        for (int r = 0; r < 4; ++r) {
            int gm = bm + xr0 + mi * 16 + lg * 4 + r;
            long rowoff = fold ? ((long)(gm >> 2) * ldy + (gm & 3) * 128) : (long)gm * ldy;
            rowoff += (long)a * ysa;
#pragma unroll
            for (int ni = 0; ni < 4; ++ni) {
                int gc = bn + ni * 16 + lr;
                if (gc < N) {
                    float v = acc[mi][ni][r];
                    if (sbias) v += (gc < 512) ? b1[gc] : b2[gc - 512];
                    else { if (b1) v += b1[gc]; if (b2) v += b2[gc]; }
                    if (relu) v = fmaxf(v, 0.f);
                    if (obf) Yh[rowoff + gc] = f2b(v);
                    else     Yf[rowoff + gc] = v;
                }
            }
        }
    }
}

// ===== fused qkv-GEMM + 4-token MHA + out-proj, BOTH chains, 512 thr (8 waves) =====
// v5: single-plane W (hi only) for qkv and out-proj; staging halved (3 qkv slots +
// 1 outproj slot per thread); MFMA count halved. Q stride 396. Structure = r19 v3.
__launch_bounds__(512)
__global__ void sattn_k(const unsigned short* __restrict__ tokS,
                        const unsigned short* __restrict__ tokC,
                        const unsigned short* __restrict__ WqS,
                        const unsigned short* __restrict__ WqC,
                        const float* __restrict__ qbS, const float* __restrict__ qbC,
                        const unsigned short* __restrict__ WoS,
                        const unsigned short* __restrict__ WoC,
                        const float* __restrict__ obS, const float* __restrict__ obC,
                        unsigned short* __restrict__ feat)
{
    __shared__ __align__(16) unsigned short Xs[64 * 128];    // tok tile -> attn_o (reused)
    __shared__ __align__(16) unsigned short BufW[25600];     // W chunks -> Q[64][396]
    __shared__ float qbias[384];
    __shared__ float obias[128];

    int bid = blockIdx.x;
    const unsigned short* tok; const unsigned short* Wq; const float* qb;
    const unsigned short* Wo; const float* ob; int foff;
    if (bid < 1024) { tok = tokS; Wq = WqS; qb = qbS; Wo = WoS; ob = obS; foff = 512; }
    else { bid -= 1024; tok = tokC; Wq = WqC; qb = qbC; Wo = WoC; ob = obC; foff = 1152; }

    const int a = bid & 7;               // agent-per-XCD
    const int g = bid >> 3;              // 0..127
    const int b0 = g * 16;

    const unsigned short* Wqa = Wq + (long)a * 49152;
    const unsigned short* Woa = Wo + (long)a * 16384;
    const unsigned short* tokb = tok + ((long)a * B_ + b0) * 512;

    const int t = threadIdx.x;
    const int lane = t & 63, wid = t >> 6;          // wid 0..7
    const int lr = lane & 15, lk = lane >> 4, lg = lane >> 4;

    // ---- per-thread W slot geometry (qkv: 3 slots of 1536; outproj: 1 of 512) ----
    int qwr[3], qws[3];
#pragma unroll
    for (int j = 0; j < 3; ++j) {
        int idx = t + j * 512;
        qwr[j] = idx >> 2; qws[j] = idx & 3;
    }
    const int owr = t >> 2, ows = t & 3;            // t < 512 covers all 512 slots

    // ---- stage X (64x128, slot-swizzled s^(r&7)) + biases ----
    for (int idx = t; idx < 1024; idx += 512) {
        int r = idx >> 4, s = idx & 15;
        *(short8*)&Xs[r * 128 + (s ^ (r & 7)) * 8] = *(const short8*)(tokb + r * 128 + s * 8);
    }
    if (t < 384) qbias[t] = qb[a * 384 + t];
    if (t < 128) obias[t] = ob[a * 128 + t];

    unsigned short* Wh = BufW;             // [384][32]

    short8 pw[3];
#pragma unroll
    for (int j = 0; j < 3; ++j)
        pw[j] = *(const short8*)(Wqa + qwr[j] * 128 + qws[j] * 8);

    floatx4 acc[4][3] = {};                // m-frag 0..3 (rows), n-frag 0..2 (cols wid*48+)

    for (int kc = 0; kc < 4; ++kc) {
        const int k0 = kc * 32;
        if (kc) __syncthreads();           // prior chunk LDS reads done
#pragma unroll
        for (int j = 0; j < 3; ++j) {
            unsigned short* dst = Wh + qwr[j] * 32 + ((qws[j] ^ ((qwr[j] >> 1) & 3)) * 8);
            *(short8*)dst = pw[j];
        }
        __syncthreads();                   // X (first iter) + W writes visible
        if (kc < 3) {
            const int k1 = k0 + 32;
#pragma unroll
            for (int j = 0; j < 3; ++j)
                pw[j] = *(const short8*)(Wqa + qwr[j] * 128 + k1 + qws[j] * 8);
        }
        short8 af[4];
#pragma unroll
        for (int mi = 0; mi < 4; ++mi) {
            int row = mi * 16 + lr;
            int sl = ((k0 >> 3) + lk) ^ (row & 7);
            af[mi] = *(const short8*)&Xs[row * 128 + sl * 8];
        }
#pragma unroll
        for (int ni = 0; ni < 3; ++ni) {
            int nrow = wid * 48 + ni * 16 + lr;
            int off = nrow * 32 + ((lk ^ ((nrow >> 1) & 3)) * 8);
            short8 bh = *(const short8*)&Wh[off];
#pragma unroll
            for (int mi = 0; mi < 4; ++mi)
                acc[mi][ni] = __builtin_amdgcn_mfma_f32_16x16x32_bf16(af[mi], bh, acc[mi][ni], 0, 0, 0);
        }
    }
    __syncthreads();                       // all W reads done; BufW -> Q

    // ---- write qkv (bf16 + bias) to Q[64][396] ----
    unsigned short* Q = BufW;
#pragma unroll
    for (int mi = 0; mi < 4; ++mi)
#pragma unroll
        for (int ni = 0; ni < 3; ++ni)
#pragma unroll
            for (int rr = 0; rr < 4; ++rr) {
                int row = mi * 16 + lg * 4 + rr;
                int col = wid * 48 + ni * 16 + lr;
                Q[row * 396 + col] = f2b(acc[mi][ni][rr] + qbias[col]);
            }
    __syncthreads();                       // Q visible

    // ---- prefetch out-proj W chunk 0 (hides under attention VALU) ----
    short8 po = *(const short8*)(Woa + owr * 128 + ows * 8);

    // ---- attention: 2 threads per (sample, tq, h4); each half of PV output ----
    float oa[16];
    int qr, h4, hf;
    {
        int tt = t & 255;
        h4 = tt & 3; int tq = (tt >> 2) & 3, s = tt >> 4;
        hf = t >> 8;                       // 0 or 1: output half
        qr = s * 4 + tq;
        const unsigned short* qp = Q + qr * 396 + h4 * 32;
        float q[32];
#pragma unroll
        for (int r = 0; r < 8; ++r) {
            u16x4 v = *(const u16x4*)(qp + r * 4);
#pragma unroll
            for (int w = 0; w < 4; ++w) q[r * 4 + w] = b2f(v[w]);
        }
        float sv[4];
#pragma unroll
        for (int u = 0; u < 4; ++u) {
            const unsigned short* kp = Q + (s * 4 + u) * 396 + 128 + h4 * 32;
            float dd = 0.f;
#pragma unroll
            for (int r = 0; r < 8; ++r) {
                u16x4 v = *(const u16x4*)(kp + r * 4);
#pragma unroll
                for (int w = 0; w < 4; ++w) dd += q[r * 4 + w] * b2f(v[w]);
            }
            sv[u] = dd * 0.176776695296637f;
        }
        float mx = fmaxf(fmaxf(sv[0], sv[1]), fmaxf(sv[2], sv[3]));
        float e0 = expf(sv[0] - mx), e1 = expf(sv[1] - mx), e2 = expf(sv[2] - mx), e3 = expf(sv[3] - mx);
        float inv = 1.0f / (e0 + e1 + e2 + e3);
        float al[4] = { e0 * inv, e1 * inv, e2 * inv, e3 * inv };
#pragma unroll
        for (int w = 0; w < 16; ++w) oa[w] = 0.f;
#pragma unroll
        for (int u = 0; u < 4; ++u) {
            const unsigned short* vp = Q + (s * 4 + u) * 396 + 256 + h4 * 32 + hf * 16;
            float wgt = al[u];
#pragma unroll
            for (int r = 0; r < 4; ++r) {
                u16x4 v = *(const u16x4*)(vp + r * 4);
#pragma unroll
                for (int w = 0; w < 4; ++w) oa[r * 4 + w] += wgt * b2f(v[w]);
            }
        }
    }
    __syncthreads();                       // all Q reads done
    {                                      // write attn_o half into Xs (swizzled)
#pragma unroll
        for (int p = 0; p < 2; ++p) {
            short8 v;
#pragma unroll
            for (int w = 0; w < 8; ++w) v[w] = (short)f2b(oa[p * 8 + w]);
            int slot = h4 * 4 + hf * 2 + p;
            *(short8*)&Xs[qr * 128 + (slot ^ (qr & 7)) * 8] = v;
        }
    }

    // ---- out-proj: M=64, N=128 (wave owns 16 cols), K=128; single-plane W ----
    unsigned short* Wh2 = BufW;            // [128][32]
    floatx4 acc2[4] = {};                  // m-frag 0..3, col block wid*16

    for (int kc = 0; kc < 4; ++kc) {
        const int k0 = kc * 32;
        __syncthreads();                   // prior reads done (incl. attn Xs writes visible)
        {
            unsigned short* dst = Wh2 + owr * 32 + ((ows ^ ((owr >> 1) & 3)) * 8);
            *(short8*)dst = po;
        }
        __syncthreads();
        if (kc < 3) {
            const int k1 = k0 + 32;
            po = *(const short8*)(Woa + owr * 128 + k1 + ows * 8);
        }
        short8 af[4];
#pragma unroll
        for (int mi = 0; mi < 4; ++mi) {
            int row = mi * 16 + lr;
            int sl = ((k0 >> 3) + lk) ^ (row & 7);
            af[mi] = *(const short8*)&Xs[row * 128 + sl * 8];
        }
        {
            int nrow = wid * 16 + lr;
            int off = nrow * 32 + ((lk ^ ((nrow >> 1) & 3)) * 8);
            short8 bh = *(const short8*)&Wh2[off];
#pragma unroll
            for (int mi = 0; mi < 4; ++mi)
                acc2[mi] = __builtin_amdgcn_mfma_f32_16x16x32_bf16(af[mi], bh, acc2[mi], 0, 0, 0);
        }
    }

    // ---- epilogue: token-folded feat write ----
#pragma unroll
    for (int mi = 0; mi < 4; ++mi)
#pragma unroll
        for (int rr = 0; rr < 4; ++rr) {
            int row = mi * 16 + lg * 4 + rr;
            int s2 = row >> 2, tq2 = row & 3;
            long base = ((long)a * B_ + b0 + s2) * 1664 + foff + tq2 * 128;
            int col = wid * 16 + lr;
            feat[base + col] = f2b(acc2[mi][rr] + obias[col]);
        }
}

// ===== weight cast (f32 -> bf16 hi + lo planes; optional LSTM gate permute) =====
#define NW 19
struct WTab {
    const float* src[NW];
    long hoff[NW];
    long loff[NW];
    int n[NW];
    int npad[NW];
    int kc[NW];
};
__global__ void wcast_k(WTab tab, unsigned short* __restrict__ wb)
{
    const int e = blockIdx.y;
    const int np = tab.npad[e];
    const float* s = tab.src[e];
    unsigned short* dh = wb + tab.hoff[e];
    unsigned short* dl = wb + tab.loff[e];
    const int n = tab.n[e];
    const int kc = tab.kc[e];
    for (long i = (long)blockIdx.x * 256 + threadIdx.x; i < np; i += (long)gridDim.x * 256) {
        long si = i;
        if (kc) {
            long per = 512l * kc;
            long ag = i / per;
            long rem = i - ag * per;
            int rp = (int)(rem / kc);
            int k = (int)(rem - (long)rp * kc);
            int srcr = (((rp & 63) >> 4) << 7) + ((rp >> 6) << 4) + (rp & 15);
            si = ag * per + (long)srcr * kc + k;
        }
        float v = (si < n) ? s[si] : 0.f;
        unsigned short h = f2b(v);
        dh[i] = h;
        dl[i] = f2b(v - b2f(h));
    }
}

// ===== prep: obs -> feat[:,0:128]; masked h/c states -> bf16 =====
__global__ void prep_k(const float* __restrict__ obs, const float* __restrict__ soh,
                       const float* __restrict__ sch, const float* __restrict__ soc,
                       const float* __restrict__ scc, const float* __restrict__ masks,
                       unsigned short* __restrict__ feat,
                       unsigned short* __restrict__ hmso, unsigned short* __restrict__ hmsc,
                       unsigned short* __restrict__ cmso, unsigned short* __restrict__ cmsc)
{
    long tid = (long)blockIdx.x * 256 + threadIdx.x;
    if (tid < 2097152) {
        int j = (int)(tid & 127);
        int row = (int)(tid >> 7);
        int b = row >> 3, aa = row & 7;
        feat[((long)aa * B_ + b) * 1664 + j] = f2b(obs[tid]);
        return;
    }
    long u = tid - 2097152;
    const float* src;
    unsigned short* dst;
    if (u < 4194304) { src = soh; dst = hmso; }
    else if (u < 2 * 4194304) { u -= 4194304; src = sch; dst = hmsc; }
    else if (u < 3 * 4194304) { u -= 2 * 4194304; src = soc; dst = cmso; }
    else { u -= 3 * 4194304; src = scc; dst = cmsc; }
    int j = (int)(u & 127);
    int b = (int)((u >> 7) & 2047);
    int aa = (int)((u >> 18) & 7);
    int l = (int)(u >> 21);
    float m = masks[b * 8 + aa];
    dst[u] = f2b(src[((long)(b * 8 + aa)) * 256 + l * 128 + j] * m);
}

// ===== GATv2 reduce (xlr combined [row][1024]: xl | xr) =====
__launch_bounds__(256)
__global__ void gat_reduce_k(const unsigned short* __restrict__ xlr,
                             const float* __restrict__ att, const float* __restrict__ bias,
                             unsigned short* __restrict__ feat, int coloff)
{
    __shared__ float xls[8][512];
    __shared__ float xrs[8][512];
    __shared__ float atts[512];
    __shared__ float es[8][8][4];
    __shared__ float as_[8][8][4];

    const int b = blockIdx.x;
    const int t = threadIdx.x;

    for (int i = t; i < 1024; i += 256) {
        int j = i >> 7, c4 = (i & 127) * 4;
        const unsigned short* base = xlr + ((long)j * B_ + b) * 1024;
        u16x4 vl = *(const u16x4*)(base + c4);
        u16x4 vr = *(const u16x4*)(base + 512 + c4);
#pragma unroll
        for (int q = 0; q < 4; ++q) {
            xls[j][c4 + q] = b2f(vl[q]);
            xrs[j][c4 + q] = b2f(vr[q]);
        }
    }
    for (int i = t; i < 128; i += 256)
        reinterpret_cast<float4*>(atts)[i] = reinterpret_cast<const float4*>(att)[i];
    __syncthreads();

    const int i = t >> 5, j = (t >> 2) & 7, h = t & 3;
    float e = 0.f;
    for (int cc = 0; cc < 128; ++cc) {
        int c = (cc + t) & 127;
        float s = xls[j][h * 128 + c] + xrs[i][h * 128 + c];
        s = s > 0.f ? s : 0.2f * s;
        e += s * atts[h * 128 + c];
    }
    es[i][j][h] = e;
    __syncthreads();

    float mx = -1e30f;
    for (int jj = 0; jj < 8; ++jj) mx = fmaxf(mx, es[i][jj][h]);
    float sum = 0.f;
    for (int jj = 0; jj < 8; ++jj) sum += expf(es[i][jj][h] - mx);
    as_[i][j][h] = expf(e - mx) / sum;
    __syncthreads();

    for (int idx = t; idx < 1024; idx += 256) {
        int ii = idx >> 7, c = idx & 127;
        float s = 0.f;
        for (int jj = 0; jj < 8; ++jj)
#pragma unroll
            for (int hh = 0; hh < 4; ++hh)
                s += as_[ii][jj][hh] * xls[jj][hh * 128 + c];
        s = s * 0.25f + bias[c];
        s = fmaxf(s, 0.f);
        feat[((long)ii * B_ + b) * 1664 + coloff + c] = f2b(s);
    }
}

// ===== log_softmax + transpose [A][B][14] -> (B,A,14) =====
__global__ void lsm_k(const float* __restrict__ logits, float* __restrict__ out)
{
    int tid = blockIdx.x * 256 + threadIdx.x;    // A*B
    int b = tid & (B_ - 1);
    int a = tid >> 11;
    const float* lp = logits + ((long)a * B_ + b) * ACT_;
    float x[ACT_];
    float mx = -1e30f;
#pragma unroll
    for (int n = 0; n < ACT_; ++n) { x[n] = lp[n]; mx = fmaxf(mx, x[n]); }
    float sum = 0.f;
#pragma unroll
    for (int n = 0; n < ACT_; ++n) sum += expf(x[n] - mx);
    float ls = mx + logf(sum);
    float* op = out + ((long)b * A_ + a) * ACT_;
#pragma unroll
    for (int n = 0; n < ACT_; ++n) op[n] = x[n] - ls;
}

extern "C" void kernel_launch(void* const* d_in, const int* in_sizes, int n_in,
                              void* d_out, int out_size, void* d_ws, size_t ws_size,
                              hipStream_t stream)
{
    const float* obs    = (const float*)d_in[0];
    const float* somu_h = (const float*)d_in[1];
    const float* somu_c = (const float*)d_in[2];
    const float* scmu_h = (const float*)d_in[3];
    const float* scmu_c = (const float*)d_in[4];
    const float* masks  = (const float*)d_in[5];
    const float* gWl0 = (const float*)d_in[6],  *gbl0 = (const float*)d_in[7];
    const float* gWr0 = (const float*)d_in[8],  *gbr0 = (const float*)d_in[9];
    const float* gatt0 = (const float*)d_in[10], *gbias0 = (const float*)d_in[11];
    const float* gWl1 = (const float*)d_in[12], *gbl1 = (const float*)d_in[13];
    const float* gWr1 = (const float*)d_in[14], *gbr1 = (const float*)d_in[15];
    const float* gatt1 = (const float*)d_in[16], *gbias1 = (const float*)d_in[17];
    const float* soWih0 = (const float*)d_in[18], *soWhh0 = (const float*)d_in[19];
    const float* sobih0 = (const float*)d_in[20], *sobhh0 = (const float*)d_in[21];
    const float* soWih1 = (const float*)d_in[22], *soWhh1 = (const float*)d_in[23];
    const float* sobih1 = (const float*)d_in[24], *sobhh1 = (const float*)d_in[25];
    const float* soqw = (const float*)d_in[26], *soqb = (const float*)d_in[27];
    const float* soow = (const float*)d_in[28], *soob = (const float*)d_in[29];
    const float* scWih0 = (const float*)d_in[30], *scWhh0 = (const float*)d_in[31];
    const float* scbih0 = (const float*)d_in[32], *scbhh0 = (const float*)d_in[33];
    const float* scWih1 = (const float*)d_in[34], *scWhh1 = (const float*)d_in[35];
    const float* scbih1 = (const float*)d_in[36], *scbhh1 = (const float*)d_in[37];
    const float* scqw = (const float*)d_in[38], *scqb = (const float*)d_in[39];
    const float* scow = (const float*)d_in[40], *scob = (const float*)d_in[41];
    const float* fcw0 = (const float*)d_in[42], *fcb0 = (const float*)d_in[43];
    const float* fcw1 = (const float*)d_in[44], *fcb1 = (const float*)d_in[45];
    const float* actw = (const float*)d_in[46], *actb = (const float*)d_in[47];

    // ---------- workspace layout (~200 MB) ----------
    unsigned short* wb = (unsigned short*)d_ws;
    long wo = 0;
    auto nxt = [&](long n) { long c = wo; wo += n; return c; };
    const long o_gW0 = nxt(262144), o_gW1 = nxt(262144);
    const long o_soWih0 = nxt(2 * 524288), o_soWhh0 = nxt(2 * 524288);
    const long o_soWih1 = nxt(2 * 524288), o_soWhh1 = nxt(2 * 524288);
    const long o_soqw = nxt(2 * 393216), o_soow = nxt(2 * 131072);
    const long o_scWih0 = nxt(2 * 1572864), o_scWhh0 = nxt(2 * 524288);
    const long o_scWih1 = nxt(2 * 524288), o_scWhh1 = nxt(2 * 524288);
    const long o_scqw = nxt(2 * 393216), o_scow = nxt(2 * 131072);
    const long o_fcw0 = nxt(2 * 425984), o_fcw1 = nxt(2 * 65536);
    const long o_actw = nxt(2 * 32768);                         // weights end: 14,155,776

    unsigned short* feat   = wb + nxt(FP_);            // single plane
    unsigned short* hmso   = wb + nxt(4194304);
    unsigned short* hmsc   = wb + nxt(4194304);
    unsigned short* cmso   = wb + nxt(4194304);
    unsigned short* cmsc   = wb + nxt(4194304);
    unsigned short* arenaA = wb + nxt(25165824);       // xlr | x1,x2,logits
    unsigned short* arenaB = wb + nxt(16777216);       // tokS, tokC
    // total ≈ 100.1M shorts = 200 MB

    unsigned short* xlr    = arenaA;                   // GAT phase [16384][1024]
    unsigned short* tokS   = arenaB;                   // [A][B][4][128]
    unsigned short* tokC   = arenaB + 8388608;
    unsigned short* x1     = arenaA;                   // head phase (single plane)
    unsigned short* x2     = arenaA + 4194304;
    float*          logits = (float*)(arenaA + 8388608);

    // ---------- weight cast ----------
    WTab tab;
    int ei = 0;
    auto ent = [&](const float* s, long hoff, long loff, int n, int npad, int kc) {
        tab.src[ei] = s; tab.hoff[ei] = hoff; tab.loff[ei] = loff;
        tab.n[ei] = n; tab.npad[ei] = npad; tab.kc[ei] = kc; ++ei;
    };
    ent(gWl0, o_gW0,          o_gW0 + 131072,          65536, 65536, 0);
    ent(gWr0, o_gW0 + 65536,  o_gW0 + 196608,          65536, 65536, 0);
    ent(gWl1, o_gW1,          o_gW1 + 131072,          65536, 65536, 0);
    ent(gWr1, o_gW1 + 65536,  o_gW1 + 196608,          65536, 65536, 0);
    ent(soWih0, o_soWih0, o_soWih0 + 524288, 524288, 524288, 128);
    ent(soWhh0, o_soWhh0, o_soWhh0 + 524288, 524288, 524288, 128);
    ent(soWih1, o_soWih1, o_soWih1 + 524288, 524288, 524288, 128);
    ent(soWhh1, o_soWhh1, o_soWhh1 + 524288, 524288, 524288, 128);
    ent(soqw, o_soqw, o_soqw + 393216, 393216, 393216, 0);
    ent(soow, o_soow, o_soow + 131072, 131072, 131072, 0);
    ent(scWih0, o_scWih0, o_scWih0 + 1572864, 1572864, 1572864, 384);
    ent(scWhh0, o_scWhh0, o_scWhh0 + 524288, 524288, 524288, 128);
    ent(scWih1, o_scWih1, o_scWih1 + 524288, 524288, 524288, 128);
    ent(scWhh1, o_scWhh1, o_scWhh1 + 524288, 524288, 524288, 128);
    ent(scqw, o_scqw, o_scqw + 393216, 393216, 393216, 0);
    ent(scow, o_scow, o_scow + 131072, 131072, 131072, 0);
    ent(fcw0, o_fcw0, o_fcw0 + 425984, 425984, 425984, 0);
    ent(fcw1, o_fcw1, o_fcw1 + 65536, 65536, 65536, 0);
    ent(actw, o_actw, o_actw + 32768, 3584, 32768, 0);
    wcast_k<<<dim3(1024, NW), 256, 0, stream>>>(tab, wb);

    prep_k<<<(2097152 + 4 * 4194304) / 256, 256, 0, stream>>>(
        obs, somu_h, scmu_h, somu_c, scmu_c, masks, feat, hmso, hmsc, cmso, cmsc);

    auto mkd = [&](const unsigned short* X1p, long xsa1, int ldx1, int K1,
                   const unsigned short* X2p, long xsa2, int ldx2, int K2,
                   long wo1, long wsa1, long wps1, long wo2, long wsa2, long wps2,
                   const float* bb1, long bsa1, const float* bb2, long bsa2,
                   void* Y, long ysa, int ldy, int N, int flags, int nA,
                   const unsigned short* cmsp, unsigned short* tokp, unsigned short* featp,
                   int layer, int foff) -> GDesc {
        GDesc d;
        d.X1 = X1p; d.X2 = X2p;
        d.W1 = wb + wo1; d.W2 = X2p ? wb + wo2 : nullptr;
        d.b1 = bb1; d.b2 = bb2; d.Y = Y;
        d.cms = cmsp; d.tokp = tokp; d.featp = featp;
        d.xsa1 = xsa1; d.xsa2 = xsa2;
        d.wsa1 = wsa1; d.wps1 = wps1; d.wsa2 = wsa2; d.wps2 = wps2;
        d.bsa1 = bsa1; d.bsa2 = bsa2; d.ysa = ysa;
        d.ldx1 = ldx1; d.K1 = K1; d.ldx2 = ldx2; d.K2 = K2; d.ldy = ldy; d.N = N;
        d.flags = flags; d.nA = nA; d.Nb = (N + 63) / 64;
        d.layer = layer; d.foff = foff;
        return d;
    };

    // ---------- descriptors ----------
    GDesc gat0 = mkd(feat, 0, 1664, 128, nullptr, 0, 0, 0,
                     o_gW0, 0, 131072, 0, 0, 0, gbl0, 0, gbr0, 0,
                     xlr, 0, 1024, 1024, 2 | 8, 1, nullptr, nullptr, nullptr, 0, 0);
    GDesc gat1 = mkd(feat + 128, 0, 1664, 128, nullptr, 0, 0, 0,
                     o_gW1, 0, 131072, 0, 0, 0, gbl1, 0, gbr1, 0,
                     xlr, 0, 1024, 1024, 2 | 8, 1, nullptr, nullptr, nullptr, 0, 0);
    GDesc so0  = mkd(feat, (long)B_ * 1664, 1664, 128, hmso, (long)B_ * 128, 128, 128,
                     o_soWih0, 512l * 128, 524288, o_soWhh0, 512l * 128, 524288,
                     sobih0, 512, sobhh0, 512, nullptr, 0, 0, 512, 16, A_,
                     cmso, tokS, nullptr, 0, 0);
    GDesc so1  = mkd(tokS, (long)B_ * 512, 512, 128, hmso + 2097152, (long)B_ * 128, 128, 128,
                     o_soWih1, 512l * 128, 524288, o_soWhh1, 512l * 128, 524288,
                     sobih1, 512, sobhh1, 512, nullptr, 0, 0, 512, 16, A_,
                     cmso, tokS, feat, 1, 384);
    GDesc sc0  = mkd(feat, (long)B_ * 1664, 1664, 384, hmsc, (long)B_ * 128, 128, 128,
                     o_scWih0, 512l * 384, 1572864, o_scWhh0, 512l * 128, 524288,
                     scbih0, 512, scbhh0, 512, nullptr, 0, 0, 512, 16, A_,
                     cmsc, tokC, nullptr, 0, 0);
    GDesc sc1  = mkd(tokC, (long)B_ * 512, 512, 128, hmsc + 2097152, (long)B_ * 128, 128, 128,
                     o_scWih1, 512l * 128, 524288, o_scWhh1, 512l * 128, 524288,
                     scbih1, 512, scbhh1, 512, nullptr, 0, 0, 512, 16, A_,
                     cmsc, tokC, feat, 1, 1024);
    GDesc fc0d = mkd(feat, 0, 1664, 1664, nullptr, 0, 0, 0,
                     o_fcw0, 0, 425984, 0, 0, 0, fcb0, 0, nullptr, 0,
                     x1, 0, 256, 256, 1 | 2, 1, nullptr, nullptr, nullptr, 0, 0);
    GDesc fc1d = mkd(x1, 0, 256, 256, nullptr, 0, 0, 0,
                     o_fcw1, 0, 65536, 0, 0, 0, fcb1, 0, nullptr, 0,
                     x2, 0, 256, 256, 1 | 2, 1, nullptr, nullptr, nullptr, 0, 0);
    GDesc actd = mkd(x2, 0, 256, 256, nullptr, 0, 0, 0,
                     o_actw, 0, 32768, 0, 0, 0, actb, 0, nullptr, 0,
                     logits, 0, ACT_, ACT_, 0, 1, nullptr, nullptr, nullptr, 0, 0);

    // grid helpers: MI=2 -> BM=128, MI=1 -> BM=64
    auto grid2 = [&](const GDesc& d, int M) { return d.nA * (M / 128) * d.Nb; };
    auto grid1 = [&](const GDesc& d, int M) { return d.nA * (M / 64) * d.Nb; };

    // ---------- schedule ----------
    // GAT: single-plane W
    mgemm_t<2, 0><<<grid2(gat0, 16384), 256, 0, stream>>>(gat0);
    gat_reduce_k<<<B_, 256, 0, stream>>>(xlr, gatt0, gbias0, feat, 128);
    mgemm_t<2, 0><<<grid2(gat1, 16384), 256, 0, stream>>>(gat1);
    gat_reduce_k<<<B_, 256, 0, stream>>>(xlr, gatt1, gbias1, feat, 256);

    // gates: BM=64 tiles, single-plane W
    mgemm_t<1, 0><<<grid1(so0, B_), 256, 0, stream>>>(so0);
    mgemm_t<1, 0><<<grid1(so1, B_), 256, 0, stream>>>(so1);
    mgemm_t<1, 0><<<grid1(sc0, B_), 256, 0, stream>>>(sc0);
    mgemm_t<1, 0><<<grid1(sc1, B_), 256, 0, stream>>>(sc1);

    // both chains' qkv+attn+outproj in ONE launch, single-plane W
    sattn_k<<<2048, 512, 0, stream>>>(tokS, tokC,
                                      wb + o_soqw, wb + o_scqw, soqb, scqb,
                                      wb + o_soow, wb + o_scow, soob, scob,
                                      feat);

    // head: fc0/fc1 single-plane (error ~1e-3 class); act exact (tiny, direct logits)
    mgemm_t<2, 0><<<grid2(fc0d, 16384), 256, 0, stream>>>(fc0d);
    mgemm_t<2, 0><<<grid2(fc1d, 16384), 256, 0, stream>>>(fc1d);
    mgemm_t<2, 1><<<grid2(actd, 16384), 256, 0, stream>>>(actd);
    lsm_k<<<A_ * B_ / 256, 256, 0, stream>>>(logits, (float*)d_out);
}

// Round 24
// 334.268 us; speedup vs baseline: 1.3117x; 1.0484x over previous
//
#include <hip/hip_runtime.h>
#include <math.h>

#define B_ 2048
#define A_ 8
#define ACT_ 14
#define FP_ 27262976l   // feat stride (16384*1664), single bf16 plane

typedef short short8 __attribute__((ext_vector_type(8)));
typedef float floatx4 __attribute__((ext_vector_type(4)));
typedef unsigned short u16x4 __attribute__((ext_vector_type(4)));

__device__ __forceinline__ unsigned short f2b(float f) {
    unsigned u = __float_as_uint(f);
    u += 0x7fff + ((u >> 16) & 1);
    return (unsigned short)(u >> 16);
}
__device__ __forceinline__ float b2f(unsigned short h) {
    return __uint_as_float(((unsigned)h) << 16);
}
__device__ __forceinline__ float sigm_(float x) { return 1.0f / (1.0f + __expf(-x)); }
__device__ __forceinline__ float tanh_(float x) { return 1.0f - 2.0f / (1.0f + __expf(2.0f * x)); }

// ===== bf16 MFMA GEMM: (MI*64)x64 tiles; TT=1 -> exact hi/lo W (2-term), TT=0 -> hi only.
// ===== single-bf16 activations, ping-pong LDS (1 barrier/chunk), depth-4 reg prefetch.
// flags: 1=relu, 2=bf16 out, 4=token-fold rows, 8=split bias at col 512,
//        16=LSTM epilogue (W gate-permuted at cast; writes tok/feat, skips Y).
struct GDesc {
    const unsigned short *X1, *X2, *W1, *W2;
    const float *b1, *b2;
    void* Y;
    const unsigned short* cms;       // masked bf16 c-state [l][a][b][j]
    unsigned short* tokp;
    unsigned short* featp;
    long xsa1, xsa2, wsa1, wps1, wsa2, wps2, bsa1, bsa2, ysa;
    int ldx1, K1, ldx2, K2, ldy, N, flags, nA, Nb, layer, foff;
};

#define LOADC(c, xh, whv, wlv) do {                                                       \
    const unsigned short *Xb_, *Wb_; int ldx_, K_, k0_; long wps_;                        \
    if ((c) < nC1) { Xb_ = X1; ldx_ = ldx1; K_ = K1; wps_ = wps1; Wb_ = W1; k0_ = (c) << 5; } \
    else { Xb_ = X2; ldx_ = ldx2; K_ = K2; wps_ = wps2; Wb_ = W2; k0_ = ((c) - nC1) << 5; } \
    _Pragma("unroll") for (int mi_ = 0; mi_ < MI; ++mi_) {                                \
        int row_ = xr0 + mi_ * 16 + lrow;                                                 \
        xh[mi_] = *(const short8*)(Xb_ + (long)(bm + row_) * ldx_ + k0_ + lslot * 8); }   \
    { int row_ = wr0 + lrow;                                                              \
      const unsigned short* wp_ = Wb_ + (long)(bn + row_) * K_ + k0_ + lslot * 8;         \
      whv = *(const short8*)wp_;                                                          \
      if (TT) wlv = *(const short8*)(wp_ + wps_); }                                       \
} while (0)

#define STOREC(P, xh, whv, wlv) do {                                                      \
    _Pragma("unroll") for (int mi_ = 0; mi_ < MI; ++mi_) {                                \
        int row_ = xr0 + mi_ * 16 + lrow; int sl_ = lslot ^ ((row_ >> 1) & 3);            \
        *(short8*)&Xh_l[P][row_ * 32 + sl_ * 8] = xh[mi_]; }                              \
    { int row_ = wr0 + lrow; int sl_ = lslot ^ ((row_ >> 1) & 3);                         \
      *(short8*)&Wh_l[P][row_ * 32 + sl_ * 8] = whv;                                      \
      if (TT) *(short8*)&Wl_l[P][row_ * 32 + sl_ * 8] = wlv; }                            \
} while (0)

#define COMPUTEC(P) do {                                                                  \
    short8 bh[4], bl[4];                                                                  \
    _Pragma("unroll") for (int ni = 0; ni < 4; ++ni) {                                    \
        int row_ = ni * 16 + lr; int off_ = row_ * 32 + ((lk ^ ((row_ >> 1) & 3)) * 8);   \
        bh[ni] = *(const short8*)&Wh_l[P][off_];                                          \
        if (TT) bl[ni] = *(const short8*)&Wl_l[P][off_]; }                                \
    _Pragma("unroll") for (int mi = 0; mi < MI; ++mi) {                                   \
        int row_ = xr0 + mi * 16 + lr; int off_ = row_ * 32 + ((lk ^ ((row_ >> 1) & 3)) * 8); \
        short8 ah = *(const short8*)&Xh_l[P][off_];                                       \
        _Pragma("unroll") for (int ni = 0; ni < 4; ++ni)                                  \
            acc[mi][ni] = __builtin_amdgcn_mfma_f32_16x16x32_bf16(ah, bh[ni], acc[mi][ni], 0, 0, 0); \
        if (TT) {                                                                         \
            _Pragma("unroll") for (int ni = 0; ni < 4; ++ni)                              \
                acc[mi][ni] = __builtin_amdgcn_mfma_f32_16x16x32_bf16(ah, bl[ni], acc[mi][ni], 0, 0, 0); \
        }                                                                                 \
    }                                                                                     \
} while (0)

template<int MI, int TT>
__launch_bounds__(256)
__global__ void mgemm_t(GDesc d)
{
    __shared__ __align__(16) unsigned short Xh_l[2][MI * 64 * 32];
    __shared__ __align__(16) unsigned short Wh_l[2][64 * 32];
    __shared__ __align__(16) unsigned short Wl_l[2][TT ? 64 * 32 : 8];

    const int wg = blockIdx.x;
    const unsigned short* X1 = d.X1; const unsigned short* X2 = d.X2;
    const unsigned short* W1 = d.W1; const unsigned short* W2 = d.W2;
    const float* b1 = d.b1; const float* b2 = d.b2;
    const long wps1 = d.wps1, wps2 = d.wps2, ysa = d.ysa;
    const int ldx1 = d.ldx1, K1 = d.K1, ldx2 = d.ldx2, K2 = d.K2;
    const int ldy = d.ldy, N = d.N, flags = d.flags, nA = d.nA, Nb = d.Nb;
    const int layer = d.layer, foff = d.foff;

    int a, mb, nb;
    if (nA == 8) { a = wg & 7; int q = wg >> 3; nb = q % Nb; mb = q / Nb; }
    else { a = 0; int x8 = wg & 7; int q = wg >> 3; nb = q % Nb; mb = (q / Nb) * 8 + x8; }

    X1 += (long)a * d.xsa1;
    W1 += (long)a * d.wsa1;
    if (X2) { X2 += (long)a * d.xsa2; W2 += (long)a * d.wsa2; }
    if (b1) b1 += (long)a * d.bsa1;
    if (b2) b2 += (long)a * d.bsa2;

    const int bm = mb * (MI * 64);
    const int bn = nb * 64;
    const int t = threadIdx.x;
    const int lane = t & 63, wid = t >> 6;

    floatx4 acc[MI][4] = {};

    const int xr0 = wid * (MI * 16);
    const int wr0 = wid * 16;
    const int lrow = lane >> 2;
    const int lslot = lane & 3;
    const int lr = lane & 15, lk = lane >> 4;

    const int nC1 = K1 >> 5;
    const int nC = nC1 + (X2 ? (K2 >> 5) : 0);

    short8 Axh[MI], Awh, Awl;
    short8 Bxh[MI], Bwh, Bwl;
    short8 Cxh[MI], Cwh, Cwl;
    short8 Dxh[MI], Dwh, Dwl;

    LOADC(0, Axh, Awh, Awl);
    if (nC > 1) LOADC(1, Bxh, Bwh, Bwl);
    if (nC > 2) LOADC(2, Cxh, Cwh, Cwl);
    if (nC > 3) LOADC(3, Dxh, Dwh, Dwl);

    for (int c = 0; c < nC; c += 4) {
        STOREC(0, Axh, Awh, Awl);
        __syncthreads();
        if (c + 4 < nC) LOADC(c + 4, Axh, Awh, Awl);
        COMPUTEC(0);
        if (c + 1 < nC) {
            STOREC(1, Bxh, Bwh, Bwl);
            __syncthreads();
            if (c + 5 < nC) LOADC(c + 5, Bxh, Bwh, Bwl);
            COMPUTEC(1);
        }
        if (c + 2 < nC) {
            STOREC(0, Cxh, Cwh, Cwl);
            __syncthreads();
            if (c + 6 < nC) LOADC(c + 6, Cxh, Cwh, Cwl);
            COMPUTEC(0);
        }
        if (c + 3 < nC) {
            STOREC(1, Dxh, Dwh, Dwl);
            __syncthreads();
            if (c + 7 < nC) LOADC(c + 7, Dxh, Dwh, Dwl);
            COMPUTEC(1);
        }
    }

    const int lg = lane >> 4;

    if (flags & 16) {
        // fused LSTM pointwise epilogue (W rows gate-permuted at cast); j = nb*16 + lr
        const int j = (bn >> 2) + lr;
        unsigned short* tokp = d.tokp;
        unsigned short* featp = d.featp;
        const unsigned short* cms = d.cms;
#pragma unroll
        for (int mi = 0; mi < MI; ++mi) {
#pragma unroll
            for (int r = 0; r < 4; ++r) {
                const int b = bm + xr0 + mi * 16 + lg * 4 + r;
                float iv = acc[mi][0][r] + b1[j]       + b2[j];
                float fv = acc[mi][1][r] + b1[128 + j] + b2[128 + j];
                float gv = acc[mi][2][r] + b1[256 + j] + b2[256 + j];
                float ov = acc[mi][3][r] + b1[384 + j] + b2[384 + j];
                iv = sigm_(iv); fv = sigm_(fv); gv = tanh_(gv); ov = sigm_(ov);
                float cp = b2f(cms[(long)layer * 2097152 + (long)a * 262144 + b * 128 + j]);
                float c2 = fv * cp + iv * gv;
                float hv = ov * tanh_(c2);
                long tb = ((long)a * B_ + b) * 512;
                tokp[tb + layer * 128 + j] = f2b(hv);
                tokp[tb + (2 + layer) * 128 + j] = f2b(c2);
                if (featp) featp[((long)a * B_ + b) * 1664 + foff + j] = f2b(hv);
            }
        }
        return;
    }

    const bool relu = flags & 1, obf = flags & 2, fold = flags & 4, sbias = flags & 8;
    float* Yf = (float*)d.Y;
    unsigned short* Yh = (unsigned short*)d.Y;
#pragma unroll
    for (int mi = 0; mi < MI; ++mi) {
#pragma unroll
        for (int r = 0; r < 4; ++r) {
            int gm = bm + xr0 + mi * 16 + lg * 4 + r;
            long rowoff = fold ? ((long)(gm >> 2) * ldy + (gm & 3) * 128) : (long)gm * ldy;
            rowoff += (long)a * ysa;
#pragma unroll
            for (int ni = 0; ni < 4; ++ni) {
                int gc = bn + ni * 16 + lr;
                if (gc < N) {
                    float v = acc[mi][ni][r];
                    if (sbias) v += (gc < 512) ? b1[gc] : b2[gc - 512];
                    else { if (b1) v += b1[gc]; if (b2) v += b2[gc]; }
                    if (relu) v = fmaxf(v, 0.f);
                    if (obf) Yh[rowoff + gc] = f2b(v);
                    else     Yf[rowoff + gc] = v;
                }
            }
        }
    }
}

// ===== fused qkv-GEMM + 4-token MHA + out-proj, BOTH chains, 512 thr (8 waves) =====
// v5: single-plane W; staging halved; Q stride 396; fast-exp softmax.
__launch_bounds__(512)
__global__ void sattn_k(const unsigned short* __restrict__ tokS,
                        const unsigned short* __restrict__ tokC,
                        const unsigned short* __restrict__ WqS,
                        const unsigned short* __restrict__ WqC,
                        const float* __restrict__ qbS, const float* __restrict__ qbC,
                        const unsigned short* __restrict__ WoS,
                        const unsigned short* __restrict__ WoC,
                        const float* __restrict__ obS, const float* __restrict__ obC,
                        unsigned short* __restrict__ feat)
{
    __shared__ __align__(16) unsigned short Xs[64 * 128];    // tok tile -> attn_o (reused)
    __shared__ __align__(16) unsigned short BufW[25600];     // W chunks -> Q[64][396]
    __shared__ float qbias[384];
    __shared__ float obias[128];

    int bid = blockIdx.x;
    const unsigned short* tok; const unsigned short* Wq; const float* qb;
    const unsigned short* Wo; const float* ob; int foff;
    if (bid < 1024) { tok = tokS; Wq = WqS; qb = qbS; Wo = WoS; ob = obS; foff = 512; }
    else { bid -= 1024; tok = tokC; Wq = WqC; qb = qbC; Wo = WoC; ob = obC; foff = 1152; }

    const int a = bid & 7;               // agent-per-XCD
    const int g = bid >> 3;              // 0..127
    const int b0 = g * 16;

    const unsigned short* Wqa = Wq + (long)a * 49152;
    const unsigned short* Woa = Wo + (long)a * 16384;
    const unsigned short* tokb = tok + ((long)a * B_ + b0) * 512;

    const int t = threadIdx.x;
    const int lane = t & 63, wid = t >> 6;          // wid 0..7
    const int lr = lane & 15, lk = lane >> 4, lg = lane >> 4;

    // ---- per-thread W slot geometry (qkv: 3 slots of 1536; outproj: 1 of 512) ----
    int qwr[3], qws[3];
#pragma unroll
    for (int j = 0; j < 3; ++j) {
        int idx = t + j * 512;
        qwr[j] = idx >> 2; qws[j] = idx & 3;
    }
    const int owr = t >> 2, ows = t & 3;            // t < 512 covers all 512 slots

    // ---- stage X (64x128, slot-swizzled s^(r&7)) + biases ----
    for (int idx = t; idx < 1024; idx += 512) {
        int r = idx >> 4, s = idx & 15;
        *(short8*)&Xs[r * 128 + (s ^ (r & 7)) * 8] = *(const short8*)(tokb + r * 128 + s * 8);
    }
    if (t < 384) qbias[t] = qb[a * 384 + t];
    if (t < 128) obias[t] = ob[a * 128 + t];

    unsigned short* Wh = BufW;             // [384][32]

    short8 pw[3];
#pragma unroll
    for (int j = 0; j < 3; ++j)
        pw[j] = *(const short8*)(Wqa + qwr[j] * 128 + qws[j] * 8);

    floatx4 acc[4][3] = {};                // m-frag 0..3 (rows), n-frag 0..2 (cols wid*48+)

    for (int kc = 0; kc < 4; ++kc) {
        const int k0 = kc * 32;
        if (kc) __syncthreads();           // prior chunk LDS reads done
#pragma unroll
        for (int j = 0; j < 3; ++j) {
            unsigned short* dst = Wh + qwr[j] * 32 + ((qws[j] ^ ((qwr[j] >> 1) & 3)) * 8);
            *(short8*)dst = pw[j];
        }
        __syncthreads();                   // X (first iter) + W writes visible
        if (kc < 3) {
            const int k1 = k0 + 32;
#pragma unroll
            for (int j = 0; j < 3; ++j)
                pw[j] = *(const short8*)(Wqa + qwr[j] * 128 + k1 + qws[j] * 8);
        }
        short8 af[4];
#pragma unroll
        for (int mi = 0; mi < 4; ++mi) {
            int row = mi * 16 + lr;
            int sl = ((k0 >> 3) + lk) ^ (row & 7);
            af[mi] = *(const short8*)&Xs[row * 128 + sl * 8];
        }
#pragma unroll
        for (int ni = 0; ni < 3; ++ni) {
            int nrow = wid * 48 + ni * 16 + lr;
            int off = nrow * 32 + ((lk ^ ((nrow >> 1) & 3)) * 8);
            short8 bh = *(const short8*)&Wh[off];
#pragma unroll
            for (int mi = 0; mi < 4; ++mi)
                acc[mi][ni] = __builtin_amdgcn_mfma_f32_16x16x32_bf16(af[mi], bh, acc[mi][ni], 0, 0, 0);
        }
    }
    __syncthreads();                       // all W reads done; BufW -> Q

    // ---- write qkv (bf16 + bias) to Q[64][396] ----
    unsigned short* Q = BufW;
#pragma unroll
    for (int mi = 0; mi < 4; ++mi)
#pragma unroll
        for (int ni = 0; ni < 3; ++ni)
#pragma unroll
            for (int rr = 0; rr < 4; ++rr) {
                int row = mi * 16 + lg * 4 + rr;
                int col = wid * 48 + ni * 16 + lr;
                Q[row * 396 + col] = f2b(acc[mi][ni][rr] + qbias[col]);
            }
    __syncthreads();                       // Q visible

    // ---- prefetch out-proj W chunk 0 (hides under attention VALU) ----
    short8 po = *(const short8*)(Woa + owr * 128 + ows * 8);

    // ---- attention: 2 threads per (sample, tq, h4); each half of PV output ----
    float oa[16];
    int qr, h4, hf;
    {
        int tt = t & 255;
        h4 = tt & 3; int tq = (tt >> 2) & 3, s = tt >> 4;
        hf = t >> 8;                       // 0 or 1: output half
        qr = s * 4 + tq;
        const unsigned short* qp = Q + qr * 396 + h4 * 32;
        float q[32];
#pragma unroll
        for (int r = 0; r < 8; ++r) {
            u16x4 v = *(const u16x4*)(qp + r * 4);
#pragma unroll
            for (int w = 0; w < 4; ++w) q[r * 4 + w] = b2f(v[w]);
        }
        float sv[4];
#pragma unroll
        for (int u = 0; u < 4; ++u) {
            const unsigned short* kp = Q + (s * 4 + u) * 396 + 128 + h4 * 32;
            float dd = 0.f;
#pragma unroll
            for (int r = 0; r < 8; ++r) {
                u16x4 v = *(const u16x4*)(kp + r * 4);
#pragma unroll
                for (int w = 0; w < 4; ++w) dd += q[r * 4 + w] * b2f(v[w]);
            }
            sv[u] = dd * 0.176776695296637f;
        }
        float mx = fmaxf(fmaxf(sv[0], sv[1]), fmaxf(sv[2], sv[3]));
        float e0 = __expf(sv[0] - mx), e1 = __expf(sv[1] - mx);
        float e2 = __expf(sv[2] - mx), e3 = __expf(sv[3] - mx);
        float inv = 1.0f / (e0 + e1 + e2 + e3);
        float al[4] = { e0 * inv, e1 * inv, e2 * inv, e3 * inv };
#pragma unroll
        for (int w = 0; w < 16; ++w) oa[w] = 0.f;
#pragma unroll
        for (int u = 0; u < 4; ++u) {
            const unsigned short* vp = Q + (s * 4 + u) * 396 + 256 + h4 * 32 + hf * 16;
            float wgt = al[u];
#pragma unroll
            for (int r = 0; r < 4; ++r) {
                u16x4 v = *(const u16x4*)(vp + r * 4);
#pragma unroll
                for (int w = 0; w < 4; ++w) oa[r * 4 + w] += wgt * b2f(v[w]);
            }
        }
    }
    __syncthreads();                       // all Q reads done
    {                                      // write attn_o half into Xs (swizzled)
#pragma unroll
        for (int p = 0; p < 2; ++p) {
            short8 v;
#pragma unroll
            for (int w = 0; w < 8; ++w) v[w] = (short)f2b(oa[p * 8 + w]);
            int slot = h4 * 4 + hf * 2 + p;
            *(short8*)&Xs[qr * 128 + (slot ^ (qr & 7)) * 8] = v;
        }
    }

    // ---- out-proj: M=64, N=128 (wave owns 16 cols), K=128; single-plane W ----
    unsigned short* Wh2 = BufW;            // [128][32]
    floatx4 acc2[4] = {};                  // m-frag 0..3, col block wid*16

    for (int kc = 0; kc < 4; ++kc) {
        const int k0 = kc * 32;
        __syncthreads();                   // prior reads done (incl. attn Xs writes visible)
        {
            unsigned short* dst = Wh2 + owr * 32 + ((ows ^ ((owr >> 1) & 3)) * 8);
            *(short8*)dst = po;
        }
        __syncthreads();
        if (kc < 3) {
            const int k1 = k0 + 32;
            po = *(const short8*)(Woa + owr * 128 + k1 + ows * 8);
        }
        short8 af[4];
#pragma unroll
        for (int mi = 0; mi < 4; ++mi) {
            int row = mi * 16 + lr;
            int sl = ((k0 >> 3) + lk) ^ (row & 7);
            af[mi] = *(const short8*)&Xs[row * 128 + sl * 8];
        }
        {
            int nrow = wid * 16 + lr;
            int off = nrow * 32 + ((lk ^ ((nrow >> 1) & 3)) * 8);
            short8 bh = *(const short8*)&Wh2[off];
#pragma unroll
            for (int mi = 0; mi < 4; ++mi)
                acc2[mi] = __builtin_amdgcn_mfma_f32_16x16x32_bf16(af[mi], bh, acc2[mi], 0, 0, 0);
        }
    }

    // ---- epilogue: token-folded feat write ----
#pragma unroll
    for (int mi = 0; mi < 4; ++mi)
#pragma unroll
        for (int rr = 0; rr < 4; ++rr) {
            int row = mi * 16 + lg * 4 + rr;
            int s2 = row >> 2, tq2 = row & 3;
            long base = ((long)a * B_ + b0 + s2) * 1664 + foff + tq2 * 128;
            int col = wid * 16 + lr;
            feat[base + col] = f2b(acc2[mi][rr] + obias[col]);
        }
}

// ===== weight cast (f32 -> bf16 hi; lo plane only where wlo!=0; optional gate permute) =====
#define NW 19
struct WTab {
    const float* src[NW];
    long hoff[NW];
    long loff[NW];
    int n[NW];
    int npad[NW];
    int kc[NW];
    int wlo[NW];
};
__global__ void wcast_k(WTab tab, unsigned short* __restrict__ wb)
{
    const int e = blockIdx.y;
    const int np = tab.npad[e];
    const float* s = tab.src[e];
    unsigned short* dh = wb + tab.hoff[e];
    unsigned short* dl = wb + tab.loff[e];
    const int n = tab.n[e];
    const int kc = tab.kc[e];
    const int wlo = tab.wlo[e];
    for (long i = (long)blockIdx.x * 256 + threadIdx.x; i < np; i += (long)gridDim.x * 256) {
        long si = i;
        if (kc) {
            long per = 512l * kc;
            long ag = i / per;
            long rem = i - ag * per;
            int rp = (int)(rem / kc);
            int k = (int)(rem - (long)rp * kc);
            int srcr = (((rp & 63) >> 4) << 7) + ((rp >> 6) << 4) + (rp & 15);
            si = ag * per + (long)srcr * kc + k;
        }
        float v = (si < n) ? s[si] : 0.f;
        unsigned short h = f2b(v);
        dh[i] = h;
        if (wlo) dl[i] = f2b(v - b2f(h));
    }
}

// ===== prep: obs -> feat[:,0:128]; masked h/c states -> bf16 =====
__global__ void prep_k(const float* __restrict__ obs, const float* __restrict__ soh,
                       const float* __restrict__ sch, const float* __restrict__ soc,
                       const float* __restrict__ scc, const float* __restrict__ masks,
                       unsigned short* __restrict__ feat,
                       unsigned short* __restrict__ hmso, unsigned short* __restrict__ hmsc,
                       unsigned short* __restrict__ cmso, unsigned short* __restrict__ cmsc)
{
    long tid = (long)blockIdx.x * 256 + threadIdx.x;
    if (tid < 2097152) {
        int j = (int)(tid & 127);
        int row = (int)(tid >> 7);
        int b = row >> 3, aa = row & 7;
        feat[((long)aa * B_ + b) * 1664 + j] = f2b(obs[tid]);
        return;
    }
    long u = tid - 2097152;
    const float* src;
    unsigned short* dst;
    if (u < 4194304) { src = soh; dst = hmso; }
    else if (u < 2 * 4194304) { u -= 4194304; src = sch; dst = hmsc; }
    else if (u < 3 * 4194304) { u -= 2 * 4194304; src = soc; dst = cmso; }
    else { u -= 3 * 4194304; src = scc; dst = cmsc; }
    int j = (int)(u & 127);
    int b = (int)((u >> 7) & 2047);
    int aa = (int)((u >> 18) & 7);
    int l = (int)(u >> 21);
    float m = masks[b * 8 + aa];
    dst[u] = f2b(src[((long)(b * 8 + aa)) * 256 + l * 128 + j] * m);
}

// ===== GATv2 reduce (xlr combined [row][1024]: xl | xr) =====
__launch_bounds__(256)
__global__ void gat_reduce_k(const unsigned short* __restrict__ xlr,
                             const float* __restrict__ att, const float* __restrict__ bias,
                             unsigned short* __restrict__ feat, int coloff)
{
    __shared__ float xls[8][512];
    __shared__ float xrs[8][512];
    __shared__ float atts[512];
    __shared__ float es[8][8][4];
    __shared__ float as_[8][8][4];

    const int b = blockIdx.x;
    const int t = threadIdx.x;

    for (int i = t; i < 1024; i += 256) {
        int j = i >> 7, c4 = (i & 127) * 4;
        const unsigned short* base = xlr + ((long)j * B_ + b) * 1024;
        u16x4 vl = *(const u16x4*)(base + c4);
        u16x4 vr = *(const u16x4*)(base + 512 + c4);
#pragma unroll
        for (int q = 0; q < 4; ++q) {
            xls[j][c4 + q] = b2f(vl[q]);
            xrs[j][c4 + q] = b2f(vr[q]);
        }
    }
    for (int i = t; i < 128; i += 256)
        reinterpret_cast<float4*>(atts)[i] = reinterpret_cast<const float4*>(att)[i];
    __syncthreads();

    const int i = t >> 5, j = (t >> 2) & 7, h = t & 3;
    float e = 0.f;
    for (int cc = 0; cc < 128; ++cc) {
        int c = (cc + t) & 127;
        float s = xls[j][h * 128 + c] + xrs[i][h * 128 + c];
        s = s > 0.f ? s : 0.2f * s;
        e += s * atts[h * 128 + c];
    }
    es[i][j][h] = e;
    __syncthreads();

    float mx = -1e30f;
    for (int jj = 0; jj < 8; ++jj) mx = fmaxf(mx, es[i][jj][h]);
    float sum = 0.f;
    for (int jj = 0; jj < 8; ++jj) sum += __expf(es[i][jj][h] - mx);
    as_[i][j][h] = __expf(e - mx) / sum;
    __syncthreads();

    for (int idx = t; idx < 1024; idx += 256) {
        int ii = idx >> 7, c = idx & 127;
        float s = 0.f;
        for (int jj = 0; jj < 8; ++jj)
#pragma unroll
            for (int hh = 0; hh < 4; ++hh)
                s += as_[ii][jj][hh] * xls[jj][hh * 128 + c];
        s = s * 0.25f + bias[c];
        s = fmaxf(s, 0.f);
        feat[((long)ii * B_ + b) * 1664 + coloff + c] = f2b(s);
    }
}

// ===== log_softmax + transpose [A][B][14] -> (B,A,14) =====
__global__ void lsm_k(const float* __restrict__ logits, float* __restrict__ out)
{
    int tid = blockIdx.x * 256 + threadIdx.x;    // A*B
    int b = tid & (B_ - 1);
    int a = tid >> 11;
    const float* lp = logits + ((long)a * B_ + b) * ACT_;
    float x[ACT_];
    float mx = -1e30f;
#pragma unroll
    for (int n = 0; n < ACT_; ++n) { x[n] = lp[n]; mx = fmaxf(mx, x[n]); }
    float sum = 0.f;
#pragma unroll
    for (int n = 0; n < ACT_; ++n) sum += __expf(x[n] - mx);
    float ls = mx + logf(sum);
    float* op = out + ((long)b * A_ + a) * ACT_;
#pragma unroll
    for (int n = 0; n < ACT_; ++n) op[n] = x[n] - ls;
}

extern "C" void kernel_launch(void* const* d_in, const int* in_sizes, int n_in,
                              void* d_out, int out_size, void* d_ws, size_t ws_size,
                              hipStream_t stream)
{
    const float* obs    = (const float*)d_in[0];
    const float* somu_h = (const float*)d_in[1];
    const float* somu_c = (const float*)d_in[2];
    const float* scmu_h = (const float*)d_in[3];
    const float* scmu_c = (const float*)d_in[4];
    const float* masks  = (const float*)d_in[5];
    const float* gWl0 = (const float*)d_in[6],  *gbl0 = (const float*)d_in[7];
    const float* gWr0 = (const float*)d_in[8],  *gbr0 = (const float*)d_in[9];
    const float* gatt0 = (const float*)d_in[10], *gbias0 = (const float*)d_in[11];
    const float* gWl1 = (const float*)d_in[12], *gbl1 = (const float*)d_in[13];
    const float* gWr1 = (const float*)d_in[14], *gbr1 = (const float*)d_in[15];
    const float* gatt1 = (const float*)d_in[16], *gbias1 = (const float*)d_in[17];
    const float* soWih0 = (const float*)d_in[18], *soWhh0 = (const float*)d_in[19];
    const float* sobih0 = (const float*)d_in[20], *sobhh0 = (const float*)d_in[21];
    const float* soWih1 = (const float*)d_in[22], *soWhh1 = (const float*)d_in[23];
    const float* sobih1 = (const float*)d_in[24], *sobhh1 = (const float*)d_in[25];
    const float* soqw = (const float*)d_in[26], *soqb = (const float*)d_in[27];
    const float* soow = (const float*)d_in[28], *soob = (const float*)d_in[29];
    const float* scWih0 = (const float*)d_in[30], *scWhh0 = (const float*)d_in[31];
    const float* scbih0 = (const float*)d_in[32], *scbhh0 = (const float*)d_in[33];
    const float* scWih1 = (const float*)d_in[34], *scWhh1 = (const float*)d_in[35];
    const float* scbih1 = (const float*)d_in[36], *scbhh1 = (const float*)d_in[37];
    const float* scqw = (const float*)d_in[38], *scqb = (const float*)d_in[39];
    const float* scow = (const float*)d_in[40], *scob = (const float*)d_in[41];
    const float* fcw0 = (const float*)d_in[42], *fcb0 = (const float*)d_in[43];
    const float* fcw1 = (const float*)d_in[44], *fcb1 = (const float*)d_in[45];
    const float* actw = (const float*)d_in[46], *actb = (const float*)d_in[47];

    // ---------- workspace layout (~200 MB) ----------
    unsigned short* wb = (unsigned short*)d_ws;
    long wo = 0;
    auto nxt = [&](long n) { long c = wo; wo += n; return c; };
    const long o_gW0 = nxt(262144), o_gW1 = nxt(262144);
    const long o_soWih0 = nxt(2 * 524288), o_soWhh0 = nxt(2 * 524288);
    const long o_soWih1 = nxt(2 * 524288), o_soWhh1 = nxt(2 * 524288);
    const long o_soqw = nxt(2 * 393216), o_soow = nxt(2 * 131072);
    const long o_scWih0 = nxt(2 * 1572864), o_scWhh0 = nxt(2 * 524288);
    const long o_scWih1 = nxt(2 * 524288), o_scWhh1 = nxt(2 * 524288);
    const long o_scqw = nxt(2 * 393216), o_scow = nxt(2 * 131072);
    const long o_fcw0 = nxt(2 * 425984), o_fcw1 = nxt(2 * 65536);
    const long o_actw = nxt(2 * 32768);                         // weights end: 14,155,776

    unsigned short* feat   = wb + nxt(FP_);            // single plane
    unsigned short* hmso   = wb + nxt(4194304);
    unsigned short* hmsc   = wb + nxt(4194304);
    unsigned short* cmso   = wb + nxt(4194304);
    unsigned short* cmsc   = wb + nxt(4194304);
    unsigned short* arenaA = wb + nxt(25165824);       // xlr | x1,x2,logits
    unsigned short* arenaB = wb + nxt(16777216);       // tokS, tokC
    // total ≈ 100.1M shorts = 200 MB

    unsigned short* xlr    = arenaA;                   // GAT phase [16384][1024]
    unsigned short* tokS   = arenaB;                   // [A][B][4][128]
    unsigned short* tokC   = arenaB + 8388608;
    unsigned short* x1     = arenaA;                   // head phase (single plane)
    unsigned short* x2     = arenaA + 4194304;
    float*          logits = (float*)(arenaA + 8388608);

    // ---------- weight cast ----------
    WTab tab;
    int ei = 0;
    auto ent = [&](const float* s, long hoff, long loff, int n, int npad, int kc, int wlo) {
        tab.src[ei] = s; tab.hoff[ei] = hoff; tab.loff[ei] = loff;
        tab.n[ei] = n; tab.npad[ei] = npad; tab.kc[ei] = kc; tab.wlo[ei] = wlo; ++ei;
    };
    ent(gWl0, o_gW0,          o_gW0 + 131072,          65536, 65536, 0, 0);
    ent(gWr0, o_gW0 + 65536,  o_gW0 + 196608,          65536, 65536, 0, 0);
    ent(gWl1, o_gW1,          o_gW1 + 131072,          65536, 65536, 0, 0);
    ent(gWr1, o_gW1 + 65536,  o_gW1 + 196608,          65536, 65536, 0, 0);
    ent(soWih0, o_soWih0, o_soWih0 + 524288, 524288, 524288, 128, 0);
    ent(soWhh0, o_soWhh0, o_soWhh0 + 524288, 524288, 524288, 128, 0);
    ent(soWih1, o_soWih1, o_soWih1 + 524288, 524288, 524288, 128, 0);
    ent(soWhh1, o_soWhh1, o_soWhh1 + 524288, 524288, 524288, 128, 0);
    ent(soqw, o_soqw, o_soqw + 393216, 393216, 393216, 0, 0);
    ent(soow, o_soow, o_soow + 131072, 131072, 131072, 0, 0);
    ent(scWih0, o_scWih0, o_scWih0 + 1572864, 1572864, 1572864, 384, 0);
    ent(scWhh0, o_scWhh0, o_scWhh0 + 524288, 524288, 524288, 128, 0);
    ent(scWih1, o_scWih1, o_scWih1 + 524288, 524288, 524288, 128, 0);
    ent(scWhh1, o_scWhh1, o_scWhh1 + 524288, 524288, 524288, 128, 0);
    ent(scqw, o_scqw, o_scqw + 393216, 393216, 393216, 0, 0);
    ent(scow, o_scow, o_scow + 131072, 131072, 131072, 0, 0);
    ent(fcw0, o_fcw0, o_fcw0 + 425984, 425984, 425984, 0, 0);
    ent(fcw1, o_fcw1, o_fcw1 + 65536, 65536, 65536, 0, 0);
    ent(actw, o_actw, o_actw + 32768, 3584, 32768, 0, 1);
    wcast_k<<<dim3(1024, NW), 256, 0, stream>>>(tab, wb);

    prep_k<<<(2097152 + 4 * 4194304) / 256, 256, 0, stream>>>(
        obs, somu_h, scmu_h, somu_c, scmu_c, masks, feat, hmso, hmsc, cmso, cmsc);

    auto mkd = [&](const unsigned short* X1p, long xsa1, int ldx1, int K1,
                   const unsigned short* X2p, long xsa2, int ldx2, int K2,
                   long wo1, long wsa1, long wps1, long wo2, long wsa2, long wps2,
                   const float* bb1, long bsa1, const float* bb2, long bsa2,
                   void* Y, long ysa, int ldy, int N, int flags, int nA,
                   const unsigned short* cmsp, unsigned short* tokp, unsigned short* featp,
                   int layer, int foff) -> GDesc {
        GDesc d;
        d.X1 = X1p; d.X2 = X2p;
        d.W1 = wb + wo1; d.W2 = X2p ? wb + wo2 : nullptr;
        d.b1 = bb1; d.b2 = bb2; d.Y = Y;
        d.cms = cmsp; d.tokp = tokp; d.featp = featp;
        d.xsa1 = xsa1; d.xsa2 = xsa2;
        d.wsa1 = wsa1; d.wps1 = wps1; d.wsa2 = wsa2; d.wps2 = wps2;
        d.bsa1 = bsa1; d.bsa2 = bsa2; d.ysa = ysa;
        d.ldx1 = ldx1; d.K1 = K1; d.ldx2 = ldx2; d.K2 = K2; d.ldy = ldy; d.N = N;
        d.flags = flags; d.nA = nA; d.Nb = (N + 63) / 64;
        d.layer = layer; d.foff = foff;
        return d;
    };

    // ---------- descriptors ----------
    GDesc gat0 = mkd(feat, 0, 1664, 128, nullptr, 0, 0, 0,
                     o_gW0, 0, 131072, 0, 0, 0, gbl0, 0, gbr0, 0,
                     xlr, 0, 1024, 1024, 2 | 8, 1, nullptr, nullptr, nullptr, 0, 0);
    GDesc gat1 = mkd(feat + 128, 0, 1664, 128, nullptr, 0, 0, 0,
                     o_gW1, 0, 131072, 0, 0, 0, gbl1, 0, gbr1, 0,
                     xlr, 0, 1024, 1024, 2 | 8, 1, nullptr, nullptr, nullptr, 0, 0);
    GDesc so0  = mkd(feat, (long)B_ * 1664, 1664, 128, hmso, (long)B_ * 128, 128, 128,
                     o_soWih0, 512l * 128, 524288, o_soWhh0, 512l * 128, 524288,
                     sobih0, 512, sobhh0, 512, nullptr, 0, 0, 512, 16, A_,
                     cmso, tokS, nullptr, 0, 0);
    GDesc so1  = mkd(tokS, (long)B_ * 512, 512, 128, hmso + 2097152, (long)B_ * 128, 128, 128,
                     o_soWih1, 512l * 128, 524288, o_soWhh1, 512l * 128, 524288,
                     sobih1, 512, sobhh1, 512, nullptr, 0, 0, 512, 16, A_,
                     cmso, tokS, feat, 1, 384);
    GDesc sc0  = mkd(feat, (long)B_ * 1664, 1664, 384, hmsc, (long)B_ * 128, 128, 128,
                     o_scWih0, 512l * 384, 1572864, o_scWhh0, 512l * 128, 524288,
                     scbih0, 512, scbhh0, 512, nullptr, 0, 0, 512, 16, A_,
                     cmsc, tokC, nullptr, 0, 0);
    GDesc sc1  = mkd(tokC, (long)B_ * 512, 512, 128, hmsc + 2097152, (long)B_ * 128, 128, 128,
                     o_scWih1, 512l * 128, 524288, o_scWhh1, 512l * 128, 524288,
                     scbih1, 512, scbhh1, 512, nullptr, 0, 0, 512, 16, A_,
                     cmsc, tokC, feat, 1, 1024);
    GDesc fc0d = mkd(feat, 0, 1664, 1664, nullptr, 0, 0, 0,
                     o_fcw0, 0, 425984, 0, 0, 0, fcb0, 0, nullptr, 0,
                     x1, 0, 256, 256, 1 | 2, 1, nullptr, nullptr, nullptr, 0, 0);
    GDesc fc1d = mkd(x1, 0, 256, 256, nullptr, 0, 0, 0,
                     o_fcw1, 0, 65536, 0, 0, 0, fcb1, 0, nullptr, 0,
                     x2, 0, 256, 256, 1 | 2, 1, nullptr, nullptr, nullptr, 0, 0);
    GDesc actd = mkd(x2, 0, 256, 256, nullptr, 0, 0, 0,
                     o_actw, 0, 32768, 0, 0, 0, actb, 0, nullptr, 0,
                     logits, 0, ACT_, ACT_, 0, 1, nullptr, nullptr, nullptr, 0, 0);

    // grid helpers: MI=2 -> BM=128, MI=1 -> BM=64
    auto grid2 = [&](const GDesc& d, int M) { return d.nA * (M / 128) * d.Nb; };
    auto grid1 = [&](const GDesc& d, int M) { return d.nA * (M / 64) * d.Nb; };

    // ---------- schedule ----------
    mgemm_t<2, 0><<<grid2(gat0, 16384), 256, 0, stream>>>(gat0);
    gat_reduce_k<<<B_, 256, 0, stream>>>(xlr, gatt0, gbias0, feat, 128);
    mgemm_t<2, 0><<<grid2(gat1, 16384), 256, 0, stream>>>(gat1);
    gat_reduce_k<<<B_, 256, 0, stream>>>(xlr, gatt1, gbias1, feat, 256);

    mgemm_t<1, 0><<<grid1(so0, B_), 256, 0, stream>>>(so0);
    mgemm_t<1, 0><<<grid1(so1, B_), 256, 0, stream>>>(so1);
    mgemm_t<1, 0><<<grid1(sc0, B_), 256, 0, stream>>>(sc0);
    mgemm_t<1, 0><<<grid1(sc1, B_), 256, 0, stream>>>(sc1);

    sattn_k<<<2048, 512, 0, stream>>>(tokS, tokC,
                                      wb + o_soqw, wb + o_scqw, soqb, scqb,
                                      wb + o_soow, wb + o_scow, soob, scob,
                                      feat);

    mgemm_t<2, 0><<<grid2(fc0d, 16384), 256, 0, stream>>>(fc0d);
    mgemm_t<2, 0><<<grid2(fc1d, 16384), 256, 0, stream>>>(fc1d);
    mgemm_t<2, 1><<<grid2(actd, 16384), 256, 0, stream>>>(actd);
    lsm_k<<<A_ * B_ / 256, 256, 0, stream>>>(logits, (float*)d_out);
}

// Round 25
// 322.771 us; speedup vs baseline: 1.3584x; 1.0356x over previous
//
#include <hip/hip_runtime.h>
#include <math.h>

#define B_ 2048
#define A_ 8
#define ACT_ 14
#define FP_ 27262976l   // feat stride (16384*1664), single bf16 plane
#define BIGSPLIT (1 << 30)

typedef short short8 __attribute__((ext_vector_type(8)));
typedef float floatx4 __attribute__((ext_vector_type(4)));
typedef unsigned short u16x4 __attribute__((ext_vector_type(4)));

__device__ __forceinline__ unsigned short f2b(float f) {
    unsigned u = __float_as_uint(f);
    u += 0x7fff + ((u >> 16) & 1);
    return (unsigned short)(u >> 16);
}
__device__ __forceinline__ float b2f(unsigned short h) {
    return __uint_as_float(((unsigned)h) << 16);
}
__device__ __forceinline__ float sigm_(float x) { return 1.0f / (1.0f + __expf(-x)); }
__device__ __forceinline__ float tanh_(float x) { return 1.0f - 2.0f / (1.0f + __expf(2.0f * x)); }

// ===== bf16 MFMA GEMM: (MI*64)x64 tiles; TT=1 -> exact hi/lo W (2-term), TT=0 -> hi only.
// ===== single-bf16 activations, ping-pong LDS (1 barrier/chunk), depth-4 reg prefetch.
// ===== Takes TWO descriptors + split: blocks >= split run dB (merged independent GEMMs).
// flags: 1=relu, 2=bf16 out, 4=token-fold rows, 8=split bias at col 512,
//        16=LSTM epilogue (W gate-permuted at cast; writes tok/feat, skips Y).
struct GDesc {
    const unsigned short *X1, *X2, *W1, *W2;
    const float *b1, *b2;
    void* Y;
    const unsigned short* cms;       // masked bf16 c-state [l][a][b][j]
    unsigned short* tokp;
    unsigned short* featp;
    long xsa1, xsa2, wsa1, wps1, wsa2, wps2, bsa1, bsa2, ysa;
    int ldx1, K1, ldx2, K2, ldy, N, flags, nA, Nb, layer, foff;
};

#define LOADC(c, xh, whv, wlv) do {                                                       \
    const unsigned short *Xb_, *Wb_; int ldx_, K_, k0_; long wps_;                        \
    if ((c) < nC1) { Xb_ = X1; ldx_ = ldx1; K_ = K1; wps_ = wps1; Wb_ = W1; k0_ = (c) << 5; } \
    else { Xb_ = X2; ldx_ = ldx2; K_ = K2; wps_ = wps2; Wb_ = W2; k0_ = ((c) - nC1) << 5; } \
    _Pragma("unroll") for (int mi_ = 0; mi_ < MI; ++mi_) {                                \
        int row_ = xr0 + mi_ * 16 + lrow;                                                 \
        xh[mi_] = *(const short8*)(Xb_ + (long)(bm + row_) * ldx_ + k0_ + lslot * 8); }   \
    { int row_ = wr0 + lrow;                                                              \
      const unsigned short* wp_ = Wb_ + (long)(bn + row_) * K_ + k0_ + lslot * 8;         \
      whv = *(const short8*)wp_;                                                          \
      if (TT) wlv = *(const short8*)(wp_ + wps_); }                                       \
} while (0)

#define STOREC(P, xh, whv, wlv) do {                                                      \
    _Pragma("unroll") for (int mi_ = 0; mi_ < MI; ++mi_) {                                \
        int row_ = xr0 + mi_ * 16 + lrow; int sl_ = lslot ^ ((row_ >> 1) & 3);            \
        *(short8*)&Xh_l[P][row_ * 32 + sl_ * 8] = xh[mi_]; }                              \
    { int row_ = wr0 + lrow; int sl_ = lslot ^ ((row_ >> 1) & 3);                         \
      *(short8*)&Wh_l[P][row_ * 32 + sl_ * 8] = whv;                                      \
      if (TT) *(short8*)&Wl_l[P][row_ * 32 + sl_ * 8] = wlv; }                            \
} while (0)

#define COMPUTEC(P) do {                                                                  \
    short8 bh[4], bl[4];                                                                  \
    _Pragma("unroll") for (int ni = 0; ni < 4; ++ni) {                                    \
        int row_ = ni * 16 + lr; int off_ = row_ * 32 + ((lk ^ ((row_ >> 1) & 3)) * 8);   \
        bh[ni] = *(const short8*)&Wh_l[P][off_];                                          \
        if (TT) bl[ni] = *(const short8*)&Wl_l[P][off_]; }                                \
    _Pragma("unroll") for (int mi = 0; mi < MI; ++mi) {                                   \
        int row_ = xr0 + mi * 16 + lr; int off_ = row_ * 32 + ((lk ^ ((row_ >> 1) & 3)) * 8); \
        short8 ah = *(const short8*)&Xh_l[P][off_];                                       \
        _Pragma("unroll") for (int ni = 0; ni < 4; ++ni)                                  \
            acc[mi][ni] = __builtin_amdgcn_mfma_f32_16x16x32_bf16(ah, bh[ni], acc[mi][ni], 0, 0, 0); \
        if (TT) {                                                                         \
            _Pragma("unroll") for (int ni = 0; ni < 4; ++ni)                              \
                acc[mi][ni] = __builtin_amdgcn_mfma_f32_16x16x32_bf16(ah, bl[ni], acc[mi][ni], 0, 0, 0); \
        }                                                                                 \
    }                                                                                     \
} while (0)

template<int MI, int TT>
__launch_bounds__(256)
__global__ void mgemm_t(GDesc dA, GDesc dB, int split)
{
    __shared__ __align__(16) unsigned short Xh_l[2][MI * 64 * 32];
    __shared__ __align__(16) unsigned short Wh_l[2][64 * 32];
    __shared__ __align__(16) unsigned short Wl_l[2][TT ? 64 * 32 : 8];

    int wg = blockIdx.x;
    GDesc d = dA;
    if (wg >= split) { d = dB; wg -= split; }

    const unsigned short* X1 = d.X1; const unsigned short* X2 = d.X2;
    const unsigned short* W1 = d.W1; const unsigned short* W2 = d.W2;
    const float* b1 = d.b1; const float* b2 = d.b2;
    const long wps1 = d.wps1, wps2 = d.wps2, ysa = d.ysa;
    const int ldx1 = d.ldx1, K1 = d.K1, ldx2 = d.ldx2, K2 = d.K2;
    const int ldy = d.ldy, N = d.N, flags = d.flags, nA = d.nA, Nb = d.Nb;
    const int layer = d.layer, foff = d.foff;

    int a, mb, nb;
    if (nA == 8) { a = wg & 7; int q = wg >> 3; nb = q % Nb; mb = q / Nb; }
    else { a = 0; int x8 = wg & 7; int q = wg >> 3; nb = q % Nb; mb = (q / Nb) * 8 + x8; }

    X1 += (long)a * d.xsa1;
    W1 += (long)a * d.wsa1;
    if (X2) { X2 += (long)a * d.xsa2; W2 += (long)a * d.wsa2; }
    if (b1) b1 += (long)a * d.bsa1;
    if (b2) b2 += (long)a * d.bsa2;

    const int bm = mb * (MI * 64);
    const int bn = nb * 64;
    const int t = threadIdx.x;
    const int lane = t & 63, wid = t >> 6;

    floatx4 acc[MI][4] = {};

    const int xr0 = wid * (MI * 16);
    const int wr0 = wid * 16;
    const int lrow = lane >> 2;
    const int lslot = lane & 3;
    const int lr = lane & 15, lk = lane >> 4;

    const int nC1 = K1 >> 5;
    const int nC = nC1 + (X2 ? (K2 >> 5) : 0);

    short8 Axh[MI], Awh, Awl;
    short8 Bxh[MI], Bwh, Bwl;
    short8 Cxh[MI], Cwh, Cwl;
    short8 Dxh[MI], Dwh, Dwl;

    LOADC(0, Axh, Awh, Awl);
    if (nC > 1) LOADC(1, Bxh, Bwh, Bwl);
    if (nC > 2) LOADC(2, Cxh, Cwh, Cwl);
    if (nC > 3) LOADC(3, Dxh, Dwh, Dwl);

    for (int c = 0; c < nC; c += 4) {
        STOREC(0, Axh, Awh, Awl);
        __syncthreads();
        if (c + 4 < nC) LOADC(c + 4, Axh, Awh, Awl);
        COMPUTEC(0);
        if (c + 1 < nC) {
            STOREC(1, Bxh, Bwh, Bwl);
            __syncthreads();
            if (c + 5 < nC) LOADC(c + 5, Bxh, Bwh, Bwl);
            COMPUTEC(1);
        }
        if (c + 2 < nC) {
            STOREC(0, Cxh, Cwh, Cwl);
            __syncthreads();
            if (c + 6 < nC) LOADC(c + 6, Cxh, Cwh, Cwl);
            COMPUTEC(0);
        }
        if (c + 3 < nC) {
            STOREC(1, Dxh, Dwh, Dwl);
            __syncthreads();
            if (c + 7 < nC) LOADC(c + 7, Dxh, Dwh, Dwl);
            COMPUTEC(1);
        }
    }

    const int lg = lane >> 4;

    if (flags & 16) {
        // fused LSTM pointwise epilogue (W rows gate-permuted at cast); j = nb*16 + lr
        const int j = (bn >> 2) + lr;
        unsigned short* tokp = d.tokp;
        unsigned short* featp = d.featp;
        const unsigned short* cms = d.cms;
#pragma unroll
        for (int mi = 0; mi < MI; ++mi) {
#pragma unroll
            for (int r = 0; r < 4; ++r) {
                const int b = bm + xr0 + mi * 16 + lg * 4 + r;
                float iv = acc[mi][0][r] + b1[j]       + b2[j];
                float fv = acc[mi][1][r] + b1[128 + j] + b2[128 + j];
                float gv = acc[mi][2][r] + b1[256 + j] + b2[256 + j];
                float ov = acc[mi][3][r] + b1[384 + j] + b2[384 + j];
                iv = sigm_(iv); fv = sigm_(fv); gv = tanh_(gv); ov = sigm_(ov);
                float cp = b2f(cms[(long)layer * 2097152 + (long)a * 262144 + b * 128 + j]);
                float c2 = fv * cp + iv * gv;
                float hv = ov * tanh_(c2);
                long tb = ((long)a * B_ + b) * 512;
                tokp[tb + layer * 128 + j] = f2b(hv);
                tokp[tb + (2 + layer) * 128 + j] = f2b(c2);
                if (featp) featp[((long)a * B_ + b) * 1664 + foff + j] = f2b(hv);
            }
        }
        return;
    }

    const bool relu = flags & 1, obf = flags & 2, fold = flags & 4, sbias = flags & 8;
    float* Yf = (float*)d.Y;
    unsigned short* Yh = (unsigned short*)d.Y;
#pragma unroll
    for (int mi = 0; mi < MI; ++mi) {
#pragma unroll
        for (int r = 0; r < 4; ++r) {
            int gm = bm + xr0 + mi * 16 + lg * 4 + r;
            long rowoff = fold ? ((long)(gm >> 2) * ldy + (gm & 3) * 128) : (long)gm * ldy;
            rowoff += (long)a * ysa;
#pragma unroll
            for (int ni = 0; ni < 4; ++ni) {
                int gc = bn + ni * 16 + lr;
                if (gc < N) {
                    float v = acc[mi][ni][r];
                    if (sbias) v += (gc < 512) ? b1[gc] : b2[gc - 512];
                    else { if (b1) v += b1[gc]; if (b2) v += b2[gc]; }
                    if (relu) v = fmaxf(v, 0.f);
                    if (obf) Yh[rowoff + gc] = f2b(v);
                    else     Yf[rowoff + gc] = v;
                }
            }
        }
    }
}

// ===== fused qkv-GEMM + 4-token MHA + out-proj, BOTH chains, 512 thr (8 waves) =====
// v6: double-buffered W staging (1 barrier/chunk in both GEMM loops; 11 barriers total
// vs 19). Single-plane W; Q stride 396; fast-exp softmax. Numerics identical to v5.
__launch_bounds__(512)
__global__ void sattn_k(const unsigned short* __restrict__ tokS,
                        const unsigned short* __restrict__ tokC,
                        const unsigned short* __restrict__ WqS,
                        const unsigned short* __restrict__ WqC,
                        const float* __restrict__ qbS, const float* __restrict__ qbC,
                        const unsigned short* __restrict__ WoS,
                        const unsigned short* __restrict__ WoC,
                        const float* __restrict__ obS, const float* __restrict__ obC,
                        unsigned short* __restrict__ feat)
{
    __shared__ __align__(16) unsigned short Xs[64 * 128];    // tok tile -> attn_o (reused)
    __shared__ __align__(16) unsigned short BufW[25600];     // 2xWh[384][32] | Q[64][396] | 2xWo[128][32]
    __shared__ float qbias[384];
    __shared__ float obias[128];

    int bid = blockIdx.x;
    const unsigned short* tok; const unsigned short* Wq; const float* qb;
    const unsigned short* Wo; const float* ob; int foff;
    if (bid < 1024) { tok = tokS; Wq = WqS; qb = qbS; Wo = WoS; ob = obS; foff = 512; }
    else { bid -= 1024; tok = tokC; Wq = WqC; qb = qbC; Wo = WoC; ob = obC; foff = 1152; }

    const int a = bid & 7;               // agent-per-XCD
    const int g = bid >> 3;              // 0..127
    const int b0 = g * 16;

    const unsigned short* Wqa = Wq + (long)a * 49152;
    const unsigned short* Woa = Wo + (long)a * 16384;
    const unsigned short* tokb = tok + ((long)a * B_ + b0) * 512;

    const int t = threadIdx.x;
    const int lane = t & 63, wid = t >> 6;          // wid 0..7
    const int lr = lane & 15, lk = lane >> 4, lg = lane >> 4;

    // ---- per-thread W slot geometry (qkv: 3 slots of 1536; outproj: 1 of 512) ----
    int qwr[3], qws[3];
#pragma unroll
    for (int j = 0; j < 3; ++j) {
        int idx = t + j * 512;
        qwr[j] = idx >> 2; qws[j] = idx & 3;
    }
    const int owr = t >> 2, ows = t & 3;            // t < 512 covers all 512 slots

    // ---- stage X (64x128, slot-swizzled s^(r&7)) + biases ----
    for (int idx = t; idx < 1024; idx += 512) {
        int r = idx >> 4, s = idx & 15;
        *(short8*)&Xs[r * 128 + (s ^ (r & 7)) * 8] = *(const short8*)(tokb + r * 128 + s * 8);
    }
    if (t < 384) qbias[t] = qb[a * 384 + t];
    if (t < 128) obias[t] = ob[a * 128 + t];

    unsigned short* Wh0 = BufW;            // [384][32]
    unsigned short* Wh1 = BufW + 12288;    // [384][32]

    short8 pw[3];
#pragma unroll
    for (int j = 0; j < 3; ++j)
        pw[j] = *(const short8*)(Wqa + qwr[j] * 128 + qws[j] * 8);
#pragma unroll
    for (int j = 0; j < 3; ++j)            // chunk 0 -> buf0 (pre-barrier)
        *(short8*)(Wh0 + qwr[j] * 32 + ((qws[j] ^ ((qwr[j] >> 1) & 3)) * 8)) = pw[j];
#pragma unroll
    for (int j = 0; j < 3; ++j)            // prefetch chunk 1
        pw[j] = *(const short8*)(Wqa + qwr[j] * 128 + 32 + qws[j] * 8);

    __syncthreads();                       // bar: Xs + biases + Wh0 visible

    floatx4 acc[4][3] = {};                // m-frag 0..3 (rows), n-frag 0..2 (cols wid*48+)

#pragma unroll
    for (int kc = 0; kc < 4; ++kc) {
        const int k0 = kc * 32;
        unsigned short* cur = (kc & 1) ? Wh1 : Wh0;
        unsigned short* nxt = (kc & 1) ? Wh0 : Wh1;
        if (kc < 3) {
            // write chunk kc+1 into the buffer whose readers finished at the last barrier
#pragma unroll
            for (int j = 0; j < 3; ++j)
                *(short8*)(nxt + qwr[j] * 32 + ((qws[j] ^ ((qwr[j] >> 1) & 3)) * 8)) = pw[j];
            if (kc < 2) {
#pragma unroll
                for (int j = 0; j < 3; ++j)
                    pw[j] = *(const short8*)(Wqa + qwr[j] * 128 + k0 + 64 + qws[j] * 8);
            }
        }
        short8 af[4];
#pragma unroll
        for (int mi = 0; mi < 4; ++mi) {
            int row = mi * 16 + lr;
            int sl = ((k0 >> 3) + lk) ^ (row & 7);
            af[mi] = *(const short8*)&Xs[row * 128 + sl * 8];
        }
#pragma unroll
        for (int ni = 0; ni < 3; ++ni) {
            int nrow = wid * 48 + ni * 16 + lr;
            int off = nrow * 32 + ((lk ^ ((nrow >> 1) & 3)) * 8);
            short8 bh = *(const short8*)&cur[off];
#pragma unroll
            for (int mi = 0; mi < 4; ++mi)
                acc[mi][ni] = __builtin_amdgcn_mfma_f32_16x16x32_bf16(af[mi], bh, acc[mi][ni], 0, 0, 0);
        }
        __syncthreads();                   // 1 barrier/chunk (last one guards Q overwrite)
    }

    // ---- write qkv (bf16 + bias) to Q[64][396] ----
    unsigned short* Q = BufW;
#pragma unroll
    for (int mi = 0; mi < 4; ++mi)
#pragma unroll
        for (int ni = 0; ni < 3; ++ni)
#pragma unroll
            for (int rr = 0; rr < 4; ++rr) {
                int row = mi * 16 + lg * 4 + rr;
                int col = wid * 48 + ni * 16 + lr;
                Q[row * 396 + col] = f2b(acc[mi][ni][rr] + qbias[col]);
            }
    __syncthreads();                       // bar: Q visible

    // ---- prefetch out-proj W chunk 0 (hides under attention VALU) ----
    short8 po = *(const short8*)(Woa + owr * 128 + ows * 8);

    // ---- attention: 2 threads per (sample, tq, h4); each half of PV output ----
    float oa[16];
    int qr, h4, hf;
    {
        int tt = t & 255;
        h4 = tt & 3; int tq = (tt >> 2) & 3, s = tt >> 4;
        hf = t >> 8;                       // 0 or 1: output half
        qr = s * 4 + tq;
        const unsigned short* qp = Q + qr * 396 + h4 * 32;
        float q[32];
#pragma unroll
        for (int r = 0; r < 8; ++r) {
            u16x4 v = *(const u16x4*)(qp + r * 4);
#pragma unroll
            for (int w = 0; w < 4; ++w) q[r * 4 + w] = b2f(v[w]);
        }
        float sv[4];
#pragma unroll
        for (int u = 0; u < 4; ++u) {
            const unsigned short* kp = Q + (s * 4 + u) * 396 + 128 + h4 * 32;
            float dd = 0.f;
#pragma unroll
            for (int r = 0; r < 8; ++r) {
                u16x4 v = *(const u16x4*)(kp + r * 4);
#pragma unroll
                for (int w = 0; w < 4; ++w) dd += q[r * 4 + w] * b2f(v[w]);
            }
            sv[u] = dd * 0.176776695296637f;
        }
        float mx = fmaxf(fmaxf(sv[0], sv[1]), fmaxf(sv[2], sv[3]));
        float e0 = __expf(sv[0] - mx), e1 = __expf(sv[1] - mx);
        float e2 = __expf(sv[2] - mx), e3 = __expf(sv[3] - mx);
        float inv = 1.0f / (e0 + e1 + e2 + e3);
        float al[4] = { e0 * inv, e1 * inv, e2 * inv, e3 * inv };
#pragma unroll
        for (int w = 0; w < 16; ++w) oa[w] = 0.f;
#pragma unroll
        for (int u = 0; u < 4; ++u) {
            const unsigned short* vp = Q + (s * 4 + u) * 396 + 256 + h4 * 32 + hf * 16;
            float wgt = al[u];
#pragma unroll
            for (int r = 0; r < 4; ++r) {
                u16x4 v = *(const u16x4*)(vp + r * 4);
#pragma unroll
                for (int w = 0; w < 4; ++w) oa[r * 4 + w] += wgt * b2f(v[w]);
            }
        }
    }
    __syncthreads();                       // bar: all Q reads done (BufW dead)

    // ---- attn_o -> Xs AND out-proj chunk-0 staging share one barrier ----
    {
#pragma unroll
        for (int p = 0; p < 2; ++p) {
            short8 v;
#pragma unroll
            for (int w = 0; w < 8; ++w) v[w] = (short)f2b(oa[p * 8 + w]);
            int slot = h4 * 4 + hf * 2 + p;
            *(short8*)&Xs[qr * 128 + (slot ^ (qr & 7)) * 8] = v;
        }
    }
    unsigned short* W20 = BufW;            // [128][32]
    unsigned short* W21 = BufW + 4096;     // [128][32]
    *(short8*)(W20 + owr * 32 + ((ows ^ ((owr >> 1) & 3)) * 8)) = po;
    po = *(const short8*)(Woa + owr * 128 + 32 + ows * 8);   // prefetch chunk 1
    __syncthreads();                       // bar: attn Xs + W20 visible

    // ---- out-proj: M=64, N=128 (wave owns 16 cols), K=128; double-buffered W ----
    floatx4 acc2[4] = {};                  // m-frag 0..3, col block wid*16
#pragma unroll
    for (int kc = 0; kc < 4; ++kc) {
        const int k0 = kc * 32;
        unsigned short* cur = (kc & 1) ? W21 : W20;
        unsigned short* nxt = (kc & 1) ? W20 : W21;
        if (kc < 3) {
            *(short8*)(nxt + owr * 32 + ((ows ^ ((owr >> 1) & 3)) * 8)) = po;
            if (kc < 2)
                po = *(const short8*)(Woa + owr * 128 + k0 + 64 + ows * 8);
        }
        short8 af[4];
#pragma unroll
        for (int mi = 0; mi < 4; ++mi) {
            int row = mi * 16 + lr;
            int sl = ((k0 >> 3) + lk) ^ (row & 7);
            af[mi] = *(const short8*)&Xs[row * 128 + sl * 8];
        }
        {
            int nrow = wid * 16 + lr;
            int off = nrow * 32 + ((lk ^ ((nrow >> 1) & 3)) * 8);
            short8 bh = *(const short8*)&cur[off];
#pragma unroll
            for (int mi = 0; mi < 4; ++mi)
                acc2[mi] = __builtin_amdgcn_mfma_f32_16x16x32_bf16(af[mi], bh, acc2[mi], 0, 0, 0);
        }
        if (kc < 3) __syncthreads();       // no trailing barrier before epilogue
    }

    // ---- epilogue: token-folded feat write ----
#pragma unroll
    for (int mi = 0; mi < 4; ++mi)
#pragma unroll
        for (int rr = 0; rr < 4; ++rr) {
            int row = mi * 16 + lg * 4 + rr;
            int s2 = row >> 2, tq2 = row & 3;
            long base = ((long)a * B_ + b0 + s2) * 1664 + foff + tq2 * 128;
            int col = wid * 16 + lr;
            feat[base + col] = f2b(acc2[mi][rr] + obias[col]);
        }
}

// ===== weight cast (f32 -> bf16 hi; lo plane only where wlo!=0; optional gate permute) =====
#define NW 19
struct WTab {
    const float* src[NW];
    long hoff[NW];
    long loff[NW];
    int n[NW];
    int npad[NW];
    int kc[NW];
    int wlo[NW];
};
__global__ void wcast_k(WTab tab, unsigned short* __restrict__ wb)
{
    const int e = blockIdx.y;
    const int np = tab.npad[e];
    const float* s = tab.src[e];
    unsigned short* dh = wb + tab.hoff[e];
    unsigned short* dl = wb + tab.loff[e];
    const int n = tab.n[e];
    const int kc = tab.kc[e];
    const int wlo = tab.wlo[e];
    for (long i = (long)blockIdx.x * 256 + threadIdx.x; i < np; i += (long)gridDim.x * 256) {
        long si = i;
        if (kc) {
            long per = 512l * kc;
            long ag = i / per;
            long rem = i - ag * per;
            int rp = (int)(rem / kc);
            int k = (int)(rem - (long)rp * kc);
            int srcr = (((rp & 63) >> 4) << 7) + ((rp >> 6) << 4) + (rp & 15);
            si = ag * per + (long)srcr * kc + k;
        }
        float v = (si < n) ? s[si] : 0.f;
        unsigned short h = f2b(v);
        dh[i] = h;
        if (wlo) dl[i] = f2b(v - b2f(h));
    }
}

// ===== prep: obs -> feat[:,0:128]; masked h/c states -> bf16 =====
__global__ void prep_k(const float* __restrict__ obs, const float* __restrict__ soh,
                       const float* __restrict__ sch, const float* __restrict__ soc,
                       const float* __restrict__ scc, const float* __restrict__ masks,
                       unsigned short* __restrict__ feat,
                       unsigned short* __restrict__ hmso, unsigned short* __restrict__ hmsc,
                       unsigned short* __restrict__ cmso, unsigned short* __restrict__ cmsc)
{
    long tid = (long)blockIdx.x * 256 + threadIdx.x;
    if (tid < 2097152) {
        int j = (int)(tid & 127);
        int row = (int)(tid >> 7);
        int b = row >> 3, aa = row & 7;
        feat[((long)aa * B_ + b) * 1664 + j] = f2b(obs[tid]);
        return;
    }
    long u = tid - 2097152;
    const float* src;
    unsigned short* dst;
    if (u < 4194304) { src = soh; dst = hmso; }
    else if (u < 2 * 4194304) { u -= 4194304; src = sch; dst = hmsc; }
    else if (u < 3 * 4194304) { u -= 2 * 4194304; src = soc; dst = cmso; }
    else { u -= 3 * 4194304; src = scc; dst = cmsc; }
    int j = (int)(u & 127);
    int b = (int)((u >> 7) & 2047);
    int aa = (int)((u >> 18) & 7);
    int l = (int)(u >> 21);
    float m = masks[b * 8 + aa];
    dst[u] = f2b(src[((long)(b * 8 + aa)) * 256 + l * 128 + j] * m);
}

// ===== GATv2 reduce (xlr combined [row][1024]: xl | xr) =====
__launch_bounds__(256)
__global__ void gat_reduce_k(const unsigned short* __restrict__ xlr,
                             const float* __restrict__ att, const float* __restrict__ bias,
                             unsigned short* __restrict__ feat, int coloff)
{
    __shared__ float xls[8][512];
    __shared__ float xrs[8][512];
    __shared__ float atts[512];
    __shared__ float es[8][8][4];
    __shared__ float as_[8][8][4];

    const int b = blockIdx.x;
    const int t = threadIdx.x;

    for (int i = t; i < 1024; i += 256) {
        int j = i >> 7, c4 = (i & 127) * 4;
        const unsigned short* base = xlr + ((long)j * B_ + b) * 1024;
        u16x4 vl = *(const u16x4*)(base + c4);
        u16x4 vr = *(const u16x4*)(base + 512 + c4);
#pragma unroll
        for (int q = 0; q < 4; ++q) {
            xls[j][c4 + q] = b2f(vl[q]);
            xrs[j][c4 + q] = b2f(vr[q]);
        }
    }
    for (int i = t; i < 128; i += 256)
        reinterpret_cast<float4*>(atts)[i] = reinterpret_cast<const float4*>(att)[i];
    __syncthreads();

    const int i = t >> 5, j = (t >> 2) & 7, h = t & 3;
    float e = 0.f;
    for (int cc = 0; cc < 128; ++cc) {
        int c = (cc + t) & 127;
        float s = xls[j][h * 128 + c] + xrs[i][h * 128 + c];
        s = s > 0.f ? s : 0.2f * s;
        e += s * atts[h * 128 + c];
    }
    es[i][j][h] = e;
    __syncthreads();

    float mx = -1e30f;
    for (int jj = 0; jj < 8; ++jj) mx = fmaxf(mx, es[i][jj][h]);
    float sum = 0.f;
    for (int jj = 0; jj < 8; ++jj) sum += __expf(es[i][jj][h] - mx);
    as_[i][j][h] = __expf(e - mx) / sum;
    __syncthreads();

    for (int idx = t; idx < 1024; idx += 256) {
        int ii = idx >> 7, c = idx & 127;
        float s = 0.f;
        for (int jj = 0; jj < 8; ++jj)
#pragma unroll
            for (int hh = 0; hh < 4; ++hh)
                s += as_[ii][jj][hh] * xls[jj][hh * 128 + c];
        s = s * 0.25f + bias[c];
        s = fmaxf(s, 0.f);
        feat[((long)ii * B_ + b) * 1664 + coloff + c] = f2b(s);
    }
}

// ===== log_softmax + transpose [A][B][14] -> (B,A,14) =====
__global__ void lsm_k(const float* __restrict__ logits, float* __restrict__ out)
{
    int tid = blockIdx.x * 256 + threadIdx.x;    // A*B
    int b = tid & (B_ - 1);
    int a = tid >> 11;
    const float* lp = logits + ((long)a * B_ + b) * ACT_;
    float x[ACT_];
    float mx = -1e30f;
#pragma unroll
    for (int n = 0; n < ACT_; ++n) { x[n] = lp[n]; mx = fmaxf(mx, x[n]); }
    float sum = 0.f;
#pragma unroll
    for (int n = 0; n < ACT_; ++n) sum += __expf(x[n] - mx);
    float ls = mx + logf(sum);
    float* op = out + ((long)b * A_ + a) * ACT_;
#pragma unroll
    for (int n = 0; n < ACT_; ++n) op[n] = x[n] - ls;
}

extern "C" void kernel_launch(void* const* d_in, const int* in_sizes, int n_in,
                              void* d_out, int out_size, void* d_ws, size_t ws_size,
                              hipStream_t stream)
{
    const float* obs    = (const float*)d_in[0];
    const float* somu_h = (const float*)d_in[1];
    const float* somu_c = (const float*)d_in[2];
    const float* scmu_h = (const float*)d_in[3];
    const float* scmu_c = (const float*)d_in[4];
    const float* masks  = (const float*)d_in[5];
    const float* gWl0 = (const float*)d_in[6],  *gbl0 = (const float*)d_in[7];
    const float* gWr0 = (const float*)d_in[8],  *gbr0 = (const float*)d_in[9];
    const float* gatt0 = (const float*)d_in[10], *gbias0 = (const float*)d_in[11];
    const float* gWl1 = (const float*)d_in[12], *gbl1 = (const float*)d_in[13];
    const float* gWr1 = (const float*)d_in[14], *gbr1 = (const float*)d_in[15];
    const float* gatt1 = (const float*)d_in[16], *gbias1 = (const float*)d_in[17];
    const float* soWih0 = (const float*)d_in[18], *soWhh0 = (const float*)d_in[19];
    const float* sobih0 = (const float*)d_in[20], *sobhh0 = (const float*)d_in[21];
    const float* soWih1 = (const float*)d_in[22], *soWhh1 = (const float*)d_in[23];
    const float* sobih1 = (const float*)d_in[24], *sobhh1 = (const float*)d_in[25];
    const float* soqw = (const float*)d_in[26], *soqb = (const float*)d_in[27];
    const float* soow = (const float*)d_in[28], *soob = (const float*)d_in[29];
    const float* scWih0 = (const float*)d_in[30], *scWhh0 = (const float*)d_in[31];
    const float* scbih0 = (const float*)d_in[32], *scbhh0 = (const float*)d_in[33];
    const float* scWih1 = (const float*)d_in[34], *scWhh1 = (const float*)d_in[35];
    const float* scbih1 = (const float*)d_in[36], *scbhh1 = (const float*)d_in[37];
    const float* scqw = (const float*)d_in[38], *scqb = (const float*)d_in[39];
    const float* scow = (const float*)d_in[40], *scob = (const float*)d_in[41];
    const float* fcw0 = (const float*)d_in[42], *fcb0 = (const float*)d_in[43];
    const float* fcw1 = (const float*)d_in[44], *fcb1 = (const float*)d_in[45];
    const float* actw = (const float*)d_in[46], *actb = (const float*)d_in[47];

    // ---------- workspace layout (~200 MB) ----------
    unsigned short* wb = (unsigned short*)d_ws;
    long wo = 0;
    auto nxt = [&](long n) { long c = wo; wo += n; return c; };
    const long o_gW0 = nxt(262144), o_gW1 = nxt(262144);
    const long o_soWih0 = nxt(2 * 524288), o_soWhh0 = nxt(2 * 524288);
    const long o_soWih1 = nxt(2 * 524288), o_soWhh1 = nxt(2 * 524288);
    const long o_soqw = nxt(2 * 393216), o_soow = nxt(2 * 131072);
    const long o_scWih0 = nxt(2 * 1572864), o_scWhh0 = nxt(2 * 524288);
    const long o_scWih1 = nxt(2 * 524288), o_scWhh1 = nxt(2 * 524288);
    const long o_scqw = nxt(2 * 393216), o_scow = nxt(2 * 131072);
    const long o_fcw0 = nxt(2 * 425984), o_fcw1 = nxt(2 * 65536);
    const long o_actw = nxt(2 * 32768);                         // weights end: 14,155,776

    unsigned short* feat   = wb + nxt(FP_);            // single plane
    unsigned short* hmso   = wb + nxt(4194304);
    unsigned short* hmsc   = wb + nxt(4194304);
    unsigned short* cmso   = wb + nxt(4194304);
    unsigned short* cmsc   = wb + nxt(4194304);
    unsigned short* arenaA = wb + nxt(25165824);       // xlr | x1,x2,logits
    unsigned short* arenaB = wb + nxt(16777216);       // tokS, tokC
    // total ≈ 100.1M shorts = 200 MB

    unsigned short* xlr    = arenaA;                   // GAT phase [16384][1024]
    unsigned short* tokS   = arenaB;                   // [A][B][4][128]
    unsigned short* tokC   = arenaB + 8388608;
    unsigned short* x1     = arenaA;                   // head phase (single plane)
    unsigned short* x2     = arenaA + 4194304;
    float*          logits = (float*)(arenaA + 8388608);

    // ---------- weight cast ----------
    WTab tab;
    int ei = 0;
    auto ent = [&](const float* s, long hoff, long loff, int n, int npad, int kc, int wlo) {
        tab.src[ei] = s; tab.hoff[ei] = hoff; tab.loff[ei] = loff;
        tab.n[ei] = n; tab.npad[ei] = npad; tab.kc[ei] = kc; tab.wlo[ei] = wlo; ++ei;
    };
    ent(gWl0, o_gW0,          o_gW0 + 131072,          65536, 65536, 0, 0);
    ent(gWr0, o_gW0 + 65536,  o_gW0 + 196608,          65536, 65536, 0, 0);
    ent(gWl1, o_gW1,          o_gW1 + 131072,          65536, 65536, 0, 0);
    ent(gWr1, o_gW1 + 65536,  o_gW1 + 196608,          65536, 65536, 0, 0);
    ent(soWih0, o_soWih0, o_soWih0 + 524288, 524288, 524288, 128, 0);
    ent(soWhh0, o_soWhh0, o_soWhh0 + 524288, 524288, 524288, 128, 0);
    ent(soWih1, o_soWih1, o_soWih1 + 524288, 524288, 524288, 128, 0);
    ent(soWhh1, o_soWhh1, o_soWhh1 + 524288, 524288, 524288, 128, 0);
    ent(soqw, o_soqw, o_soqw + 393216, 393216, 393216, 0, 0);
    ent(soow, o_soow, o_soow + 131072, 131072, 131072, 0, 0);
    ent(scWih0, o_scWih0, o_scWih0 + 1572864, 1572864, 1572864, 384, 0);
    ent(scWhh0, o_scWhh0, o_scWhh0 + 524288, 524288, 524288, 128, 0);
    ent(scWih1, o_scWih1, o_scWih1 + 524288, 524288, 524288, 128, 0);
    ent(scWhh1, o_scWhh1, o_scWhh1 + 524288, 524288, 524288, 128, 0);
    ent(scqw, o_scqw, o_scqw + 393216, 393216, 393216, 0, 0);
    ent(scow, o_scow, o_scow + 131072, 131072, 131072, 0, 0);
    ent(fcw0, o_fcw0, o_fcw0 + 425984, 425984, 425984, 0, 0);
    ent(fcw1, o_fcw1, o_fcw1 + 65536, 65536, 65536, 0, 0);
    ent(actw, o_actw, o_actw + 32768, 3584, 32768, 0, 1);
    wcast_k<<<dim3(1024, NW), 256, 0, stream>>>(tab, wb);

    prep_k<<<(2097152 + 4 * 4194304) / 256, 256, 0, stream>>>(
        obs, somu_h, scmu_h, somu_c, scmu_c, masks, feat, hmso, hmsc, cmso, cmsc);

    auto mkd = [&](const unsigned short* X1p, long xsa1, int ldx1, int K1,
                   const unsigned short* X2p, long xsa2, int ldx2, int K2,
                   long wo1, long wsa1, long wps1, long wo2, long wsa2, long wps2,
                   const float* bb1, long bsa1, const float* bb2, long bsa2,
                   void* Y, long ysa, int ldy, int N, int flags, int nA,
                   const unsigned short* cmsp, unsigned short* tokp, unsigned short* featp,
                   int layer, int foff) -> GDesc {
        GDesc d;
        d.X1 = X1p; d.X2 = X2p;
        d.W1 = wb + wo1; d.W2 = X2p ? wb + wo2 : nullptr;
        d.b1 = bb1; d.b2 = bb2; d.Y = Y;
        d.cms = cmsp; d.tokp = tokp; d.featp = featp;
        d.xsa1 = xsa1; d.xsa2 = xsa2;
        d.wsa1 = wsa1; d.wps1 = wps1; d.wsa2 = wsa2; d.wps2 = wps2;
        d.bsa1 = bsa1; d.bsa2 = bsa2; d.ysa = ysa;
        d.ldx1 = ldx1; d.K1 = K1; d.ldx2 = ldx2; d.K2 = K2; d.ldy = ldy; d.N = N;
        d.flags = flags; d.nA = nA; d.Nb = (N + 63) / 64;
        d.layer = layer; d.foff = foff;
        return d;
    };

    // ---------- descriptors ----------
    GDesc gat0 = mkd(feat, 0, 1664, 128, nullptr, 0, 0, 0,
                     o_gW0, 0, 131072, 0, 0, 0, gbl0, 0, gbr0, 0,
                     xlr, 0, 1024, 1024, 2 | 8, 1, nullptr, nullptr, nullptr, 0, 0);
    GDesc gat1 = mkd(feat + 128, 0, 1664, 128, nullptr, 0, 0, 0,
                     o_gW1, 0, 131072, 0, 0, 0, gbl1, 0, gbr1, 0,
                     xlr, 0, 1024, 1024, 2 | 8, 1, nullptr, nullptr, nullptr, 0, 0);
    GDesc so0  = mkd(feat, (long)B_ * 1664, 1664, 128, hmso, (long)B_ * 128, 128, 128,
                     o_soWih0, 512l * 128, 524288, o_soWhh0, 512l * 128, 524288,
                     sobih0, 512, sobhh0, 512, nullptr, 0, 0, 512, 16, A_,
                     cmso, tokS, nullptr, 0, 0);
    GDesc so1  = mkd(tokS, (long)B_ * 512, 512, 128, hmso + 2097152, (long)B_ * 128, 128, 128,
                     o_soWih1, 512l * 128, 524288, o_soWhh1, 512l * 128, 524288,
                     sobih1, 512, sobhh1, 512, nullptr, 0, 0, 512, 16, A_,
                     cmso, tokS, feat, 1, 384);
    GDesc sc0  = mkd(feat, (long)B_ * 1664, 1664, 384, hmsc, (long)B_ * 128, 128, 128,
                     o_scWih0, 512l * 384, 1572864, o_scWhh0, 512l * 128, 524288,
                     scbih0, 512, scbhh0, 512, nullptr, 0, 0, 512, 16, A_,
                     cmsc, tokC, nullptr, 0, 0);
    GDesc sc1  = mkd(tokC, (long)B_ * 512, 512, 128, hmsc + 2097152, (long)B_ * 128, 128, 128,
                     o_scWih1, 512l * 128, 524288, o_scWhh1, 512l * 128, 524288,
                     scbih1, 512, scbhh1, 512, nullptr, 0, 0, 512, 16, A_,
                     cmsc, tokC, feat, 1, 1024);
    GDesc fc0d = mkd(feat, 0, 1664, 1664, nullptr, 0, 0, 0,
                     o_fcw0, 0, 425984, 0, 0, 0, fcb0, 0, nullptr, 0,
                     x1, 0, 256, 256, 1 | 2, 1, nullptr, nullptr, nullptr, 0, 0);
    GDesc fc1d = mkd(x1, 0, 256, 256, nullptr, 0, 0, 0,
                     o_fcw1, 0, 65536, 0, 0, 0, fcb1, 0, nullptr, 0,
                     x2, 0, 256, 256, 1 | 2, 1, nullptr, nullptr, nullptr, 0, 0);
    GDesc actd = mkd(x2, 0, 256, 256, nullptr, 0, 0, 0,
                     o_actw, 0, 32768, 0, 0, 0, actb, 0, nullptr, 0,
                     logits, 0, ACT_, ACT_, 0, 1, nullptr, nullptr, nullptr, 0, 0);

    // grid helpers: MI=2 -> BM=128, MI=1 -> BM=64
    auto grid2 = [&](const GDesc& d, int M) { return d.nA * (M / 128) * d.Nb; };
    auto grid1 = [&](const GDesc& d, int M) { return d.nA * (M / 64) * d.Nb; };

    // ---------- schedule ----------
    // merged: gat0 (2048 blocks) + so0 (1024 blocks @ MI=2); so0 only reads obs cols
    {
        int gA = grid2(gat0, 16384), gB = grid2(so0, B_);
        mgemm_t<2, 0><<<gA + gB, 256, 0, stream>>>(gat0, so0, gA);
    }
    gat_reduce_k<<<B_, 256, 0, stream>>>(xlr, gatt0, gbias0, feat, 128);
    // merged: gat1 + so1 (so0 completed in previous launch)
    {
        int gA = grid2(gat1, 16384), gB = grid2(so1, B_);
        mgemm_t<2, 0><<<gA + gB, 256, 0, stream>>>(gat1, so1, gA);
    }
    gat_reduce_k<<<B_, 256, 0, stream>>>(xlr, gatt1, gbias1, feat, 256);

    // scmu gates need full feat (after reduce1)
    mgemm_t<1, 0><<<grid1(sc0, B_), 256, 0, stream>>>(sc0, sc0, BIGSPLIT);
    mgemm_t<1, 0><<<grid1(sc1, B_), 256, 0, stream>>>(sc1, sc1, BIGSPLIT);

    // both chains' qkv+attn+outproj in ONE launch (double-buffered W)
    sattn_k<<<2048, 512, 0, stream>>>(tokS, tokC,
                                      wb + o_soqw, wb + o_scqw, soqb, scqb,
                                      wb + o_soow, wb + o_scow, soob, scob,
                                      feat);

    mgemm_t<2, 0><<<grid2(fc0d, 16384), 256, 0, stream>>>(fc0d, fc0d, BIGSPLIT);
    mgemm_t<2, 0><<<grid2(fc1d, 16384), 256, 0, stream>>>(fc1d, fc1d, BIGSPLIT);
    mgemm_t<2, 1><<<grid2(actd, 16384), 256, 0, stream>>>(actd, actd, BIGSPLIT);
    lsm_k<<<A_ * B_ / 256, 256, 0, stream>>>(logits, (float*)d_out);
}

// Round 26
// 303.673 us; speedup vs baseline: 1.4439x; 1.0629x over previous
//
#include <hip/hip_runtime.h>
#include <math.h>

#define B_ 2048
#define A_ 8
#define ACT_ 14
#define FP_ 27262976l   // feat stride (16384*1664), single bf16 plane
#define BIGSPLIT (1 << 30)

typedef short short8 __attribute__((ext_vector_type(8)));
typedef float floatx4 __attribute__((ext_vector_type(4)));
typedef unsigned short u16x4 __attribute__((ext_vector_type(4)));

__device__ __forceinline__ unsigned short f2b(float f) {
    unsigned u = __float_as_uint(f);
    u += 0x7fff + ((u >> 16) & 1);
    return (unsigned short)(u >> 16);
}
__device__ __forceinline__ float b2f(unsigned short h) {
    return __uint_as_float(((unsigned)h) << 16);
}
__device__ __forceinline__ float sigm_(float x) { return 1.0f / (1.0f + __expf(-x)); }
__device__ __forceinline__ float tanh_(float x) { return 1.0f - 2.0f / (1.0f + __expf(2.0f * x)); }

// ===== bf16 MFMA GEMM: (MI*64)x64 tiles; TT=1 -> exact hi/lo W (2-term), TT=0 -> hi only.
// ===== single-bf16 activations, ping-pong LDS (1 barrier/chunk), depth-4 reg prefetch.
// ===== obf non-fold epilogue: LDS-staged coalesced tile dump (short8 rows).
// flags: 1=relu, 2=bf16 out, 4=token-fold rows, 8=split bias at col 512,
//        16=LSTM epilogue (W gate-permuted at cast; writes tok/feat, skips Y).
struct GDesc {
    const unsigned short *X1, *X2, *W1, *W2;
    const float *b1, *b2;
    void* Y;
    const unsigned short* cms;       // masked bf16 c-state [l][a][b][j]
    unsigned short* tokp;
    unsigned short* featp;
    long xsa1, xsa2, wsa1, wps1, wsa2, wps2, bsa1, bsa2, ysa;
    int ldx1, K1, ldx2, K2, ldy, N, flags, nA, Nb, layer, foff;
};

#define LOADC(c, xh, whv, wlv) do {                                                       \
    const unsigned short *Xb_, *Wb_; int ldx_, K_, k0_; long wps_;                        \
    if ((c) < nC1) { Xb_ = X1; ldx_ = ldx1; K_ = K1; wps_ = wps1; Wb_ = W1; k0_ = (c) << 5; } \
    else { Xb_ = X2; ldx_ = ldx2; K_ = K2; wps_ = wps2; Wb_ = W2; k0_ = ((c) - nC1) << 5; } \
    _Pragma("unroll") for (int mi_ = 0; mi_ < MI; ++mi_) {                                \
        int row_ = xr0 + mi_ * 16 + lrow;                                                 \
        xh[mi_] = *(const short8*)(Xb_ + (long)(bm + row_) * ldx_ + k0_ + lslot * 8); }   \
    { int row_ = wr0 + lrow;                                                              \
      const unsigned short* wp_ = Wb_ + (long)(bn + row_) * K_ + k0_ + lslot * 8;         \
      whv = *(const short8*)wp_;                                                          \
      if (TT) wlv = *(const short8*)(wp_ + wps_); }                                       \
} while (0)

#define STOREC(P, xh, whv, wlv) do {                                                      \
    _Pragma("unroll") for (int mi_ = 0; mi_ < MI; ++mi_) {                                \
        int row_ = xr0 + mi_ * 16 + lrow; int sl_ = lslot ^ ((row_ >> 1) & 3);            \
        *(short8*)&Xh_l[P][row_ * 32 + sl_ * 8] = xh[mi_]; }                              \
    { int row_ = wr0 + lrow; int sl_ = lslot ^ ((row_ >> 1) & 3);                         \
      *(short8*)&Wh_l[P][row_ * 32 + sl_ * 8] = whv;                                      \
      if (TT) *(short8*)&Wl_l[P][row_ * 32 + sl_ * 8] = wlv; }                            \
} while (0)

#define COMPUTEC(P) do {                                                                  \
    short8 bh[4], bl[4];                                                                  \
    _Pragma("unroll") for (int ni = 0; ni < 4; ++ni) {                                    \
        int row_ = ni * 16 + lr; int off_ = row_ * 32 + ((lk ^ ((row_ >> 1) & 3)) * 8);   \
        bh[ni] = *(const short8*)&Wh_l[P][off_];                                          \
        if (TT) bl[ni] = *(const short8*)&Wl_l[P][off_]; }                                \
    _Pragma("unroll") for (int mi = 0; mi < MI; ++mi) {                                   \
        int row_ = xr0 + mi * 16 + lr; int off_ = row_ * 32 + ((lk ^ ((row_ >> 1) & 3)) * 8); \
        short8 ah = *(const short8*)&Xh_l[P][off_];                                       \
        _Pragma("unroll") for (int ni = 0; ni < 4; ++ni)                                  \
            acc[mi][ni] = __builtin_amdgcn_mfma_f32_16x16x32_bf16(ah, bh[ni], acc[mi][ni], 0, 0, 0); \
        if (TT) {                                                                         \
            _Pragma("unroll") for (int ni = 0; ni < 4; ++ni)                              \
                acc[mi][ni] = __builtin_amdgcn_mfma_f32_16x16x32_bf16(ah, bl[ni], acc[mi][ni], 0, 0, 0); \
        }                                                                                 \
    }                                                                                     \
} while (0)

template<int MI, int TT>
__launch_bounds__(256)
__global__ void mgemm_t(GDesc dA, GDesc dB, int split)
{
    __shared__ __align__(16) unsigned short Xh_l[2][MI * 64 * 32];
    __shared__ __align__(16) unsigned short Wh_l[2][64 * 32];
    __shared__ __align__(16) unsigned short Wl_l[2][TT ? 64 * 32 : 8];

    int wg = blockIdx.x;
    GDesc d = dA;
    if (wg >= split) { d = dB; wg -= split; }

    const unsigned short* X1 = d.X1; const unsigned short* X2 = d.X2;
    const unsigned short* W1 = d.W1; const unsigned short* W2 = d.W2;
    const float* b1 = d.b1; const float* b2 = d.b2;
    const long wps1 = d.wps1, wps2 = d.wps2, ysa = d.ysa;
    const int ldx1 = d.ldx1, K1 = d.K1, ldx2 = d.ldx2, K2 = d.K2;
    const int ldy = d.ldy, N = d.N, flags = d.flags, nA = d.nA, Nb = d.Nb;
    const int layer = d.layer, foff = d.foff;

    int a, mb, nb;
    if (nA == 8) { a = wg & 7; int q = wg >> 3; nb = q % Nb; mb = q / Nb; }
    else { a = 0; int x8 = wg & 7; int q = wg >> 3; nb = q % Nb; mb = (q / Nb) * 8 + x8; }

    X1 += (long)a * d.xsa1;
    W1 += (long)a * d.wsa1;
    if (X2) { X2 += (long)a * d.xsa2; W2 += (long)a * d.wsa2; }
    if (b1) b1 += (long)a * d.bsa1;
    if (b2) b2 += (long)a * d.bsa2;

    const int bm = mb * (MI * 64);
    const int bn = nb * 64;
    const int t = threadIdx.x;
    const int lane = t & 63, wid = t >> 6;

    floatx4 acc[MI][4] = {};

    const int xr0 = wid * (MI * 16);
    const int wr0 = wid * 16;
    const int lrow = lane >> 2;
    const int lslot = lane & 3;
    const int lr = lane & 15, lk = lane >> 4;

    const int nC1 = K1 >> 5;
    const int nC = nC1 + (X2 ? (K2 >> 5) : 0);

    short8 Axh[MI], Awh, Awl;
    short8 Bxh[MI], Bwh, Bwl;
    short8 Cxh[MI], Cwh, Cwl;
    short8 Dxh[MI], Dwh, Dwl;

    LOADC(0, Axh, Awh, Awl);
    if (nC > 1) LOADC(1, Bxh, Bwh, Bwl);
    if (nC > 2) LOADC(2, Cxh, Cwh, Cwl);
    if (nC > 3) LOADC(3, Dxh, Dwh, Dwl);

    for (int c = 0; c < nC; c += 4) {
        STOREC(0, Axh, Awh, Awl);
        __syncthreads();
        if (c + 4 < nC) LOADC(c + 4, Axh, Awh, Awl);
        COMPUTEC(0);
        if (c + 1 < nC) {
            STOREC(1, Bxh, Bwh, Bwl);
            __syncthreads();
            if (c + 5 < nC) LOADC(c + 5, Bxh, Bwh, Bwl);
            COMPUTEC(1);
        }
        if (c + 2 < nC) {
            STOREC(0, Cxh, Cwh, Cwl);
            __syncthreads();
            if (c + 6 < nC) LOADC(c + 6, Cxh, Cwh, Cwl);
            COMPUTEC(0);
        }
        if (c + 3 < nC) {
            STOREC(1, Dxh, Dwh, Dwl);
            __syncthreads();
            if (c + 7 < nC) LOADC(c + 7, Dxh, Dwh, Dwl);
            COMPUTEC(1);
        }
    }

    const int lg = lane >> 4;

    if (flags & 16) {
        // fused LSTM pointwise epilogue (W rows gate-permuted at cast); j = nb*16 + lr
        const int j = (bn >> 2) + lr;
        unsigned short* tokp = d.tokp;
        unsigned short* featp = d.featp;
        const unsigned short* cms = d.cms;
#pragma unroll
        for (int mi = 0; mi < MI; ++mi) {
#pragma unroll
            for (int r = 0; r < 4; ++r) {
                const int b = bm + xr0 + mi * 16 + lg * 4 + r;
                float iv = acc[mi][0][r] + b1[j]       + b2[j];
                float fv = acc[mi][1][r] + b1[128 + j] + b2[128 + j];
                float gv = acc[mi][2][r] + b1[256 + j] + b2[256 + j];
                float ov = acc[mi][3][r] + b1[384 + j] + b2[384 + j];
                iv = sigm_(iv); fv = sigm_(fv); gv = tanh_(gv); ov = sigm_(ov);
                float cp = b2f(cms[(long)layer * 2097152 + (long)a * 262144 + b * 128 + j]);
                float c2 = fv * cp + iv * gv;
                float hv = ov * tanh_(c2);
                long tb = ((long)a * B_ + b) * 512;
                tokp[tb + layer * 128 + j] = f2b(hv);
                tokp[tb + (2 + layer) * 128 + j] = f2b(c2);
                if (featp) featp[((long)a * B_ + b) * 1664 + foff + j] = f2b(hv);
            }
        }
        return;
    }

    const bool relu = flags & 1, obf = flags & 2, fold = flags & 4, sbias = flags & 8;
    float* Yf = (float*)d.Y;
    unsigned short* Yh = (unsigned short*)d.Y;

    if (obf && !fold) {
        // ---- LDS-staged coalesced epilogue: tile [MI*64][64] bf16 -> short8 row dump ----
        __syncthreads();                           // K-loop LDS reads done; reuse Xh_l
        unsigned short* tile = (unsigned short*)Xh_l;
#pragma unroll
        for (int mi = 0; mi < MI; ++mi)
#pragma unroll
            for (int r = 0; r < 4; ++r) {
                int row = xr0 + mi * 16 + lg * 4 + r;
#pragma unroll
                for (int ni = 0; ni < 4; ++ni) {
                    int gc = bn + ni * 16 + lr;
                    float v = acc[mi][ni][r];
                    if (sbias) v += (gc < 512) ? b1[gc] : b2[gc - 512];
                    else { if (b1) v += b1[gc]; if (b2) v += b2[gc]; }
                    if (relu) v = fmaxf(v, 0.f);
                    tile[row * 64 + ni * 16 + lr] = f2b(v);
                }
            }
        __syncthreads();
        const int nch = MI * 64 * 8;               // 16B chunks (N%64==0 on this path)
        for (int cid = t; cid < nch; cid += 256) {
            int row = cid >> 3, sl = cid & 7;
            long dst = (long)(bm + row) * ldy + (long)a * ysa + bn + sl * 8;
            *(short8*)(Yh + dst) = *(const short8*)&tile[row * 64 + sl * 8];
        }
        return;
    }

#pragma unroll
    for (int mi = 0; mi < MI; ++mi) {
#pragma unroll
        for (int r = 0; r < 4; ++r) {
            int gm = bm + xr0 + mi * 16 + lg * 4 + r;
            long rowoff = fold ? ((long)(gm >> 2) * ldy + (gm & 3) * 128) : (long)gm * ldy;
            rowoff += (long)a * ysa;
#pragma unroll
            for (int ni = 0; ni < 4; ++ni) {
                int gc = bn + ni * 16 + lr;
                if (gc < N) {
                    float v = acc[mi][ni][r];
                    if (sbias) v += (gc < 512) ? b1[gc] : b2[gc - 512];
                    else { if (b1) v += b1[gc]; if (b2) v += b2[gc]; }
                    if (relu) v = fmaxf(v, 0.f);
                    if (obf) Yh[rowoff + gc] = f2b(v);
                    else     Yf[rowoff + gc] = v;
                }
            }
        }
    }
}

// ===== fused qkv-GEMM + 4-token MHA + out-proj, BOTH chains, 512 thr (8 waves) =====
// v6: double-buffered W staging (1 barrier/chunk in both GEMM loops).
__launch_bounds__(512)
__global__ void sattn_k(const unsigned short* __restrict__ tokS,
                        const unsigned short* __restrict__ tokC,
                        const unsigned short* __restrict__ WqS,
                        const unsigned short* __restrict__ WqC,
                        const float* __restrict__ qbS, const float* __restrict__ qbC,
                        const unsigned short* __restrict__ WoS,
                        const unsigned short* __restrict__ WoC,
                        const float* __restrict__ obS, const float* __restrict__ obC,
                        unsigned short* __restrict__ feat)
{
    __shared__ __align__(16) unsigned short Xs[64 * 128];    // tok tile -> attn_o (reused)
    __shared__ __align__(16) unsigned short BufW[25600];     // 2xWh[384][32] | Q[64][396] | 2xWo[128][32]
    __shared__ float qbias[384];
    __shared__ float obias[128];

    int bid = blockIdx.x;
    const unsigned short* tok; const unsigned short* Wq; const float* qb;
    const unsigned short* Wo; const float* ob; int foff;
    if (bid < 1024) { tok = tokS; Wq = WqS; qb = qbS; Wo = WoS; ob = obS; foff = 512; }
    else { bid -= 1024; tok = tokC; Wq = WqC; qb = qbC; Wo = WoC; ob = obC; foff = 1152; }

    const int a = bid & 7;               // agent-per-XCD
    const int g = bid >> 3;              // 0..127
    const int b0 = g * 16;

    const unsigned short* Wqa = Wq + (long)a * 49152;
    const unsigned short* Woa = Wo + (long)a * 16384;
    const unsigned short* tokb = tok + ((long)a * B_ + b0) * 512;

    const int t = threadIdx.x;
    const int lane = t & 63, wid = t >> 6;          // wid 0..7
    const int lr = lane & 15, lk = lane >> 4, lg = lane >> 4;

    // ---- per-thread W slot geometry (qkv: 3 slots of 1536; outproj: 1 of 512) ----
    int qwr[3], qws[3];
#pragma unroll
    for (int j = 0; j < 3; ++j) {
        int idx = t + j * 512;
        qwr[j] = idx >> 2; qws[j] = idx & 3;
    }
    const int owr = t >> 2, ows = t & 3;            // t < 512 covers all 512 slots

    // ---- stage X (64x128, slot-swizzled s^(r&7)) + biases ----
    for (int idx = t; idx < 1024; idx += 512) {
        int r = idx >> 4, s = idx & 15;
        *(short8*)&Xs[r * 128 + (s ^ (r & 7)) * 8] = *(const short8*)(tokb + r * 128 + s * 8);
    }
    if (t < 384) qbias[t] = qb[a * 384 + t];
    if (t < 128) obias[t] = ob[a * 128 + t];

    unsigned short* Wh0 = BufW;            // [384][32]
    unsigned short* Wh1 = BufW + 12288;    // [384][32]

    short8 pw[3];
#pragma unroll
    for (int j = 0; j < 3; ++j)
        pw[j] = *(const short8*)(Wqa + qwr[j] * 128 + qws[j] * 8);
#pragma unroll
    for (int j = 0; j < 3; ++j)            // chunk 0 -> buf0 (pre-barrier)
        *(short8*)(Wh0 + qwr[j] * 32 + ((qws[j] ^ ((qwr[j] >> 1) & 3)) * 8)) = pw[j];
#pragma unroll
    for (int j = 0; j < 3; ++j)            // prefetch chunk 1
        pw[j] = *(const short8*)(Wqa + qwr[j] * 128 + 32 + qws[j] * 8);

    __syncthreads();                       // bar: Xs + biases + Wh0 visible

    floatx4 acc[4][3] = {};                // m-frag 0..3 (rows), n-frag 0..2 (cols wid*48+)

#pragma unroll
    for (int kc = 0; kc < 4; ++kc) {
        const int k0 = kc * 32;
        unsigned short* cur = (kc & 1) ? Wh1 : Wh0;
        unsigned short* nxt = (kc & 1) ? Wh0 : Wh1;
        if (kc < 3) {
            // write chunk kc+1 into the buffer whose readers finished at the last barrier
#pragma unroll
            for (int j = 0; j < 3; ++j)
                *(short8*)(nxt + qwr[j] * 32 + ((qws[j] ^ ((qwr[j] >> 1) & 3)) * 8)) = pw[j];
            if (kc < 2) {
#pragma unroll
                for (int j = 0; j < 3; ++j)
                    pw[j] = *(const short8*)(Wqa + qwr[j] * 128 + k0 + 64 + qws[j] * 8);
            }
        }
        short8 af[4];
#pragma unroll
        for (int mi = 0; mi < 4; ++mi) {
            int row = mi * 16 + lr;
            int sl = ((k0 >> 3) + lk) ^ (row & 7);
            af[mi] = *(const short8*)&Xs[row * 128 + sl * 8];
        }
#pragma unroll
        for (int ni = 0; ni < 3; ++ni) {
            int nrow = wid * 48 + ni * 16 + lr;
            int off = nrow * 32 + ((lk ^ ((nrow >> 1) & 3)) * 8);
            short8 bh = *(const short8*)&cur[off];
#pragma unroll
            for (int mi = 0; mi < 4; ++mi)
                acc[mi][ni] = __builtin_amdgcn_mfma_f32_16x16x32_bf16(af[mi], bh, acc[mi][ni], 0, 0, 0);
        }
        __syncthreads();                   // 1 barrier/chunk (last one guards Q overwrite)
    }

    // ---- write qkv (bf16 + bias) to Q[64][396] ----
    unsigned short* Q = BufW;
#pragma unroll
    for (int mi = 0; mi < 4; ++mi)
#pragma unroll
        for (int ni = 0; ni < 3; ++ni)
#pragma unroll
            for (int rr = 0; rr < 4; ++rr) {
                int row = mi * 16 + lg * 4 + rr;
                int col = wid * 48 + ni * 16 + lr;
                Q[row * 396 + col] = f2b(acc[mi][ni][rr] + qbias[col]);
            }
    __syncthreads();                       // bar: Q visible

    // ---- prefetch out-proj W chunk 0 (hides under attention VALU) ----
    short8 po = *(const short8*)(Woa + owr * 128 + ows * 8);

    // ---- attention: 2 threads per (sample, tq, h4); each half of PV output ----
    float oa[16];
    int qr, h4, hf;
    {
        int tt = t & 255;
        h4 = tt & 3; int tq = (tt >> 2) & 3, s = tt >> 4;
        hf = t >> 8;                       // 0 or 1: output half
        qr = s * 4 + tq;
        const unsigned short* qp = Q + qr * 396 + h4 * 32;
        float q[32];
#pragma unroll
        for (int r = 0; r < 8; ++r) {
            u16x4 v = *(const u16x4*)(qp + r * 4);
#pragma unroll
            for (int w = 0; w < 4; ++w) q[r * 4 + w] = b2f(v[w]);
        }
        float sv[4];
#pragma unroll
        for (int u = 0; u < 4; ++u) {
            const unsigned short* kp = Q + (s * 4 + u) * 396 + 128 + h4 * 32;
            float dd = 0.f;
#pragma unroll
            for (int r = 0; r < 8; ++r) {
                u16x4 v = *(const u16x4*)(kp + r * 4);
#pragma unroll
                for (int w = 0; w < 4; ++w) dd += q[r * 4 + w] * b2f(v[w]);
            }
            sv[u] = dd * 0.176776695296637f;
        }
        float mx = fmaxf(fmaxf(sv[0], sv[1]), fmaxf(sv[2], sv[3]));
        float e0 = __expf(sv[0] - mx), e1 = __expf(sv[1] - mx);
        float e2 = __expf(sv[2] - mx), e3 = __expf(sv[3] - mx);
        float inv = 1.0f / (e0 + e1 + e2 + e3);
        float al[4] = { e0 * inv, e1 * inv, e2 * inv, e3 * inv };
#pragma unroll
        for (int w = 0; w < 16; ++w) oa[w] = 0.f;
#pragma unroll
        for (int u = 0; u < 4; ++u) {
            const unsigned short* vp = Q + (s * 4 + u) * 396 + 256 + h4 * 32 + hf * 16;
            float wgt = al[u];
#pragma unroll
            for (int r = 0; r < 4; ++r) {
                u16x4 v = *(const u16x4*)(vp + r * 4);
#pragma unroll
                for (int w = 0; w < 4; ++w) oa[r * 4 + w] += wgt * b2f(v[w]);
            }
        }
    }
    __syncthreads();                       // bar: all Q reads done (BufW dead)

    // ---- attn_o -> Xs AND out-proj chunk-0 staging share one barrier ----
    {
#pragma unroll
        for (int p = 0; p < 2; ++p) {
            short8 v;
#pragma unroll
            for (int w = 0; w < 8; ++w) v[w] = (short)f2b(oa[p * 8 + w]);
            int slot = h4 * 4 + hf * 2 + p;
            *(short8*)&Xs[qr * 128 + (slot ^ (qr & 7)) * 8] = v;
        }
    }
    unsigned short* W20 = BufW;            // [128][32]
    unsigned short* W21 = BufW + 4096;     // [128][32]
    *(short8*)(W20 + owr * 32 + ((ows ^ ((owr >> 1) & 3)) * 8)) = po;
    po = *(const short8*)(Woa + owr * 128 + 32 + ows * 8);   // prefetch chunk 1
    __syncthreads();                       // bar: attn Xs + W20 visible

    // ---- out-proj: M=64, N=128 (wave owns 16 cols), K=128; double-buffered W ----
    floatx4 acc2[4] = {};                  // m-frag 0..3, col block wid*16
#pragma unroll
    for (int kc = 0; kc < 4; ++kc) {
        const int k0 = kc * 32;
        unsigned short* cur = (kc & 1) ? W21 : W20;
        unsigned short* nxt = (kc & 1) ? W20 : W21;
        if (kc < 3) {
            *(short8*)(nxt + owr * 32 + ((ows ^ ((owr >> 1) & 3)) * 8)) = po;
            if (kc < 2)
                po = *(const short8*)(Woa + owr * 128 + k0 + 64 + ows * 8);
        }
        short8 af[4];
#pragma unroll
        for (int mi = 0; mi < 4; ++mi) {
            int row = mi * 16 + lr;
            int sl = ((k0 >> 3) + lk) ^ (row & 7);
            af[mi] = *(const short8*)&Xs[row * 128 + sl * 8];
        }
        {
            int nrow = wid * 16 + lr;
            int off = nrow * 32 + ((lk ^ ((nrow >> 1) & 3)) * 8);
            short8 bh = *(const short8*)&cur[off];
#pragma unroll
            for (int mi = 0; mi < 4; ++mi)
                acc2[mi] = __builtin_amdgcn_mfma_f32_16x16x32_bf16(af[mi], bh, acc2[mi], 0, 0, 0);
        }
        if (kc < 3) __syncthreads();       // no trailing barrier before epilogue
    }

    // ---- epilogue: token-folded feat write ----
#pragma unroll
    for (int mi = 0; mi < 4; ++mi)
#pragma unroll
        for (int rr = 0; rr < 4; ++rr) {
            int row = mi * 16 + lg * 4 + rr;
            int s2 = row >> 2, tq2 = row & 3;
            long base = ((long)a * B_ + b0 + s2) * 1664 + foff + tq2 * 128;
            int col = wid * 16 + lr;
            feat[base + col] = f2b(acc2[mi][rr] + obias[col]);
        }
}

// ===== weight cast (f32 -> bf16 hi; lo plane only where wlo!=0; optional gate permute) =====
#define NW 19
struct WTab {
    const float* src[NW];
    long hoff[NW];
    long loff[NW];
    int n[NW];
    int npad[NW];
    int kc[NW];
    int wlo[NW];
};
__global__ void wcast_k(WTab tab, unsigned short* __restrict__ wb)
{
    const int e = blockIdx.y;
    const int np = tab.npad[e];
    const float* s = tab.src[e];
    unsigned short* dh = wb + tab.hoff[e];
    unsigned short* dl = wb + tab.loff[e];
    const int n = tab.n[e];
    const int kc = tab.kc[e];
    const int wlo = tab.wlo[e];
    for (long i = (long)blockIdx.x * 256 + threadIdx.x; i < np; i += (long)gridDim.x * 256) {
        long si = i;
        if (kc) {
            long per = 512l * kc;
            long ag = i / per;
            long rem = i - ag * per;
            int rp = (int)(rem / kc);
            int k = (int)(rem - (long)rp * kc);
            int srcr = (((rp & 63) >> 4) << 7) + ((rp >> 6) << 4) + (rp & 15);
            si = ag * per + (long)srcr * kc + k;
        }
        float v = (si < n) ? s[si] : 0.f;
        unsigned short h = f2b(v);
        dh[i] = h;
        if (wlo) dl[i] = f2b(v - b2f(h));
    }
}

// ===== prep: obs -> feat[:,0:128]; masked h/c states -> bf16 =====
__global__ void prep_k(const float* __restrict__ obs, const float* __restrict__ soh,
                       const float* __restrict__ sch, const float* __restrict__ soc,
                       const float* __restrict__ scc, const float* __restrict__ masks,
                       unsigned short* __restrict__ feat,
                       unsigned short* __restrict__ hmso, unsigned short* __restrict__ hmsc,
                       unsigned short* __restrict__ cmso, unsigned short* __restrict__ cmsc)
{
    long tid = (long)blockIdx.x * 256 + threadIdx.x;
    if (tid < 2097152) {
        int j = (int)(tid & 127);
        int row = (int)(tid >> 7);
        int b = row >> 3, aa = row & 7;
        feat[((long)aa * B_ + b) * 1664 + j] = f2b(obs[tid]);
        return;
    }
    long u = tid - 2097152;
    const float* src;
    unsigned short* dst;
    if (u < 4194304) { src = soh; dst = hmso; }
    else if (u < 2 * 4194304) { u -= 4194304; src = sch; dst = hmsc; }
    else if (u < 3 * 4194304) { u -= 2 * 4194304; src = soc; dst = cmso; }
    else { u -= 3 * 4194304; src = scc; dst = cmsc; }
    int j = (int)(u & 127);
    int b = (int)((u >> 7) & 2047);
    int aa = (int)((u >> 18) & 7);
    int l = (int)(u >> 21);
    float m = masks[b * 8 + aa];
    dst[u] = f2b(src[((long)(b * 8 + aa)) * 256 + l * 128 + j] * m);
}

// ===== GATv2 reduce (xlr combined [row][1024]: xl | xr) =====
__launch_bounds__(256)
__global__ void gat_reduce_k(const unsigned short* __restrict__ xlr,
                             const float* __restrict__ att, const float* __restrict__ bias,
                             unsigned short* __restrict__ feat, int coloff)
{
    __shared__ float xls[8][512];
    __shared__ float xrs[8][512];
    __shared__ float atts[512];
    __shared__ float es[8][8][4];
    __shared__ float as_[8][8][4];

    const int b = blockIdx.x;
    const int t = threadIdx.x;

    for (int i = t; i < 1024; i += 256) {
        int j = i >> 7, c4 = (i & 127) * 4;
        const unsigned short* base = xlr + ((long)j * B_ + b) * 1024;
        u16x4 vl = *(const u16x4*)(base + c4);
        u16x4 vr = *(const u16x4*)(base + 512 + c4);
#pragma unroll
        for (int q = 0; q < 4; ++q) {
            xls[j][c4 + q] = b2f(vl[q]);
            xrs[j][c4 + q] = b2f(vr[q]);
        }
    }
    for (int i = t; i < 128; i += 256)
        reinterpret_cast<float4*>(atts)[i] = reinterpret_cast<const float4*>(att)[i];
    __syncthreads();

    const int i = t >> 5, j = (t >> 2) & 7, h = t & 3;
    float e = 0.f;
    for (int cc = 0; cc < 128; ++cc) {
        int c = (cc + t) & 127;
        float s = xls[j][h * 128 + c] + xrs[i][h * 128 + c];
        s = s > 0.f ? s : 0.2f * s;
        e += s * atts[h * 128 + c];
    }
    es[i][j][h] = e;
    __syncthreads();

    float mx = -1e30f;
    for (int jj = 0; jj < 8; ++jj) mx = fmaxf(mx, es[i][jj][h]);
    float sum = 0.f;
    for (int jj = 0; jj < 8; ++jj) sum += __expf(es[i][jj][h] - mx);
    as_[i][j][h] = __expf(e - mx) / sum;
    __syncthreads();

    for (int idx = t; idx < 1024; idx += 256) {
        int ii = idx >> 7, c = idx & 127;
        float s = 0.f;
        for (int jj = 0; jj < 8; ++jj)
#pragma unroll
            for (int hh = 0; hh < 4; ++hh)
                s += as_[ii][jj][hh] * xls[jj][hh * 128 + c];
        s = s * 0.25f + bias[c];
        s = fmaxf(s, 0.f);
        feat[((long)ii * B_ + b) * 1664 + coloff + c] = f2b(s);
    }
}

// ===== log_softmax + transpose [A][B][14] -> (B,A,14) =====
__global__ void lsm_k(const float* __restrict__ logits, float* __restrict__ out)
{
    int tid = blockIdx.x * 256 + threadIdx.x;    // A*B
    int b = tid & (B_ - 1);
    int a = tid >> 11;
    const float* lp = logits + ((long)a * B_ + b) * ACT_;
    float x[ACT_];
    float mx = -1e30f;
#pragma unroll
    for (int n = 0; n < ACT_; ++n) { x[n] = lp[n]; mx = fmaxf(mx, x[n]); }
    float sum = 0.f;
#pragma unroll
    for (int n = 0; n < ACT_; ++n) sum += __expf(x[n] - mx);
    float ls = mx + logf(sum);
    float* op = out + ((long)b * A_ + a) * ACT_;
#pragma unroll
    for (int n = 0; n < ACT_; ++n) op[n] = x[n] - ls;
}

extern "C" void kernel_launch(void* const* d_in, const int* in_sizes, int n_in,
                              void* d_out, int out_size, void* d_ws, size_t ws_size,
                              hipStream_t stream)
{
    const float* obs    = (const float*)d_in[0];
    const float* somu_h = (const float*)d_in[1];
    const float* somu_c = (const float*)d_in[2];
    const float* scmu_h = (const float*)d_in[3];
    const float* scmu_c = (const float*)d_in[4];
    const float* masks  = (const float*)d_in[5];
    const float* gWl0 = (const float*)d_in[6],  *gbl0 = (const float*)d_in[7];
    const float* gWr0 = (const float*)d_in[8],  *gbr0 = (const float*)d_in[9];
    const float* gatt0 = (const float*)d_in[10], *gbias0 = (const float*)d_in[11];
    const float* gWl1 = (const float*)d_in[12], *gbl1 = (const float*)d_in[13];
    const float* gWr1 = (const float*)d_in[14], *gbr1 = (const float*)d_in[15];
    const float* gatt1 = (const float*)d_in[16], *gbias1 = (const float*)d_in[17];
    const float* soWih0 = (const float*)d_in[18], *soWhh0 = (const float*)d_in[19];
    const float* sobih0 = (const float*)d_in[20], *sobhh0 = (const float*)d_in[21];
    const float* soWih1 = (const float*)d_in[22], *soWhh1 = (const float*)d_in[23];
    const float* sobih1 = (const float*)d_in[24], *sobhh1 = (const float*)d_in[25];
    const float* soqw = (const float*)d_in[26], *soqb = (const float*)d_in[27];
    const float* soow = (const float*)d_in[28], *soob = (const float*)d_in[29];
    const float* scWih0 = (const float*)d_in[30], *scWhh0 = (const float*)d_in[31];
    const float* scbih0 = (const float*)d_in[32], *scbhh0 = (const float*)d_in[33];
    const float* scWih1 = (const float*)d_in[34], *scWhh1 = (const float*)d_in[35];
    const float* scbih1 = (const float*)d_in[36], *scbhh1 = (const float*)d_in[37];
    const float* scqw = (const float*)d_in[38], *scqb = (const float*)d_in[39];
    const float* scow = (const float*)d_in[40], *scob = (const float*)d_in[41];
    const float* fcw0 = (const float*)d_in[42], *fcb0 = (const float*)d_in[43];
    const float* fcw1 = (const float*)d_in[44], *fcb1 = (const float*)d_in[45];
    const float* actw = (const float*)d_in[46], *actb = (const float*)d_in[47];

    // ---------- workspace layout (~200 MB) ----------
    unsigned short* wb = (unsigned short*)d_ws;
    long wo = 0;
    auto nxt = [&](long n) { long c = wo; wo += n; return c; };
    const long o_gW0 = nxt(262144), o_gW1 = nxt(262144);
    const long o_soWih0 = nxt(2 * 524288), o_soWhh0 = nxt(2 * 524288);
    const long o_soWih1 = nxt(2 * 524288), o_soWhh1 = nxt(2 * 524288);
    const long o_soqw = nxt(2 * 393216), o_soow = nxt(2 * 131072);
    const long o_scWih0 = nxt(2 * 1572864), o_scWhh0 = nxt(2 * 524288);
    const long o_scWih1 = nxt(2 * 524288), o_scWhh1 = nxt(2 * 524288);
    const long o_scqw = nxt(2 * 393216), o_scow = nxt(2 * 131072);
    const long o_fcw0 = nxt(2 * 425984), o_fcw1 = nxt(2 * 65536);
    const long o_actw = nxt(2 * 32768);                         // weights end: 14,155,776

    unsigned short* feat   = wb + nxt(FP_);            // single plane
    unsigned short* hmso   = wb + nxt(4194304);
    unsigned short* hmsc   = wb + nxt(4194304);
    unsigned short* cmso   = wb + nxt(4194304);
    unsigned short* cmsc   = wb + nxt(4194304);
    unsigned short* arenaA = wb + nxt(25165824);       // xlr | x1,x2,logits
    unsigned short* arenaB = wb + nxt(16777216);       // tokS, tokC
    // total ≈ 100.1M shorts = 200 MB

    unsigned short* xlr    = arenaA;                   // GAT phase [16384][1024]
    unsigned short* tokS   = arenaB;                   // [A][B][4][128]
    unsigned short* tokC   = arenaB + 8388608;
    unsigned short* x1     = arenaA;                   // head phase (single plane)
    unsigned short* x2     = arenaA + 4194304;
    float*          logits = (float*)(arenaA + 8388608);

    // ---------- weight cast ----------
    WTab tab;
    int ei = 0;
    auto ent = [&](const float* s, long hoff, long loff, int n, int npad, int kc, int wlo) {
        tab.src[ei] = s; tab.hoff[ei] = hoff; tab.loff[ei] = loff;
        tab.n[ei] = n; tab.npad[ei] = npad; tab.kc[ei] = kc; tab.wlo[ei] = wlo; ++ei;
    };
    ent(gWl0, o_gW0,          o_gW0 + 131072,          65536, 65536, 0, 0);
    ent(gWr0, o_gW0 + 65536,  o_gW0 + 196608,          65536, 65536, 0, 0);
    ent(gWl1, o_gW1,          o_gW1 + 131072,          65536, 65536, 0, 0);
    ent(gWr1, o_gW1 + 65536,  o_gW1 + 196608,          65536, 65536, 0, 0);
    ent(soWih0, o_soWih0, o_soWih0 + 524288, 524288, 524288, 128, 0);
    ent(soWhh0, o_soWhh0, o_soWhh0 + 524288, 524288, 524288, 128, 0);
    ent(soWih1, o_soWih1, o_soWih1 + 524288, 524288, 524288, 128, 0);
    ent(soWhh1, o_soWhh1, o_soWhh1 + 524288, 524288, 524288, 128, 0);
    ent(soqw, o_soqw, o_soqw + 393216, 393216, 393216, 0, 0);
    ent(soow, o_soow, o_soow + 131072, 131072, 131072, 0, 0);
    ent(scWih0, o_scWih0, o_scWih0 + 1572864, 1572864, 1572864, 384, 0);
    ent(scWhh0, o_scWhh0, o_scWhh0 + 524288, 524288, 524288, 128, 0);
    ent(scWih1, o_scWih1, o_scWih1 + 524288, 524288, 524288, 128, 0);
    ent(scWhh1, o_scWhh1, o_scWhh1 + 524288, 524288, 524288, 128, 0);
    ent(scqw, o_scqw, o_scqw + 393216, 393216, 393216, 0, 0);
    ent(scow, o_scow, o_scow + 131072, 131072, 131072, 0, 0);
    ent(fcw0, o_fcw0, o_fcw0 + 425984, 425984, 425984, 0, 0);
    ent(fcw1, o_fcw1, o_fcw1 + 65536, 65536, 65536, 0, 0);
    ent(actw, o_actw, o_actw + 32768, 3584, 32768, 0, 1);
    wcast_k<<<dim3(1024, NW), 256, 0, stream>>>(tab, wb);

    prep_k<<<(2097152 + 4 * 4194304) / 256, 256, 0, stream>>>(
        obs, somu_h, scmu_h, somu_c, scmu_c, masks, feat, hmso, hmsc, cmso, cmsc);

    auto mkd = [&](const unsigned short* X1p, long xsa1, int ldx1, int K1,
                   const unsigned short* X2p, long xsa2, int ldx2, int K2,
                   long wo1, long wsa1, long wps1, long wo2, long wsa2, long wps2,
                   const float* bb1, long bsa1, const float* bb2, long bsa2,
                   void* Y, long ysa, int ldy, int N, int flags, int nA,
                   const unsigned short* cmsp, unsigned short* tokp, unsigned short* featp,
                   int layer, int foff) -> GDesc {
        GDesc d;
        d.X1 = X1p; d.X2 = X2p;
        d.W1 = wb + wo1; d.W2 = X2p ? wb + wo2 : nullptr;
        d.b1 = bb1; d.b2 = bb2; d.Y = Y;
        d.cms = cmsp; d.tokp = tokp; d.featp = featp;
        d.xsa1 = xsa1; d.xsa2 = xsa2;
        d.wsa1 = wsa1; d.wps1 = wps1; d.wsa2 = wsa2; d.wps2 = wps2;
        d.bsa1 = bsa1; d.bsa2 = bsa2; d.ysa = ysa;
        d.ldx1 = ldx1; d.K1 = K1; d.ldx2 = ldx2; d.K2 = K2; d.ldy = ldy; d.N = N;
        d.flags = flags; d.nA = nA; d.Nb = (N + 63) / 64;
        d.layer = layer; d.foff = foff;
        return d;
    };

    // ---------- descriptors ----------
    GDesc gat0 = mkd(feat, 0, 1664, 128, nullptr, 0, 0, 0,
                     o_gW0, 0, 131072, 0, 0, 0, gbl0, 0, gbr0, 0,
                     xlr, 0, 1024, 1024, 2 | 8, 1, nullptr, nullptr, nullptr, 0, 0);
    GDesc gat1 = mkd(feat + 128, 0, 1664, 128, nullptr, 0, 0, 0,
                     o_gW1, 0, 131072, 0, 0, 0, gbl1, 0, gbr1, 0,
                     xlr, 0, 1024, 1024, 2 | 8, 1, nullptr, nullptr, nullptr, 0, 0);
    GDesc so0  = mkd(feat, (long)B_ * 1664, 1664, 128, hmso, (long)B_ * 128, 128, 128,
                     o_soWih0, 512l * 128, 524288, o_soWhh0, 512l * 128, 524288,
                     sobih0, 512, sobhh0, 512, nullptr, 0, 0, 512, 16, A_,
                     cmso, tokS, nullptr, 0, 0);
    GDesc so1  = mkd(tokS, (long)B_ * 512, 512, 128, hmso + 2097152, (long)B_ * 128, 128, 128,
                     o_soWih1, 512l * 128, 524288, o_soWhh1, 512l * 128, 524288,
                     sobih1, 512, sobhh1, 512, nullptr, 0, 0, 512, 16, A_,
                     cmso, tokS, feat, 1, 384);
    GDesc sc0  = mkd(feat, (long)B_ * 1664, 1664, 384, hmsc, (long)B_ * 128, 128, 128,
                     o_scWih0, 512l * 384, 1572864, o_scWhh0, 512l * 128, 524288,
                     scbih0, 512, scbhh0, 512, nullptr, 0, 0, 512, 16, A_,
                     cmsc, tokC, nullptr, 0, 0);
    GDesc sc1  = mkd(tokC, (long)B_ * 512, 512, 128, hmsc + 2097152, (long)B_ * 128, 128, 128,
                     o_scWih1, 512l * 128, 524288, o_scWhh1, 512l * 128, 524288,
                     scbih1, 512, scbhh1, 512, nullptr, 0, 0, 512, 16, A_,
                     cmsc, tokC, feat, 1, 1024);
    GDesc fc0d = mkd(feat, 0, 1664, 1664, nullptr, 0, 0, 0,
                     o_fcw0, 0, 425984, 0, 0, 0, fcb0, 0, nullptr, 0,
                     x1, 0, 256, 256, 1 | 2, 1, nullptr, nullptr, nullptr, 0, 0);
    GDesc fc1d = mkd(x1, 0, 256, 256, nullptr, 0, 0, 0,
                     o_fcw1, 0, 65536, 0, 0, 0, fcb1, 0, nullptr, 0,
                     x2, 0, 256, 256, 1 | 2, 1, nullptr, nullptr, nullptr, 0, 0);
    GDesc actd = mkd(x2, 0, 256, 256, nullptr, 0, 0, 0,
                     o_actw, 0, 32768, 0, 0, 0, actb, 0, nullptr, 0,
                     logits, 0, ACT_, ACT_, 0, 1, nullptr, nullptr, nullptr, 0, 0);

    // grid helpers: MI=2 -> BM=128, MI=1 -> BM=64
    auto grid2 = [&](const GDesc& d, int M) { return d.nA * (M / 128) * d.Nb; };
    auto grid1 = [&](const GDesc& d, int M) { return d.nA * (M / 64) * d.Nb; };

    // ---------- schedule ----------
    // merged: gat0 (2048 blocks) + so0 (1024 blocks @ MI=2); so0 only reads obs cols
    {
        int gA = grid2(gat0, 16384), gB = grid2(so0, B_);
        mgemm_t<2, 0><<<gA + gB, 256, 0, stream>>>(gat0, so0, gA);
    }
    gat_reduce_k<<<B_, 256, 0, stream>>>(xlr, gatt0, gbias0, feat, 128);
    // merged: gat1 + so1 (so0 completed in previous launch)
    {
        int gA = grid2(gat1, 16384), gB = grid2(so1, B_);
        mgemm_t<2, 0><<<gA + gB, 256, 0, stream>>>(gat1, so1, gA);
    }
    gat_reduce_k<<<B_, 256, 0, stream>>>(xlr, gatt1, gbias1, feat, 256);

    // scmu gates need full feat (after reduce1)
    mgemm_t<1, 0><<<grid1(sc0, B_), 256, 0, stream>>>(sc0, sc0, BIGSPLIT);
    mgemm_t<1, 0><<<grid1(sc1, B_), 256, 0, stream>>>(sc1, sc1, BIGSPLIT);

    // both chains' qkv+attn+outproj in ONE launch (double-buffered W)
    sattn_k<<<2048, 512, 0, stream>>>(tokS, tokC,
                                      wb + o_soqw, wb + o_scqw, soqb, scqb,
                                      wb + o_soow, wb + o_scow, soob, scob,
                                      feat);

    mgemm_t<2, 0><<<grid2(fc0d, 16384), 256, 0, stream>>>(fc0d, fc0d, BIGSPLIT);
    mgemm_t<2, 0><<<grid2(fc1d, 16384), 256, 0, stream>>>(fc1d, fc1d, BIGSPLIT);
    mgemm_t<2, 1><<<grid2(actd, 16384), 256, 0, stream>>>(actd, actd, BIGSPLIT);
    lsm_k<<<A_ * B_ / 256, 256, 0, stream>>>(logits, (float*)d_out);
}